// Round 6
// baseline (6022.820 us; speedup 1.0000x reference)
//
#include <hip/hip_runtime.h>

typedef __attribute__((ext_vector_type(8))) short s8v;
typedef __attribute__((ext_vector_type(4))) float f4v;
using u16 = unsigned short;

__device__ __forceinline__ u16 f2bf(float f) {
  union { float f; unsigned u; } v; v.f = f;
  return (u16)((v.u + 0x7FFFu + ((v.u >> 16) & 1u)) >> 16);
}

// ---------------- positional encoding: pe[256][512] ----------------
__global__ __launch_bounds__(256) void pe_kernel(float* __restrict__ pe) {
  int i = blockIdx.x * 256 + threadIdx.x;
  int t = i >> 8, p = i & 255;
  float ex = (2.f * (float)p) / 512.f;
  float ang = (float)t * expf(-ex * 9.210340371976184f);
  pe[t * 512 + 2 * p]     = sinf(ang);
  pe[t * 512 + 2 * p + 1] = cosf(ang);
}

// -------- weight convert: f32 [R][C] -> bf16 [C][R], z-batched, dst stride --
__global__ __launch_bounds__(256) void wconv_kernel(const float* __restrict__ in,
    u16* __restrict__ out, int R, int C, size_t dstride) {
  __shared__ float tile[64][65];
  const size_t mat = (size_t)R * C;
  const float* src = in + (size_t)blockIdx.z * mat;
  u16* dst = out + (size_t)blockIdx.z * dstride;
  int r0 = blockIdx.x * 64, c0 = blockIdx.y * 64;
  int tr = threadIdx.x >> 6, tc = threadIdx.x & 63;
#pragma unroll
  for (int i = 0; i < 16; ++i)
    tile[i * 4 + tr][tc] = src[(size_t)(r0 + i * 4 + tr) * C + (c0 + tc)];
  __syncthreads();
#pragma unroll
  for (int i = 0; i < 16; ++i)
    dst[(size_t)(c0 + i * 4 + tr) * R + (r0 + tc)] = f2bf(tile[tc][i * 4 + tr]);
}

// ---------------- embedding + pe ----------------
__global__ __launch_bounds__(256) void embed_kernel(const int* __restrict__ idx,
    const float* __restrict__ emb, const float* __restrict__ pe, float* __restrict__ y) {
  int i = blockIdx.x * 256 + threadIdx.x;
  int row = i >> 7, c = (i & 127) * 4;
  int t = row & 255;
  int tok = idx[row];
  f4v e = *(const f4v*)(emb + (size_t)tok * 512 + c);
  f4v p = *(const f4v*)(pe + (size_t)t * 512 + c);
  *(f4v*)(y + (size_t)row * 512 + c) = e + p;
}

// ---------------- LayerNorm f32 -> bf16, wave per row ----------------
__global__ __launch_bounds__(256) void ln_kernel(const float* __restrict__ x,
    const float* __restrict__ g, const float* __restrict__ b, u16* __restrict__ out) {
  int row = blockIdx.x * 4 + (threadIdx.x >> 6);
  int lane = threadIdx.x & 63;
  const float* xr = x + (size_t)row * 512 + lane * 8;
  f4v v0 = *(const f4v*)xr;
  f4v v1 = *(const f4v*)(xr + 4);
  float s = v0[0] + v0[1] + v0[2] + v0[3] + v1[0] + v1[1] + v1[2] + v1[3];
#pragma unroll
  for (int o = 1; o < 64; o <<= 1) s += __shfl_xor(s, o);
  float mu = s * (1.f / 512.f);
  float q = 0.f;
#pragma unroll
  for (int j = 0; j < 4; ++j) {
    float d0 = v0[j] - mu; q += d0 * d0;
    float d1 = v1[j] - mu; q += d1 * d1;
  }
#pragma unroll
  for (int o = 1; o < 64; o <<= 1) q += __shfl_xor(q, o);
  float rs = rsqrtf(q * (1.f / 512.f) + 1e-5f);
  f4v g0 = *(const f4v*)(g + lane * 8), g1 = *(const f4v*)(g + lane * 8 + 4);
  f4v b0 = *(const f4v*)(b + lane * 8), b1 = *(const f4v*)(b + lane * 8 + 4);
  s8v ov;
#pragma unroll
  for (int j = 0; j < 4; ++j) {
    ov[j]     = (short)f2bf((v0[j] - mu) * rs * g0[j] + b0[j]);
    ov[4 + j] = (short)f2bf((v1[j] - mu) * rs * g1[j] + b1[j]);
  }
  *(s8v*)(out + (size_t)row * 512 + lane * 8) = ov;
}

// ======== GEMM: C[M,N] = A[M,K](bf16) @ Bt[N,K](bf16)^T ========
// 256x128 tile, BK=64, 8 waves (4M x 2N, wave tile 64x64), 3-deep LDS ring,
// T4 counted vmcnt: iter t stages tile t+2, computes tile t, waits vmcnt(6)
// (tile t+1 retired; t+2's 6 loads stay in flight across the barrier).
// T2 XOR swizzle: linear LDS dest, pre-swizzled global slot, XOR'd ds_read.
template<int HAS_BIAS, int ADD_RES, int RELU, int OUT_BF16, int WLOSS, int NT>
__global__ __launch_bounds__(512, 1) void gemm3r(
    const u16* __restrict__ A, const u16* __restrict__ Bt,
    const float* __restrict__ bias, const float* __restrict__ res,
    void* __restrict__ outp, int M, int N, int K,
    float* __restrict__ pmax, float* __restrict__ psum) {
  __shared__ __align__(16) u16 As[3][256 * 64];
  __shared__ __align__(16) u16 Bs[3][128 * 64];
  const int tid = threadIdx.x, lane = tid & 63, w = tid >> 6;
  // bijective XCD swizzle (grids always % 8 == 0 here)
  int nx = gridDim.x;
  int flat = blockIdx.y * nx + blockIdx.x;
  int per = (nx * gridDim.y) >> 3;
  int sw = (flat & 7) * per + (flat >> 3);
  int by = sw / nx, bx = sw - by * nx;
  const int m0 = bx * 256, n0 = by * 128;
  const int wm = (w >> 1) * 64, wn = (w & 1) * 64;
  const int lhi = lane >> 4, llo = lane & 15;
  const int srow = tid >> 3;                     // 0..63, 8 threads/row
  const int sl = tid & 7;                        // 16B slot within 128B row
  const int gcol = (sl ^ (srow & 7)) * 8;        // pre-swizzled global slot

  const u16* Ag = A + (size_t)(m0 + srow) * K + gcol;
  const u16* Bg = Bt + (size_t)(n0 + srow) * K + gcol;
  const size_t rstep = (size_t)64 * K;

  auto STAGE = [&](int b, int kt) {               // 6 loads/thread
#pragma unroll
    for (int q = 0; q < 4; ++q)
      __builtin_amdgcn_global_load_lds(
          (const __attribute__((address_space(1))) void*)(Ag + q * rstep + kt),
          (__attribute__((address_space(3))) void*)(&As[b][(q * 64 + srow) * 64 + sl * 8]),
          16, 0, 0);
#pragma unroll
    for (int q = 0; q < 2; ++q)
      __builtin_amdgcn_global_load_lds(
          (const __attribute__((address_space(1))) void*)(Bg + q * rstep + kt),
          (__attribute__((address_space(3))) void*)(&Bs[b][(q * 64 + srow) * 64 + sl * 8]),
          16, 0, 0);
  };
  const int sx = llo & 7;

  f4v acc[4][4] = {};
  const int nk = K >> 6;                          // >= 8 for all our launches
  STAGE(0, 0);
  STAGE(1, 64);
  asm volatile("s_waitcnt vmcnt(6)" ::: "memory");   // tile0 retired, tile1 in flight
  __builtin_amdgcn_s_barrier();
  __builtin_amdgcn_sched_barrier(0);
  int cur = 0, nxt = 2;
  for (int t = 0; t < nk; ++t) {
    if (t + 2 < nk) STAGE(nxt, (t + 2) * 64);
#pragma unroll
    for (int kk = 0; kk < 2; ++kk) {
      s8v af[4], bfv[4];
#pragma unroll
      for (int i = 0; i < 4; ++i)
        af[i] = *(const s8v*)&As[cur][(wm + i * 16 + llo) * 64 + (((kk * 4 + lhi) ^ sx) * 8)];
#pragma unroll
      for (int j = 0; j < 4; ++j)
        bfv[j] = *(const s8v*)&Bs[cur][(wn + j * 16 + llo) * 64 + (((kk * 4 + lhi) ^ sx) * 8)];
      __builtin_amdgcn_s_setprio(1);
#pragma unroll
      for (int i = 0; i < 4; ++i)
#pragma unroll
        for (int j = 0; j < 4; ++j)
          acc[i][j] = __builtin_amdgcn_mfma_f32_16x16x32_bf16(af[i], bfv[j], acc[i][j], 0, 0, 0);
      __builtin_amdgcn_s_setprio(0);
    }
    // counted wait: tile t+1's 6 loads retired; tile t+2's 6 remain in flight
    if (t + 2 < nk) asm volatile("s_waitcnt vmcnt(6)" ::: "memory");
    else            asm volatile("s_waitcnt vmcnt(0)" ::: "memory");
    __builtin_amdgcn_s_barrier();
    __builtin_amdgcn_sched_barrier(0);
    cur = (cur == 2) ? 0 : cur + 1;
    nxt = (nxt == 2) ? 0 : nxt + 1;
  }

  // ---- epilogue (D row = (l>>4)*4 + r, col = l&15 — verified layout) ----
  if (OUT_BF16) {
    float bvj[4];
#pragma unroll
    for (int j = 0; j < 4; ++j)
      bvj[j] = HAS_BIAS ? bias[n0 + wn + j * 16 + llo] : 0.f;
#pragma unroll
    for (int i = 0; i < 4; ++i) {
#pragma unroll
      for (int j = 0; j < 4; ++j) {
        int col = n0 + wn + j * 16 + llo;
#pragma unroll
        for (int r = 0; r < 4; ++r) {
          int row = m0 + wm + i * 16 + lhi * 4 + r;
          float v = acc[i][j][r] + bvj[j];
          if (RELU) v = fmaxf(v, 0.f);
          ((u16*)outp)[(size_t)row * N + col] = f2bf(v);
        }
      }
    }
  } else {
    // transposed coalesced f32 path: wave-private LDS [16][68] f32 in As;
    // loss partial buffers in Bs (disjoint).
    float* wbuf = (float*)&As[0][0] + w * 1088;
    float* lbm = (float*)&Bs[0][0];
    float* lbs = lbm + 512;
    f4v bias4 = {0.f, 0.f, 0.f, 0.f};
    if (HAS_BIAS) bias4 = *(const f4v*)(bias + n0 + wn + llo * 4);
#pragma unroll
    for (int i = 0; i < 4; ++i) {
#pragma unroll
      for (int j = 0; j < 4; ++j)
#pragma unroll
        for (int r = 0; r < 4; ++r)
          wbuf[(lhi * 4 + r) * 68 + j * 16 + llo] = acc[i][j][r];
      asm volatile("s_waitcnt lgkmcnt(0)" ::: "memory");
      __builtin_amdgcn_sched_barrier(0);
#pragma unroll
      for (int p = 0; p < 4; ++p) {
        int r16 = p * 4 + lhi;
        f4v v4 = *(const f4v*)&wbuf[r16 * 68 + llo * 4];
        v4 += bias4;
        int grow = m0 + wm + i * 16 + r16;
        int gcol4 = n0 + wn + llo * 4;
        if (ADD_RES) v4 += *(const f4v*)(res + (size_t)grow * N + gcol4);
        if (RELU) {
          v4[0] = fmaxf(v4[0], 0.f); v4[1] = fmaxf(v4[1], 0.f);
          v4[2] = fmaxf(v4[2], 0.f); v4[3] = fmaxf(v4[3], 0.f);
        }
        float* dst = (float*)outp + (size_t)grow * N + gcol4;
        if (NT) __builtin_nontemporal_store(v4, (f4v*)dst);
        else    *(f4v*)dst = v4;
        if (WLOSS) {
          float mx = fmaxf(fmaxf(v4[0], v4[1]), fmaxf(v4[2], v4[3]));
          mx = fmaxf(mx, __shfl_xor(mx, 1));
          mx = fmaxf(mx, __shfl_xor(mx, 2));
          mx = fmaxf(mx, __shfl_xor(mx, 4));
          mx = fmaxf(mx, __shfl_xor(mx, 8));
          float sum = __expf(v4[0] - mx) + __expf(v4[1] - mx)
                    + __expf(v4[2] - mx) + __expf(v4[3] - mx);
          sum += __shfl_xor(sum, 1); sum += __shfl_xor(sum, 2);
          sum += __shfl_xor(sum, 4); sum += __shfl_xor(sum, 8);
          if (llo == 0) {
            int lr = wm + i * 16 + r16;
            lbm[lr * 2 + (wn >> 6)] = mx;
            lbs[lr * 2 + (wn >> 6)] = sum;
          }
        }
      }
      asm volatile("s_waitcnt lgkmcnt(0)" ::: "memory");
      __builtin_amdgcn_sched_barrier(0);
    }
    if (WLOSS) {
      __syncthreads();
      if (tid < 256) {
        float ma = lbm[tid * 2], mb = lbm[tid * 2 + 1];
        float sa = lbs[tid * 2], sb = lbs[tid * 2 + 1];
        float m = fmaxf(ma, mb);
        float ss = sa * __expf(ma - m) + sb * __expf(mb - m);
        int ntile = N >> 7;
        pmax[(size_t)(m0 + tid) * ntile + by] = m;
        psum[(size_t)(m0 + tid) * ntile + by] = ss;
      }
    }
  }
}

// -------- fused attention, one (b,h) per block, T=256, hd=64, strided QKV ----
__global__ __launch_bounds__(256) void attn_kernel(
    const u16* __restrict__ Qp, int qs, const u16* __restrict__ Kp,
    const u16* __restrict__ Vp, int kvs, u16* __restrict__ Ob, int causal) {
  __shared__ __align__(16) u16 Ks[256][72];
  __shared__ __align__(16) u16 Vt[64][264];
  __shared__ __align__(16) u16 Ps[4][16][264];
  const int tid = threadIdx.x, lane = tid & 63, w = tid >> 6;
  const int b = blockIdx.x >> 3, h = blockIdx.x & 7;
  const size_t qbase  = (size_t)b * 256 * qs  + (size_t)h * 64;
  const size_t kvbase = (size_t)b * 256 * kvs + (size_t)h * 64;
  const size_t obase  = (size_t)b * 256 * 512 + (size_t)h * 64;
  {
    int t0 = tid >> 3, d0 = (tid & 7) * 8;
#pragma unroll
    for (int it = 0; it < 8; ++it) {
      int t = it * 32 + t0;
      s8v kv = *(const s8v*)(Kp + kvbase + (size_t)t * kvs + d0);
      *(s8v*)&Ks[t][d0] = kv;
      s8v vv = *(const s8v*)(Vp + kvbase + (size_t)t * kvs + d0);
#pragma unroll
      for (int j = 0; j < 8; ++j) Vt[d0 + j][t] = (u16)vv[j];
    }
  }
  __syncthreads();
  const int lhi = lane >> 4, llo = lane & 15;
  for (int qc = 0; qc < 4; ++qc) {
    const int qr0 = w * 64 + qc * 16;
    s8v aq0 = *(const s8v*)(Qp + qbase + (size_t)(qr0 + llo) * qs + lhi * 8);
    s8v aq1 = *(const s8v*)(Qp + qbase + (size_t)(qr0 + llo) * qs + 32 + lhi * 8);
    f4v S[16];
#pragma unroll
    for (int c = 0; c < 16; ++c) {
      s8v bk0 = *(const s8v*)&Ks[c * 16 + llo][lhi * 8];
      s8v bk1 = *(const s8v*)&Ks[c * 16 + llo][32 + lhi * 8];
      f4v z = {0.f, 0.f, 0.f, 0.f};
      z = __builtin_amdgcn_mfma_f32_16x16x32_bf16(aq0, bk0, z, 0, 0, 0);
      S[c] = __builtin_amdgcn_mfma_f32_16x16x32_bf16(aq1, bk1, z, 0, 0, 0);
    }
#pragma unroll
    for (int r = 0; r < 4; ++r) {
      const int tq = qr0 + lhi * 4 + r;
      float mx = -1e30f;
#pragma unroll
      for (int c = 0; c < 16; ++c) {
        float s = S[c][r] * 0.125f;
        if (causal && (c * 16 + llo) > tq) s = -1e30f;
        S[c][r] = s;
        mx = fmaxf(mx, s);
      }
      mx = fmaxf(mx, __shfl_xor(mx, 1));
      mx = fmaxf(mx, __shfl_xor(mx, 2));
      mx = fmaxf(mx, __shfl_xor(mx, 4));
      mx = fmaxf(mx, __shfl_xor(mx, 8));
      float sum = 0.f;
#pragma unroll
      for (int c = 0; c < 16; ++c) { float p = __expf(S[c][r] - mx); S[c][r] = p; sum += p; }
      sum += __shfl_xor(sum, 1); sum += __shfl_xor(sum, 2);
      sum += __shfl_xor(sum, 4); sum += __shfl_xor(sum, 8);
      float inv = 1.f / sum;
#pragma unroll
      for (int c = 0; c < 16; ++c)
        Ps[w][lhi * 4 + r][c * 16 + llo] = f2bf(S[c][r] * inv);
    }
    asm volatile("s_waitcnt lgkmcnt(0)" ::: "memory");
    f4v o[4] = {};
#pragma unroll
    for (int kb = 0; kb < 8; ++kb) {
      s8v pa = *(const s8v*)&Ps[w][llo][kb * 32 + lhi * 8];
#pragma unroll
      for (int nb = 0; nb < 4; ++nb) {
        s8v bv = *(const s8v*)&Vt[nb * 16 + llo][kb * 32 + lhi * 8];
        o[nb] = __builtin_amdgcn_mfma_f32_16x16x32_bf16(pa, bv, o[nb], 0, 0, 0);
      }
    }
#pragma unroll
    for (int nb = 0; nb < 4; ++nb)
#pragma unroll
      for (int r = 0; r < 4; ++r)
        Ob[obase + (size_t)(qr0 + lhi * 4 + r) * 512 + nb * 16 + llo] = f2bf(o[nb][r]);
  }
}

// ---------------- loss: merge per-tile partials -> per-row nll ----------------
__global__ __launch_bounds__(256) void loss_lse_kernel(const float* __restrict__ pmax,
    const float* __restrict__ psum, const float* __restrict__ logits,
    const int* __restrict__ tgt, float* __restrict__ nll, float* __restrict__ valid) {
  const int w = threadIdx.x >> 6, lane = threadIdx.x & 63;
  const int row = blockIdx.x * 4 + w;
  float m = -1e30f, s = 0.f;
  for (int e = lane; e < 250; e += 64) {
    float pm = pmax[(size_t)row * 250 + e], ps = psum[(size_t)row * 250 + e];
    if (pm > m) { s = s * __expf(m - pm) + ps; m = pm; }
    else          s += ps * __expf(pm - m);
  }
#pragma unroll
  for (int o = 1; o < 64; o <<= 1) {
    float om = __shfl_xor(m, o), os = __shfl_xor(s, o);
    float mm = fmaxf(m, om);
    s = s * __expf(m - mm) + os * __expf(om - mm);
    m = mm;
  }
  if (lane == 0) {
    int t = tgt[row];
    float lse = m + logf(s);
    float v = (t != 1) ? 1.f : 0.f;
    nll[row] = v * (lse - logits[(size_t)row * 32000 + t]);
    valid[row] = v;
  }
}

__global__ __launch_bounds__(256) void loss_final_kernel(const float* __restrict__ nll,
    const float* __restrict__ valid, float* __restrict__ out) {
  __shared__ float sa[256], sb[256];
  int tid = threadIdx.x;
  float s = 0.f, c = 0.f;
  for (int i = tid; i < 16384; i += 256) { s += nll[i]; c += valid[i]; }
  sa[tid] = s; sb[tid] = c;
  __syncthreads();
  for (int st = 128; st > 0; st >>= 1) {
    if (tid < st) { sa[tid] += sa[tid + st]; sb[tid] += sb[tid + st]; }
    __syncthreads();
  }
  if (tid == 0) out[0] = sa[0] / fmaxf(sb[0], 1.f);
}

// =============================== host ===============================
extern "C" void kernel_launch(void* const* d_in, const int* in_sizes, int n_in,
                              void* d_out, int out_size, void* d_ws, size_t ws_size,
                              hipStream_t stream) {
  (void)in_sizes; (void)n_in; (void)out_size; (void)ws_size;
  const int* idx       = (const int*)d_in[0];
  const int* idx_enc   = (const int*)d_in[1];
  const int* targets   = (const int*)d_in[2];
  const float* emb_dec = (const float*)d_in[3];
  const float* emb_enc = (const float*)d_in[4];
  const float* enc_Wq  = (const float*)d_in[5];
  const float* enc_Wk  = (const float*)d_in[6];
  const float* enc_Wv  = (const float*)d_in[7];
  const float* enc_Wo  = (const float*)d_in[8];
  const float* enc_bo  = (const float*)d_in[9];
  const float* enc_ln_g = (const float*)d_in[10];
  const float* enc_ln_b = (const float*)d_in[11];
  const float* enc_W1  = (const float*)d_in[12];
  const float* enc_b1  = (const float*)d_in[13];
  const float* enc_W2  = (const float*)d_in[14];
  const float* enc_b2  = (const float*)d_in[15];
  const float* dWq_sa  = (const float*)d_in[16];
  const float* dWk_sa  = (const float*)d_in[17];
  const float* dWv_sa  = (const float*)d_in[18];
  const float* dWo_sa  = (const float*)d_in[19];
  const float* dbo_sa  = (const float*)d_in[20];
  const float* dWq_xa  = (const float*)d_in[21];
  const float* dWk_xa  = (const float*)d_in[22];
  const float* dWv_xa  = (const float*)d_in[23];
  const float* dWo_xa  = (const float*)d_in[24];
  const float* dbo_xa  = (const float*)d_in[25];
  const float* dec_ln_g = (const float*)d_in[26];
  const float* dec_ln_b = (const float*)d_in[27];
  const float* dec_W1  = (const float*)d_in[28];
  const float* dec_b1  = (const float*)d_in[29];
  const float* dec_W2  = (const float*)d_in[30];
  const float* dec_b2  = (const float*)d_in[31];
  const float* lnf_g   = (const float*)d_in[32];
  const float* lnf_b   = (const float*)d_in[33];
  const float* Wlm     = (const float*)d_in[34];
  const float* blm     = (const float*)d_in[35];
  float* out_logits = (float*)d_out;
  float* out_loss   = out_logits + (size_t)16384 * 32000;

  size_t off = 0;
  auto alloc = [&](size_t bytes) -> char* {
    char* p = (char*)d_ws + off;
    off += (bytes + 255) & ~(size_t)255;
    return p;
  };
  const size_t SQ = 512 * 512, SF = 512 * 2048;
  u16* tWqkvE = (u16*)alloc(6 * 3 * SQ * 2);
  u16* tWoE   = (u16*)alloc(6 * SQ * 2);
  u16* tW1E   = (u16*)alloc(6 * SF * 2);
  u16* tW2E   = (u16*)alloc(6 * SF * 2);
  u16* tWqkvS = (u16*)alloc(6 * 3 * SQ * 2);
  u16* tWoS   = (u16*)alloc(6 * SQ * 2);
  u16* tWqX   = (u16*)alloc(6 * SQ * 2);
  u16* tWkvX  = (u16*)alloc(6 * 2 * SQ * 2);
  u16* tWoX   = (u16*)alloc(6 * SQ * 2);
  u16* tW1D   = (u16*)alloc(6 * SF * 2);
  u16* tW2D   = (u16*)alloc(6 * SF * 2);
  u16* tWlm   = (u16*)alloc((size_t)32000 * 512 * 2);
  float* pe   = (float*)alloc(256 * 512 * 4);
  float* yE   = (float*)alloc((size_t)16384 * 512 * 4);
  float* xD   = (float*)alloc((size_t)16384 * 512 * 4);
  u16* hA     = (u16*)alloc((size_t)16384 * 512 * 2);
  u16* hB     = (u16*)alloc((size_t)16384 * 512 * 2);
  u16* qkvB   = (u16*)alloc((size_t)16384 * 1536 * 2);
  u16* qB     = (u16*)alloc((size_t)16384 * 512 * 2);
  u16* kvB    = (u16*)alloc((size_t)16384 * 1024 * 2);
  u16* atB    = (u16*)alloc((size_t)16384 * 512 * 2);
  u16* midB   = (u16*)alloc((size_t)16384 * 2048 * 2);
  float* pmax = (float*)alloc((size_t)16384 * 250 * 4);
  float* psum = (float*)alloc((size_t)16384 * 250 * 4);
  float* rnll = (float*)alloc(16384 * 4);
  float* rval = (float*)alloc(16384 * 4);

  // ---- weight conversion (every call; deterministic) ----
  dim3 tb(256);
  const size_t S3 = 3 * SQ, S2 = 2 * SQ;
  wconv_kernel<<<dim3(8, 8, 6), tb, 0, stream>>>(enc_Wq, tWqkvE + 0 * SQ, 512, 512, S3);
  wconv_kernel<<<dim3(8, 8, 6), tb, 0, stream>>>(enc_Wk, tWqkvE + 1 * SQ, 512, 512, S3);
  wconv_kernel<<<dim3(8, 8, 6), tb, 0, stream>>>(enc_Wv, tWqkvE + 2 * SQ, 512, 512, S3);
  wconv_kernel<<<dim3(8, 8, 6), tb, 0, stream>>>(enc_Wo, tWoE, 512, 512, SQ);
  wconv_kernel<<<dim3(8, 32, 6), tb, 0, stream>>>(enc_W1, tW1E, 512, 2048, SF);
  wconv_kernel<<<dim3(32, 8, 6), tb, 0, stream>>>(enc_W2, tW2E, 2048, 512, SF);
  wconv_kernel<<<dim3(8, 8, 6), tb, 0, stream>>>(dWq_sa, tWqkvS + 0 * SQ, 512, 512, S3);
  wconv_kernel<<<dim3(8, 8, 6), tb, 0, stream>>>(dWk_sa, tWqkvS + 1 * SQ, 512, 512, S3);
  wconv_kernel<<<dim3(8, 8, 6), tb, 0, stream>>>(dWv_sa, tWqkvS + 2 * SQ, 512, 512, S3);
  wconv_kernel<<<dim3(8, 8, 6), tb, 0, stream>>>(dWo_sa, tWoS, 512, 512, SQ);
  wconv_kernel<<<dim3(8, 8, 6), tb, 0, stream>>>(dWq_xa, tWqX, 512, 512, SQ);
  wconv_kernel<<<dim3(8, 8, 6), tb, 0, stream>>>(dWk_xa, tWkvX + 0 * SQ, 512, 512, S2);
  wconv_kernel<<<dim3(8, 8, 6), tb, 0, stream>>>(dWv_xa, tWkvX + 1 * SQ, 512, 512, S2);
  wconv_kernel<<<dim3(8, 8, 6), tb, 0, stream>>>(dWo_xa, tWoX, 512, 512, SQ);
  wconv_kernel<<<dim3(8, 32, 6), tb, 0, stream>>>(dec_W1, tW1D, 512, 2048, SF);
  wconv_kernel<<<dim3(32, 8, 6), tb, 0, stream>>>(dec_W2, tW2D, 2048, 512, SF);
  wconv_kernel<<<dim3(8, 500, 1), tb, 0, stream>>>(Wlm, tWlm, 512, 32000, (size_t)0);
  pe_kernel<<<256, 256, 0, stream>>>(pe);

  auto ln = [&](const float* xin, const float* g, const float* bb, u16* o) {
    ln_kernel<<<4096, 256, 0, stream>>>(xin, g, bb, o);
  };
  auto g_bf16 = [&](const u16* Ap, const u16* Bp, u16* Op, int N) {
    gemm3r<0, 0, 0, 1, 0, 0><<<dim3(64, N / 128), 512, 0, stream>>>(
        Ap, Bp, nullptr, nullptr, Op, 16384, N, 512, nullptr, nullptr);
  };
  auto proj_res = [&](const u16* Ap, const u16* Bp, const float* bi, float* xr, int K) {
    gemm3r<1, 1, 0, 0, 0, 0><<<dim3(64, 4), 512, 0, stream>>>(
        Ap, Bp, bi, xr, xr, 16384, 512, K, nullptr, nullptr);
  };
  auto ffn1 = [&](const u16* Ap, const u16* Bp, const float* bi, u16* Op) {
    gemm3r<1, 0, 1, 1, 0, 0><<<dim3(64, 16), 512, 0, stream>>>(
        Ap, Bp, bi, nullptr, Op, 16384, 2048, 512, nullptr, nullptr);
  };

  // ---------------- encoder ----------------
  embed_kernel<<<8192, 256, 0, stream>>>(idx_enc, emb_enc, pe, yE);
  for (int l = 0; l < 6; ++l) {
    ln(yE, enc_ln_g + (l * 2 + 0) * 512, enc_ln_b + (l * 2 + 0) * 512, hA);
    g_bf16(hA, tWqkvE + l * S3, qkvB, 1536);
    attn_kernel<<<512, 256, 0, stream>>>(qkvB, 1536, qkvB + 512, qkvB + 1024, 1536, atB, 0);
    proj_res(atB, tWoE + l * SQ, enc_bo + l * 512, yE, 512);
    ln(yE, enc_ln_g + (l * 2 + 1) * 512, enc_ln_b + (l * 2 + 1) * 512, hA);
    ffn1(hA, tW1E + l * SF, enc_b1 + l * 2048, midB);
    proj_res(midB, tW2E + l * SF, enc_b2 + l * 512, yE, 2048);
  }

  // ---------------- decoder ----------------
  embed_kernel<<<8192, 256, 0, stream>>>(idx, emb_dec, pe, xD);
  for (int l = 0; l < 6; ++l) {
    ln(xD, dec_ln_g + (l * 4 + 0) * 512, dec_ln_b + (l * 4 + 0) * 512, hA);
    g_bf16(hA, tWqkvS + l * S3, qkvB, 1536);
    attn_kernel<<<512, 256, 0, stream>>>(qkvB, 1536, qkvB + 512, qkvB + 1024, 1536, atB, 1);
    proj_res(atB, tWoS + l * SQ, dbo_sa + l * 512, xD, 512);
    ln(xD, dec_ln_g + (l * 4 + 1) * 512, dec_ln_b + (l * 4 + 1) * 512, hA);
    ln(yE, dec_ln_g + (l * 4 + 2) * 512, dec_ln_b + (l * 4 + 2) * 512, hB);
    g_bf16(hA, tWqX + l * SQ, qB, 512);
    g_bf16(hB, tWkvX + l * S2, kvB, 1024);
    attn_kernel<<<512, 256, 0, stream>>>(qB, 512, kvB, kvB + 512, 1024, atB, 0);
    proj_res(atB, tWoX + l * SQ, dbo_xa + l * 512, xD, 512);
    ln(xD, dec_ln_g + (l * 4 + 3) * 512, dec_ln_b + (l * 4 + 3) * 512, hA);
    ffn1(hA, tW1D + l * SF, dec_b1 + l * 2048, midB);
    proj_res(midB, tW2D + l * SF, dec_b2 + l * 512, xD, 2048);
  }

  // ---------------- LM head (fused loss partials, nt logits) + loss ----------------
  ln(xD, lnf_g, lnf_b, hA);
  gemm3r<1, 0, 0, 0, 1, 1><<<dim3(64, 250), 512, 0, stream>>>(
      hA, tWlm, blm, nullptr, out_logits, 16384, 32000, 512, pmax, psum);
  loss_lse_kernel<<<4096, 256, 0, stream>>>(pmax, psum, out_logits, targets, rnll, rval);
  loss_final_kernel<<<1, 256, 0, stream>>>(rnll, rval, out_loss);
}

// Round 7
// 4993.998 us; speedup vs baseline: 1.2060x; 1.2060x over previous
//
#include <hip/hip_runtime.h>

typedef __attribute__((ext_vector_type(8))) short s8v;
typedef __attribute__((ext_vector_type(4))) float f4v;
using u16 = unsigned short;

__device__ __forceinline__ u16 f2bf(float f) {
  union { float f; unsigned u; } v; v.f = f;
  return (u16)((v.u + 0x7FFFu + ((v.u >> 16) & 1u)) >> 16);
}

// ---------------- positional encoding: pe[256][512] ----------------
__global__ __launch_bounds__(256) void pe_kernel(float* __restrict__ pe) {
  int i = blockIdx.x * 256 + threadIdx.x;
  int t = i >> 8, p = i & 255;
  float ex = (2.f * (float)p) / 512.f;
  float ang = (float)t * expf(-ex * 9.210340371976184f);
  pe[t * 512 + 2 * p]     = sinf(ang);
  pe[t * 512 + 2 * p + 1] = cosf(ang);
}

// -------- weight convert: f32 [R][C] -> bf16 [C][R], z-batched, dst stride --
__global__ __launch_bounds__(256) void wconv_kernel(const float* __restrict__ in,
    u16* __restrict__ out, int R, int C, size_t dstride) {
  __shared__ float tile[64][65];
  const size_t mat = (size_t)R * C;
  const float* src = in + (size_t)blockIdx.z * mat;
  u16* dst = out + (size_t)blockIdx.z * dstride;
  int r0 = blockIdx.x * 64, c0 = blockIdx.y * 64;
  int tr = threadIdx.x >> 6, tc = threadIdx.x & 63;
#pragma unroll
  for (int i = 0; i < 16; ++i)
    tile[i * 4 + tr][tc] = src[(size_t)(r0 + i * 4 + tr) * C + (c0 + tc)];
  __syncthreads();
#pragma unroll
  for (int i = 0; i < 16; ++i)
    dst[(size_t)(c0 + i * 4 + tr) * R + (r0 + tc)] = f2bf(tile[tc][i * 4 + tr]);
}

// ---------------- embedding + pe ----------------
__global__ __launch_bounds__(256) void embed_kernel(const int* __restrict__ idx,
    const float* __restrict__ emb, const float* __restrict__ pe, float* __restrict__ y) {
  int i = blockIdx.x * 256 + threadIdx.x;
  int row = i >> 7, c = (i & 127) * 4;
  int t = row & 255;
  int tok = idx[row];
  f4v e = *(const f4v*)(emb + (size_t)tok * 512 + c);
  f4v p = *(const f4v*)(pe + (size_t)t * 512 + c);
  *(f4v*)(y + (size_t)row * 512 + c) = e + p;
}

// ---------------- LayerNorm f32 -> bf16, wave per row ----------------
__global__ __launch_bounds__(256) void ln_kernel(const float* __restrict__ x,
    const float* __restrict__ g, const float* __restrict__ b, u16* __restrict__ out) {
  int row = blockIdx.x * 4 + (threadIdx.x >> 6);
  int lane = threadIdx.x & 63;
  const float* xr = x + (size_t)row * 512 + lane * 8;
  f4v v0 = *(const f4v*)xr;
  f4v v1 = *(const f4v*)(xr + 4);
  float s = v0[0] + v0[1] + v0[2] + v0[3] + v1[0] + v1[1] + v1[2] + v1[3];
#pragma unroll
  for (int o = 1; o < 64; o <<= 1) s += __shfl_xor(s, o);
  float mu = s * (1.f / 512.f);
  float q = 0.f;
#pragma unroll
  for (int j = 0; j < 4; ++j) {
    float d0 = v0[j] - mu; q += d0 * d0;
    float d1 = v1[j] - mu; q += d1 * d1;
  }
#pragma unroll
  for (int o = 1; o < 64; o <<= 1) q += __shfl_xor(q, o);
  float rs = rsqrtf(q * (1.f / 512.f) + 1e-5f);
  f4v g0 = *(const f4v*)(g + lane * 8), g1 = *(const f4v*)(g + lane * 8 + 4);
  f4v b0 = *(const f4v*)(b + lane * 8), b1 = *(const f4v*)(b + lane * 8 + 4);
  s8v ov;
#pragma unroll
  for (int j = 0; j < 4; ++j) {
    ov[j]     = (short)f2bf((v0[j] - mu) * rs * g0[j] + b0[j]);
    ov[4 + j] = (short)f2bf((v1[j] - mu) * rs * g1[j] + b1[j]);
  }
  *(s8v*)(out + (size_t)row * 512 + lane * 8) = ov;
}

// ======== GEMM: C[M,N] = A[M,K](bf16) @ Bt[N,K](bf16)^T ========
// Tile BM x BN (BM = MW*WR*16, BN = NW*64), BK=64, waves = MW*NW,
// double-buffered LDS, 2-phase pipeline, T2 XOR swizzle.
// SWZM=0: bijective XCD-chunked swizzle. SWZM=1 (LM head, grid 64x125):
// row-panel-major per XCD — xcd owns bx = xcd*8 + local/125, sweeps by;
// A panel (262 KB) stays L2-resident, Wlm served from L3.
template<int WR, int MW, int NW, int HAS_BIAS, int ADD_RES, int RELU,
         int OUT_BF16, int WLOSS, int NT, int SWZM>
__global__ __launch_bounds__(MW * NW * 64, 2) void gemm_mfma(
    const u16* __restrict__ A, const u16* __restrict__ Bt,
    const float* __restrict__ bias, const float* __restrict__ res,
    void* __restrict__ outp, int M, int N, int K,
    float* __restrict__ pmax, float* __restrict__ psum) {
  constexpr int BM = MW * WR * 16;
  constexpr int BN = NW * 64;
  constexpr int THREADS = MW * NW * 64;
  constexpr int STEP = THREADS / 8;             // staged rows per load-iter
  __shared__ __align__(16) u16 As[2][BM * 64];
  __shared__ __align__(16) u16 Bs[2][BN * 64];
  const int tid = threadIdx.x, lane = tid & 63, w = tid >> 6;
  int bx, by;
  if (SWZM == 1) {
    int flat = blockIdx.y * gridDim.x + blockIdx.x;   // dispatch order
    int xcd = flat & 7, local = flat >> 3;            // local in [0,1000)
    int p = local / 125;
    by = local - p * 125;
    bx = (xcd << 3) + p;
  } else {
    int nx = gridDim.x;
    int flat = blockIdx.y * nx + blockIdx.x;
    int per = (nx * gridDim.y) >> 3;
    int sw = (flat & 7) * per + (flat >> 3);
    by = sw / nx; bx = sw - by * nx;
  }
  const int m0 = bx * BM, n0 = by * BN;
  const int wm = (w / NW) * (WR * 16), wn = (w % NW) * 64;
  const int lhi = lane >> 4, llo = lane & 15;
  const int srow = tid >> 3;
  const int sl = tid & 7;                        // 16B slot within 128B row
  const int gcol = (sl ^ (srow & 7)) * 8;        // pre-swizzled global slot

  const u16* Ag = A + (size_t)(m0 + srow) * K + gcol;
  const u16* Bg = Bt + (size_t)(n0 + srow) * K + gcol;
  const size_t rstep = (size_t)STEP * K;

  auto STAGE = [&](int b, int kt) {
#pragma unroll
    for (int q = 0; q < BM / STEP; ++q)
      __builtin_amdgcn_global_load_lds(
          (const __attribute__((address_space(1))) void*)(Ag + q * rstep + kt),
          (__attribute__((address_space(3))) void*)(&As[b][(q * STEP + srow) * 64 + sl * 8]),
          16, 0, 0);
#pragma unroll
    for (int q = 0; q < BN / STEP; ++q)
      __builtin_amdgcn_global_load_lds(
          (const __attribute__((address_space(1))) void*)(Bg + q * rstep + kt),
          (__attribute__((address_space(3))) void*)(&Bs[b][(q * STEP + srow) * 64 + sl * 8]),
          16, 0, 0);
  };
  const int sx = llo & 7;

  f4v acc[WR][4] = {};
  const int nk = K >> 6;
  STAGE(0, 0);
  asm volatile("s_waitcnt vmcnt(0)" ::: "memory");
  __builtin_amdgcn_s_barrier();
  __builtin_amdgcn_sched_barrier(0);
  int cur = 0;
  for (int t = 0; t < nk; ++t) {
    if (t + 1 < nk) STAGE(cur ^ 1, (t + 1) * 64);
#pragma unroll
    for (int kk = 0; kk < 2; ++kk) {
      s8v af[WR], bfv[4];
#pragma unroll
      for (int i = 0; i < WR; ++i)
        af[i] = *(const s8v*)&As[cur][(wm + i * 16 + llo) * 64 + (((kk * 4 + lhi) ^ sx) * 8)];
#pragma unroll
      for (int j = 0; j < 4; ++j)
        bfv[j] = *(const s8v*)&Bs[cur][(wn + j * 16 + llo) * 64 + (((kk * 4 + lhi) ^ sx) * 8)];
      __builtin_amdgcn_s_setprio(1);
#pragma unroll
      for (int i = 0; i < WR; ++i)
#pragma unroll
        for (int j = 0; j < 4; ++j)
          acc[i][j] = __builtin_amdgcn_mfma_f32_16x16x32_bf16(af[i], bfv[j], acc[i][j], 0, 0, 0);
      __builtin_amdgcn_s_setprio(0);
    }
    asm volatile("s_waitcnt vmcnt(0)" ::: "memory");
    __builtin_amdgcn_s_barrier();
    __builtin_amdgcn_sched_barrier(0);
    cur ^= 1;
  }

  // ---- epilogue (D row = (l>>4)*4 + r, col = l&15 — verified layout) ----
  if (OUT_BF16) {
    float bvj[4];
#pragma unroll
    for (int j = 0; j < 4; ++j)
      bvj[j] = HAS_BIAS ? bias[n0 + wn + j * 16 + llo] : 0.f;
#pragma unroll
    for (int i = 0; i < WR; ++i) {
#pragma unroll
      for (int j = 0; j < 4; ++j) {
        int col = n0 + wn + j * 16 + llo;
#pragma unroll
        for (int r = 0; r < 4; ++r) {
          int row = m0 + wm + i * 16 + lhi * 4 + r;
          float v = acc[i][j][r] + bvj[j];
          if (RELU) v = fmaxf(v, 0.f);
          ((u16*)outp)[(size_t)row * N + col] = f2bf(v);
        }
      }
    }
  } else {
    // transposed coalesced f32 path: wave-private LDS [16][68] f32
    float* lb = (float*)&As[0][0];
    float* wbuf = lb + w * 1088;
    f4v bias4 = {0.f, 0.f, 0.f, 0.f};
    if (HAS_BIAS) bias4 = *(const f4v*)(bias + n0 + wn + llo * 4);
    float* lbm = lb + 9216;
    float* lbs = lb + 10240;
#pragma unroll
    for (int i = 0; i < WR; ++i) {
#pragma unroll
      for (int j = 0; j < 4; ++j)
#pragma unroll
        for (int r = 0; r < 4; ++r)
          wbuf[(lhi * 4 + r) * 68 + j * 16 + llo] = acc[i][j][r];
      asm volatile("s_waitcnt lgkmcnt(0)" ::: "memory");
      __builtin_amdgcn_sched_barrier(0);
#pragma unroll
      for (int p = 0; p < 4; ++p) {
        int r16 = p * 4 + lhi;
        f4v v4 = *(const f4v*)&wbuf[r16 * 68 + llo * 4];
        v4 += bias4;
        int grow = m0 + wm + i * 16 + r16;
        int gcol4 = n0 + wn + llo * 4;
        if (ADD_RES) v4 += *(const f4v*)(res + (size_t)grow * N + gcol4);
        if (RELU) {
          v4[0] = fmaxf(v4[0], 0.f); v4[1] = fmaxf(v4[1], 0.f);
          v4[2] = fmaxf(v4[2], 0.f); v4[3] = fmaxf(v4[3], 0.f);
        }
        float* dst = (float*)outp + (size_t)grow * N + gcol4;
        if (NT) __builtin_nontemporal_store(v4, (f4v*)dst);
        else    *(f4v*)dst = v4;
        if (WLOSS) {
          float mx = fmaxf(fmaxf(v4[0], v4[1]), fmaxf(v4[2], v4[3]));
          mx = fmaxf(mx, __shfl_xor(mx, 1));
          mx = fmaxf(mx, __shfl_xor(mx, 2));
          mx = fmaxf(mx, __shfl_xor(mx, 4));
          mx = fmaxf(mx, __shfl_xor(mx, 8));
          float sum = __expf(v4[0] - mx) + __expf(v4[1] - mx)
                    + __expf(v4[2] - mx) + __expf(v4[3] - mx);
          sum += __shfl_xor(sum, 1); sum += __shfl_xor(sum, 2);
          sum += __shfl_xor(sum, 4); sum += __shfl_xor(sum, 8);
          if (llo == 0) {
            int lr = wm + i * 16 + r16;
            lbm[lr * 4 + (wn >> 6)] = mx;
            lbs[lr * 4 + (wn >> 6)] = sum;
          }
        }
      }
      asm volatile("s_waitcnt lgkmcnt(0)" ::: "memory");
      __builtin_amdgcn_sched_barrier(0);
    }
    if (WLOSS) {
      __syncthreads();
      if (tid < 256) {
        float m = lbm[tid * 4];
        m = fmaxf(fmaxf(m, lbm[tid * 4 + 1]), fmaxf(lbm[tid * 4 + 2], lbm[tid * 4 + 3]));
        float ss = lbs[tid * 4 + 0] * __expf(lbm[tid * 4 + 0] - m)
                 + lbs[tid * 4 + 1] * __expf(lbm[tid * 4 + 1] - m)
                 + lbs[tid * 4 + 2] * __expf(lbm[tid * 4 + 2] - m)
                 + lbs[tid * 4 + 3] * __expf(lbm[tid * 4 + 3] - m);
        int ntile = N >> 8;
        pmax[(size_t)(m0 + tid) * ntile + by] = m;
        psum[(size_t)(m0 + tid) * ntile + by] = ss;
      }
    }
  }
}

// -------- fused attention, one (b,h) per block, T=256, hd=64, strided QKV ----
__global__ __launch_bounds__(256) void attn_kernel(
    const u16* __restrict__ Qp, int qs, const u16* __restrict__ Kp,
    const u16* __restrict__ Vp, int kvs, u16* __restrict__ Ob, int causal) {
  __shared__ __align__(16) u16 Ks[256][72];
  __shared__ __align__(16) u16 Vt[64][264];
  __shared__ __align__(16) u16 Ps[4][16][264];
  const int tid = threadIdx.x, lane = tid & 63, w = tid >> 6;
  const int b = blockIdx.x >> 3, h = blockIdx.x & 7;
  const size_t qbase  = (size_t)b * 256 * qs  + (size_t)h * 64;
  const size_t kvbase = (size_t)b * 256 * kvs + (size_t)h * 64;
  const size_t obase  = (size_t)b * 256 * 512 + (size_t)h * 64;
  {
    int t0 = tid >> 3, d0 = (tid & 7) * 8;
#pragma unroll
    for (int it = 0; it < 8; ++it) {
      int t = it * 32 + t0;
      s8v kv = *(const s8v*)(Kp + kvbase + (size_t)t * kvs + d0);
      *(s8v*)&Ks[t][d0] = kv;
      s8v vv = *(const s8v*)(Vp + kvbase + (size_t)t * kvs + d0);
#pragma unroll
      for (int j = 0; j < 8; ++j) Vt[d0 + j][t] = (u16)vv[j];
    }
  }
  __syncthreads();
  const int lhi = lane >> 4, llo = lane & 15;
  for (int qc = 0; qc < 4; ++qc) {
    const int qr0 = w * 64 + qc * 16;
    s8v aq0 = *(const s8v*)(Qp + qbase + (size_t)(qr0 + llo) * qs + lhi * 8);
    s8v aq1 = *(const s8v*)(Qp + qbase + (size_t)(qr0 + llo) * qs + 32 + lhi * 8);
    f4v S[16];
#pragma unroll
    for (int c = 0; c < 16; ++c) {
      s8v bk0 = *(const s8v*)&Ks[c * 16 + llo][lhi * 8];
      s8v bk1 = *(const s8v*)&Ks[c * 16 + llo][32 + lhi * 8];
      f4v z = {0.f, 0.f, 0.f, 0.f};
      z = __builtin_amdgcn_mfma_f32_16x16x32_bf16(aq0, bk0, z, 0, 0, 0);
      S[c] = __builtin_amdgcn_mfma_f32_16x16x32_bf16(aq1, bk1, z, 0, 0, 0);
    }
#pragma unroll
    for (int r = 0; r < 4; ++r) {
      const int tq = qr0 + lhi * 4 + r;
      float mx = -1e30f;
#pragma unroll
      for (int c = 0; c < 16; ++c) {
        float s = S[c][r] * 0.125f;
        if (causal && (c * 16 + llo) > tq) s = -1e30f;
        S[c][r] = s;
        mx = fmaxf(mx, s);
      }
      mx = fmaxf(mx, __shfl_xor(mx, 1));
      mx = fmaxf(mx, __shfl_xor(mx, 2));
      mx = fmaxf(mx, __shfl_xor(mx, 4));
      mx = fmaxf(mx, __shfl_xor(mx, 8));
      float sum = 0.f;
#pragma unroll
      for (int c = 0; c < 16; ++c) { float p = __expf(S[c][r] - mx); S[c][r] = p; sum += p; }
      sum += __shfl_xor(sum, 1); sum += __shfl_xor(sum, 2);
      sum += __shfl_xor(sum, 4); sum += __shfl_xor(sum, 8);
      float inv = 1.f / sum;
#pragma unroll
      for (int c = 0; c < 16; ++c)
        Ps[w][lhi * 4 + r][c * 16 + llo] = f2bf(S[c][r] * inv);
    }
    asm volatile("s_waitcnt lgkmcnt(0)" ::: "memory");
    f4v o[4] = {};
#pragma unroll
    for (int kb = 0; kb < 8; ++kb) {
      s8v pa = *(const s8v*)&Ps[w][llo][kb * 32 + lhi * 8];
#pragma unroll
      for (int nb = 0; nb < 4; ++nb) {
        s8v bv = *(const s8v*)&Vt[nb * 16 + llo][kb * 32 + lhi * 8];
        o[nb] = __builtin_amdgcn_mfma_f32_16x16x32_bf16(pa, bv, o[nb], 0, 0, 0);
      }
    }
#pragma unroll
    for (int nb = 0; nb < 4; ++nb)
#pragma unroll
      for (int r = 0; r < 4; ++r)
        Ob[obase + (size_t)(qr0 + lhi * 4 + r) * 512 + nb * 16 + llo] = f2bf(o[nb][r]);
  }
}

// ---------------- loss: merge per-tile partials -> per-row nll ----------------
__global__ __launch_bounds__(256) void loss_lse_kernel(const float* __restrict__ pmax,
    const float* __restrict__ psum, const float* __restrict__ logits,
    const int* __restrict__ tgt, float* __restrict__ nll, float* __restrict__ valid) {
  const int w = threadIdx.x >> 6, lane = threadIdx.x & 63;
  const int row = blockIdx.x * 4 + w;
  float m = -1e30f, s = 0.f;
  for (int e = lane; e < 125; e += 64) {
    float pm = pmax[(size_t)row * 125 + e], ps = psum[(size_t)row * 125 + e];
    if (pm > m) { s = s * __expf(m - pm) + ps; m = pm; }
    else          s += ps * __expf(pm - m);
  }
#pragma unroll
  for (int o = 1; o < 64; o <<= 1) {
    float om = __shfl_xor(m, o), os = __shfl_xor(s, o);
    float mm = fmaxf(m, om);
    s = s * __expf(m - mm) + os * __expf(om - mm);
    m = mm;
  }
  if (lane == 0) {
    int t = tgt[row];
    float lse = m + logf(s);
    float v = (t != 1) ? 1.f : 0.f;
    nll[row] = v * (lse - logits[(size_t)row * 32000 + t]);
    valid[row] = v;
  }
}

__global__ __launch_bounds__(256) void loss_final_kernel(const float* __restrict__ nll,
    const float* __restrict__ valid, float* __restrict__ out) {
  __shared__ float sa[256], sb[256];
  int tid = threadIdx.x;
  float s = 0.f, c = 0.f;
  for (int i = tid; i < 16384; i += 256) { s += nll[i]; c += valid[i]; }
  sa[tid] = s; sb[tid] = c;
  __syncthreads();
  for (int st = 128; st > 0; st >>= 1) {
    if (tid < st) { sa[tid] += sa[tid + st]; sb[tid] += sb[tid + st]; }
    __syncthreads();
  }
  if (tid == 0) out[0] = sa[0] / fmaxf(sb[0], 1.f);
}

// =============================== host ===============================
extern "C" void kernel_launch(void* const* d_in, const int* in_sizes, int n_in,
                              void* d_out, int out_size, void* d_ws, size_t ws_size,
                              hipStream_t stream) {
  (void)in_sizes; (void)n_in; (void)out_size; (void)ws_size;
  const int* idx       = (const int*)d_in[0];
  const int* idx_enc   = (const int*)d_in[1];
  const int* targets   = (const int*)d_in[2];
  const float* emb_dec = (const float*)d_in[3];
  const float* emb_enc = (const float*)d_in[4];
  const float* enc_Wq  = (const float*)d_in[5];
  const float* enc_Wk  = (const float*)d_in[6];
  const float* enc_Wv  = (const float*)d_in[7];
  const float* enc_Wo  = (const float*)d_in[8];
  const float* enc_bo  = (const float*)d_in[9];
  const float* enc_ln_g = (const float*)d_in[10];
  const float* enc_ln_b = (const float*)d_in[11];
  const float* enc_W1  = (const float*)d_in[12];
  const float* enc_b1  = (const float*)d_in[13];
  const float* enc_W2  = (const float*)d_in[14];
  const float* enc_b2  = (const float*)d_in[15];
  const float* dWq_sa  = (const float*)d_in[16];
  const float* dWk_sa  = (const float*)d_in[17];
  const float* dWv_sa  = (const float*)d_in[18];
  const float* dWo_sa  = (const float*)d_in[19];
  const float* dbo_sa  = (const float*)d_in[20];
  const float* dWq_xa  = (const float*)d_in[21];
  const float* dWk_xa  = (const float*)d_in[22];
  const float* dWv_xa  = (const float*)d_in[23];
  const float* dWo_xa  = (const float*)d_in[24];
  const float* dbo_xa  = (const float*)d_in[25];
  const float* dec_ln_g = (const float*)d_in[26];
  const float* dec_ln_b = (const float*)d_in[27];
  const float* dec_W1  = (const float*)d_in[28];
  const float* dec_b1  = (const float*)d_in[29];
  const float* dec_W2  = (const float*)d_in[30];
  const float* dec_b2  = (const float*)d_in[31];
  const float* lnf_g   = (const float*)d_in[32];
  const float* lnf_b   = (const float*)d_in[33];
  const float* Wlm     = (const float*)d_in[34];
  const float* blm     = (const float*)d_in[35];
  float* out_logits = (float*)d_out;
  float* out_loss   = out_logits + (size_t)16384 * 32000;

  size_t off = 0;
  auto alloc = [&](size_t bytes) -> char* {
    char* p = (char*)d_ws + off;
    off += (bytes + 255) & ~(size_t)255;
    return p;
  };
  const size_t SQ = 512 * 512, SF = 512 * 2048;
  u16* tWqkvE = (u16*)alloc(6 * 3 * SQ * 2);
  u16* tWoE   = (u16*)alloc(6 * SQ * 2);
  u16* tW1E   = (u16*)alloc(6 * SF * 2);
  u16* tW2E   = (u16*)alloc(6 * SF * 2);
  u16* tWqkvS = (u16*)alloc(6 * 3 * SQ * 2);
  u16* tWoS   = (u16*)alloc(6 * SQ * 2);
  u16* tWqX   = (u16*)alloc(6 * SQ * 2);
  u16* tWkvX  = (u16*)alloc(6 * 2 * SQ * 2);
  u16* tWoX   = (u16*)alloc(6 * SQ * 2);
  u16* tW1D   = (u16*)alloc(6 * SF * 2);
  u16* tW2D   = (u16*)alloc(6 * SF * 2);
  u16* tWlm   = (u16*)alloc((size_t)32000 * 512 * 2);
  float* pe   = (float*)alloc(256 * 512 * 4);
  float* yE   = (float*)alloc((size_t)16384 * 512 * 4);
  float* xD   = (float*)alloc((size_t)16384 * 512 * 4);
  u16* hA     = (u16*)alloc((size_t)16384 * 512 * 2);
  u16* hB     = (u16*)alloc((size_t)16384 * 512 * 2);
  u16* qkvB   = (u16*)alloc((size_t)16384 * 1536 * 2);
  u16* qB     = (u16*)alloc((size_t)16384 * 512 * 2);
  u16* kvB    = (u16*)alloc((size_t)16384 * 1024 * 2);
  u16* atB    = (u16*)alloc((size_t)16384 * 512 * 2);
  u16* midB   = (u16*)alloc((size_t)16384 * 2048 * 2);
  float* pmax = (float*)alloc((size_t)16384 * 125 * 4);
  float* psum = (float*)alloc((size_t)16384 * 125 * 4);
  float* rnll = (float*)alloc(16384 * 4);
  float* rval = (float*)alloc(16384 * 4);

  // ---- weight conversion (every call; deterministic) ----
  dim3 tb(256);
  const size_t S3 = 3 * SQ, S2 = 2 * SQ;
  wconv_kernel<<<dim3(8, 8, 6), tb, 0, stream>>>(enc_Wq, tWqkvE + 0 * SQ, 512, 512, S3);
  wconv_kernel<<<dim3(8, 8, 6), tb, 0, stream>>>(enc_Wk, tWqkvE + 1 * SQ, 512, 512, S3);
  wconv_kernel<<<dim3(8, 8, 6), tb, 0, stream>>>(enc_Wv, tWqkvE + 2 * SQ, 512, 512, S3);
  wconv_kernel<<<dim3(8, 8, 6), tb, 0, stream>>>(enc_Wo, tWoE, 512, 512, SQ);
  wconv_kernel<<<dim3(8, 32, 6), tb, 0, stream>>>(enc_W1, tW1E, 512, 2048, SF);
  wconv_kernel<<<dim3(32, 8, 6), tb, 0, stream>>>(enc_W2, tW2E, 2048, 512, SF);
  wconv_kernel<<<dim3(8, 8, 6), tb, 0, stream>>>(dWq_sa, tWqkvS + 0 * SQ, 512, 512, S3);
  wconv_kernel<<<dim3(8, 8, 6), tb, 0, stream>>>(dWk_sa, tWqkvS + 1 * SQ, 512, 512, S3);
  wconv_kernel<<<dim3(8, 8, 6), tb, 0, stream>>>(dWv_sa, tWqkvS + 2 * SQ, 512, 512, S3);
  wconv_kernel<<<dim3(8, 8, 6), tb, 0, stream>>>(dWo_sa, tWoS, 512, 512, SQ);
  wconv_kernel<<<dim3(8, 8, 6), tb, 0, stream>>>(dWq_xa, tWqX, 512, 512, SQ);
  wconv_kernel<<<dim3(8, 8, 6), tb, 0, stream>>>(dWk_xa, tWkvX + 0 * SQ, 512, 512, S2);
  wconv_kernel<<<dim3(8, 8, 6), tb, 0, stream>>>(dWv_xa, tWkvX + 1 * SQ, 512, 512, S2);
  wconv_kernel<<<dim3(8, 8, 6), tb, 0, stream>>>(dWo_xa, tWoX, 512, 512, SQ);
  wconv_kernel<<<dim3(8, 32, 6), tb, 0, stream>>>(dec_W1, tW1D, 512, 2048, SF);
  wconv_kernel<<<dim3(32, 8, 6), tb, 0, stream>>>(dec_W2, tW2D, 2048, 512, SF);
  wconv_kernel<<<dim3(8, 500, 1), tb, 0, stream>>>(Wlm, tWlm, 512, 32000, (size_t)0);
  pe_kernel<<<256, 256, 0, stream>>>(pe);

  auto ln = [&](const float* xin, const float* g, const float* bb, u16* o) {
    ln_kernel<<<4096, 256, 0, stream>>>(xin, g, bb, o);
  };
  // 128x128-tile instances (4 waves) for small-N; 256x256 (8 waves) for big-N.
  auto g_bf16_sm = [&](const u16* Ap, const u16* Bp, u16* Op, int N) {
    gemm_mfma<4, 2, 2, 0, 0, 0, 1, 0, 0, 0><<<dim3(128, N / 128), 256, 0, stream>>>(
        Ap, Bp, nullptr, nullptr, Op, 16384, N, 512, nullptr, nullptr);
  };
  auto proj_res = [&](const u16* Ap, const u16* Bp, const float* bi, float* xr, int K) {
    gemm_mfma<4, 2, 2, 1, 1, 0, 0, 0, 0, 0><<<dim3(128, 4), 256, 0, stream>>>(
        Ap, Bp, bi, xr, xr, 16384, 512, K, nullptr, nullptr);
  };
  auto ffn1 = [&](const u16* Ap, const u16* Bp, const float* bi, u16* Op) {
    gemm_mfma<8, 2, 4, 1, 0, 1, 1, 0, 0, 0><<<dim3(64, 8), 512, 0, stream>>>(
        Ap, Bp, bi, nullptr, Op, 16384, 2048, 512, nullptr, nullptr);
  };

  // ---------------- encoder ----------------
  embed_kernel<<<8192, 256, 0, stream>>>(idx_enc, emb_enc, pe, yE);
  for (int l = 0; l < 6; ++l) {
    ln(yE, enc_ln_g + (l * 2 + 0) * 512, enc_ln_b + (l * 2 + 0) * 512, hA);
    g_bf16_sm(hA, tWqkvE + l * S3, qkvB, 1536);
    attn_kernel<<<512, 256, 0, stream>>>(qkvB, 1536, qkvB + 512, qkvB + 1024, 1536, atB, 0);
    proj_res(atB, tWoE + l * SQ, enc_bo + l * 512, yE, 512);
    ln(yE, enc_ln_g + (l * 2 + 1) * 512, enc_ln_b + (l * 2 + 1) * 512, hA);
    ffn1(hA, tW1E + l * SF, enc_b1 + l * 2048, midB);
    proj_res(midB, tW2E + l * SF, enc_b2 + l * 512, yE, 2048);
  }

  // ---------------- decoder ----------------
  embed_kernel<<<8192, 256, 0, stream>>>(idx, emb_dec, pe, xD);
  for (int l = 0; l < 6; ++l) {
    ln(xD, dec_ln_g + (l * 4 + 0) * 512, dec_ln_b + (l * 4 + 0) * 512, hA);
    g_bf16_sm(hA, tWqkvS + l * S3, qkvB, 1536);
    attn_kernel<<<512, 256, 0, stream>>>(qkvB, 1536, qkvB + 512, qkvB + 1024, 1536, atB, 1);
    proj_res(atB, tWoS + l * SQ, dbo_sa + l * 512, xD, 512);
    ln(xD, dec_ln_g + (l * 4 + 1) * 512, dec_ln_b + (l * 4 + 1) * 512, hA);
    ln(yE, dec_ln_g + (l * 4 + 2) * 512, dec_ln_b + (l * 4 + 2) * 512, hB);
    g_bf16_sm(hA, tWqX + l * SQ, qB, 512);
    g_bf16_sm(hB, tWkvX + l * S2, kvB, 1024);
    attn_kernel<<<512, 256, 0, stream>>>(qB, 512, kvB, kvB + 512, 1024, atB, 0);
    proj_res(atB, tWoX + l * SQ, dbo_xa + l * 512, xD, 512);
    ln(xD, dec_ln_g + (l * 4 + 3) * 512, dec_ln_b + (l * 4 + 3) * 512, hA);
    ffn1(hA, tW1D + l * SF, dec_b1 + l * 2048, midB);
    proj_res(midB, tW2D + l * SF, dec_b2 + l * 512, xD, 2048);
  }

  // -------- LM head (fused loss partials, nt logits, row-major XCD swizzle) --------
  ln(xD, lnf_g, lnf_b, hA);
  gemm_mfma<8, 2, 4, 1, 0, 0, 0, 1, 1, 1><<<dim3(64, 125), 512, 0, stream>>>(
      hA, tWlm, blm, nullptr, out_logits, 16384, 32000, 512, pmax, psum);
  loss_lse_kernel<<<4096, 256, 0, stream>>>(pmax, psum, out_logits, targets, rnll, rval);
  loss_final_kernel<<<1, 256, 0, stream>>>(rnll, rval, out_loss);
}

// Round 8
// 4918.040 us; speedup vs baseline: 1.2246x; 1.0154x over previous
//
#include <hip/hip_runtime.h>

typedef __attribute__((ext_vector_type(8))) short s8v;
typedef __attribute__((ext_vector_type(4))) float f4v;
using u16 = unsigned short;

__device__ __forceinline__ u16 f2bf(float f) {
  union { float f; unsigned u; } v; v.f = f;
  return (u16)((v.u + 0x7FFFu + ((v.u >> 16) & 1u)) >> 16);
}

// ---------------- positional encoding: pe[256][512] ----------------
__global__ __launch_bounds__(256) void pe_kernel(float* __restrict__ pe) {
  int i = blockIdx.x * 256 + threadIdx.x;
  int t = i >> 8, p = i & 255;
  float ex = (2.f * (float)p) / 512.f;
  float ang = (float)t * expf(-ex * 9.210340371976184f);
  pe[t * 512 + 2 * p]     = sinf(ang);
  pe[t * 512 + 2 * p + 1] = cosf(ang);
}

// -------- weight convert: f32 [R][C] -> bf16 [C][R], z-batched, dst stride --
__global__ __launch_bounds__(256) void wconv_kernel(const float* __restrict__ in,
    u16* __restrict__ out, int R, int C, size_t dstride) {
  __shared__ float tile[64][65];
  const size_t mat = (size_t)R * C;
  const float* src = in + (size_t)blockIdx.z * mat;
  u16* dst = out + (size_t)blockIdx.z * dstride;
  int r0 = blockIdx.x * 64, c0 = blockIdx.y * 64;
  int tr = threadIdx.x >> 6, tc = threadIdx.x & 63;
#pragma unroll
  for (int i = 0; i < 16; ++i)
    tile[i * 4 + tr][tc] = src[(size_t)(r0 + i * 4 + tr) * C + (c0 + tc)];
  __syncthreads();
#pragma unroll
  for (int i = 0; i < 16; ++i)
    dst[(size_t)(c0 + i * 4 + tr) * R + (r0 + tc)] = f2bf(tile[tc][i * 4 + tr]);
}

// ---------------- embedding + pe ----------------
__global__ __launch_bounds__(256) void embed_kernel(const int* __restrict__ idx,
    const float* __restrict__ emb, const float* __restrict__ pe, float* __restrict__ y) {
  int i = blockIdx.x * 256 + threadIdx.x;
  int row = i >> 7, c = (i & 127) * 4;
  int t = row & 255;
  int tok = idx[row];
  f4v e = *(const f4v*)(emb + (size_t)tok * 512 + c);
  f4v p = *(const f4v*)(pe + (size_t)t * 512 + c);
  *(f4v*)(y + (size_t)row * 512 + c) = e + p;
}

// ---------------- LayerNorm f32 -> bf16, wave per row ----------------
__global__ __launch_bounds__(256) void ln_kernel(const float* __restrict__ x,
    const float* __restrict__ g, const float* __restrict__ b, u16* __restrict__ out) {
  int row = blockIdx.x * 4 + (threadIdx.x >> 6);
  int lane = threadIdx.x & 63;
  const float* xr = x + (size_t)row * 512 + lane * 8;
  f4v v0 = *(const f4v*)xr;
  f4v v1 = *(const f4v*)(xr + 4);
  float s = v0[0] + v0[1] + v0[2] + v0[3] + v1[0] + v1[1] + v1[2] + v1[3];
#pragma unroll
  for (int o = 1; o < 64; o <<= 1) s += __shfl_xor(s, o);
  float mu = s * (1.f / 512.f);
  float q = 0.f;
#pragma unroll
  for (int j = 0; j < 4; ++j) {
    float d0 = v0[j] - mu; q += d0 * d0;
    float d1 = v1[j] - mu; q += d1 * d1;
  }
#pragma unroll
  for (int o = 1; o < 64; o <<= 1) q += __shfl_xor(q, o);
  float rs = rsqrtf(q * (1.f / 512.f) + 1e-5f);
  f4v g0 = *(const f4v*)(g + lane * 8), g1 = *(const f4v*)(g + lane * 8 + 4);
  f4v b0 = *(const f4v*)(b + lane * 8), b1 = *(const f4v*)(b + lane * 8 + 4);
  s8v ov;
#pragma unroll
  for (int j = 0; j < 4; ++j) {
    ov[j]     = (short)f2bf((v0[j] - mu) * rs * g0[j] + b0[j]);
    ov[4 + j] = (short)f2bf((v1[j] - mu) * rs * g1[j] + b1[j]);
  }
  *(s8v*)(out + (size_t)row * 512 + lane * 8) = ov;
}

// ======== GEMM: C[M,N] = A[M,K](bf16) @ Bt[N,K](bf16)^T ========
// m97-replica: 128x128 tile, BK=64, 4 waves (2Mx2N, 64x64 each),
// SINGLE-buffered 32KB LDS, two __syncthreads per K-step (compiler inserts
// waitcnts) -> ~4 blocks/CU; cross-block overlap hides the drain (m114).
// T2 XOR swizzle: linear LDS dest, pre-swizzled global slot, XOR'd ds_read.
// SWZM=0: bijective XCD-chunked. SWZM=1: row-panel-major per XCD (LM head).
template<int HAS_BIAS, int ADD_RES, int RELU, int OUT_BF16, int WLOSS, int NT, int SWZM>
__global__ __launch_bounds__(256, 4) void gemm128(
    const u16* __restrict__ A, const u16* __restrict__ Bt,
    const float* __restrict__ bias, const float* __restrict__ res,
    void* __restrict__ outp, int M, int N, int K,
    float* __restrict__ pmax, float* __restrict__ psum) {
  __shared__ __align__(16) u16 smem[2 * 128 * 64];   // As | Bs (32 KB)
  u16* As = smem;
  u16* Bs = smem + 128 * 64;
  const int tid = threadIdx.x, lane = tid & 63, w = tid >> 6;
  int bx, by;
  if (SWZM == 1) {
    int flat = blockIdx.y * gridDim.x + blockIdx.x;
    int xcd = flat & 7, local = flat >> 3;
    int p = local / gridDim.y;
    by = local - p * gridDim.y;
    bx = xcd * (gridDim.x >> 3) + p;
  } else {
    int nx = gridDim.x;
    int flat = blockIdx.y * nx + blockIdx.x;
    int per = (nx * gridDim.y) >> 3;
    int sw = (flat & 7) * per + (flat >> 3);
    by = sw / nx; bx = sw - by * nx;
  }
  const int m0 = bx * 128, n0 = by * 128;
  const int wm = (w >> 1) * 64, wn = (w & 1) * 64;
  const int lhi = lane >> 4, llo = lane & 15;
  const int srow = tid >> 3;                     // 0..31, staged rows/iter
  const int sl = tid & 7;                        // 16B slot within 128B row
  const int gcol = (sl ^ (srow & 7)) * 8;        // pre-swizzled global slot

  const u16* Ag = A + (size_t)(m0 + srow) * K + gcol;
  const u16* Bg = Bt + (size_t)(n0 + srow) * K + gcol;
  const size_t rstep = (size_t)32 * K;
  const int sx = llo & 7;

  f4v acc[4][4] = {};
  const int nk = K >> 6;
  for (int t = 0; t < nk; ++t) {
    const int kt = t * 64;
#pragma unroll
    for (int q = 0; q < 4; ++q)
      __builtin_amdgcn_global_load_lds(
          (const __attribute__((address_space(1))) void*)(Ag + q * rstep + kt),
          (__attribute__((address_space(3))) void*)(&As[(q * 32 + srow) * 64 + sl * 8]),
          16, 0, 0);
#pragma unroll
    for (int q = 0; q < 4; ++q)
      __builtin_amdgcn_global_load_lds(
          (const __attribute__((address_space(1))) void*)(Bg + q * rstep + kt),
          (__attribute__((address_space(3))) void*)(&Bs[(q * 32 + srow) * 64 + sl * 8]),
          16, 0, 0);
    __syncthreads();
#pragma unroll
    for (int kk = 0; kk < 2; ++kk) {
      s8v af[4], bfv[4];
#pragma unroll
      for (int i = 0; i < 4; ++i)
        af[i] = *(const s8v*)&As[(wm + i * 16 + llo) * 64 + (((kk * 4 + lhi) ^ sx) * 8)];
#pragma unroll
      for (int j = 0; j < 4; ++j)
        bfv[j] = *(const s8v*)&Bs[(wn + j * 16 + llo) * 64 + (((kk * 4 + lhi) ^ sx) * 8)];
#pragma unroll
      for (int i = 0; i < 4; ++i)
#pragma unroll
        for (int j = 0; j < 4; ++j)
          acc[i][j] = __builtin_amdgcn_mfma_f32_16x16x32_bf16(af[i], bfv[j], acc[i][j], 0, 0, 0);
    }
    __syncthreads();
  }

  // ---- epilogue (D row = (l>>4)*4 + r, col = l&15 — verified layout) ----
  if (OUT_BF16) {
    float bvj[4];
#pragma unroll
    for (int j = 0; j < 4; ++j)
      bvj[j] = HAS_BIAS ? bias[n0 + wn + j * 16 + llo] : 0.f;
#pragma unroll
    for (int i = 0; i < 4; ++i) {
#pragma unroll
      for (int j = 0; j < 4; ++j) {
        int col = n0 + wn + j * 16 + llo;
#pragma unroll
        for (int r = 0; r < 4; ++r) {
          int row = m0 + wm + i * 16 + lhi * 4 + r;
          float v = acc[i][j][r] + bvj[j];
          if (RELU) v = fmaxf(v, 0.f);
          ((u16*)outp)[(size_t)row * N + col] = f2bf(v);
        }
      }
    }
  } else {
    // transposed coalesced f32 path: wave-private LDS [16][68] f32
    float* lb = (float*)smem;
    float* wbuf = lb + w * 1088;          // 4 waves x 4352 B = 17408 B
    float* lbm = lb + 4608;               // 128 rows x 2 halves
    float* lbs = lb + 4864;
    f4v bias4 = {0.f, 0.f, 0.f, 0.f};
    if (HAS_BIAS) bias4 = *(const f4v*)(bias + n0 + wn + llo * 4);
#pragma unroll
    for (int i = 0; i < 4; ++i) {
#pragma unroll
      for (int j = 0; j < 4; ++j)
#pragma unroll
        for (int r = 0; r < 4; ++r)
          wbuf[(lhi * 4 + r) * 68 + j * 16 + llo] = acc[i][j][r];
      asm volatile("s_waitcnt lgkmcnt(0)" ::: "memory");
      __builtin_amdgcn_sched_barrier(0);
#pragma unroll
      for (int p = 0; p < 4; ++p) {
        int r16 = p * 4 + lhi;
        f4v v4 = *(const f4v*)&wbuf[r16 * 68 + llo * 4];
        v4 += bias4;
        int grow = m0 + wm + i * 16 + r16;
        int gcol4 = n0 + wn + llo * 4;
        if (ADD_RES) v4 += *(const f4v*)(res + (size_t)grow * N + gcol4);
        if (RELU) {
          v4[0] = fmaxf(v4[0], 0.f); v4[1] = fmaxf(v4[1], 0.f);
          v4[2] = fmaxf(v4[2], 0.f); v4[3] = fmaxf(v4[3], 0.f);
        }
        float* dst = (float*)outp + (size_t)grow * N + gcol4;
        if (NT) __builtin_nontemporal_store(v4, (f4v*)dst);
        else    *(f4v*)dst = v4;
        if (WLOSS) {
          float mx = fmaxf(fmaxf(v4[0], v4[1]), fmaxf(v4[2], v4[3]));
          mx = fmaxf(mx, __shfl_xor(mx, 1));
          mx = fmaxf(mx, __shfl_xor(mx, 2));
          mx = fmaxf(mx, __shfl_xor(mx, 4));
          mx = fmaxf(mx, __shfl_xor(mx, 8));
          float sum = __expf(v4[0] - mx) + __expf(v4[1] - mx)
                    + __expf(v4[2] - mx) + __expf(v4[3] - mx);
          sum += __shfl_xor(sum, 1); sum += __shfl_xor(sum, 2);
          sum += __shfl_xor(sum, 4); sum += __shfl_xor(sum, 8);
          if (llo == 0) {
            int lr = wm + i * 16 + r16;
            lbm[lr * 2 + (wn >> 6)] = mx;
            lbs[lr * 2 + (wn >> 6)] = sum;
          }
        }
      }
      asm volatile("s_waitcnt lgkmcnt(0)" ::: "memory");
      __builtin_amdgcn_sched_barrier(0);
    }
    if (WLOSS) {
      __syncthreads();
      if (tid < 128) {
        float ma = lbm[tid * 2], mb = lbm[tid * 2 + 1];
        float sa = lbs[tid * 2], sb = lbs[tid * 2 + 1];
        float m = fmaxf(ma, mb);
        float ss = sa * __expf(ma - m) + sb * __expf(mb - m);
        int ntile = N >> 7;
        pmax[(size_t)(m0 + tid) * ntile + by] = m;
        psum[(size_t)(m0 + tid) * ntile + by] = ss;
      }
    }
  }
}

// -------- fused attention, one (b,h) per block, T=256, hd=64, strided QKV ----
__global__ __launch_bounds__(256) void attn_kernel(
    const u16* __restrict__ Qp, int qs, const u16* __restrict__ Kp,
    const u16* __restrict__ Vp, int kvs, u16* __restrict__ Ob, int causal) {
  __shared__ __align__(16) u16 Ks[256][72];
  __shared__ __align__(16) u16 Vt[64][264];
  __shared__ __align__(16) u16 Ps[4][16][264];
  const int tid = threadIdx.x, lane = tid & 63, w = tid >> 6;
  const int b = blockIdx.x >> 3, h = blockIdx.x & 7;
  const size_t qbase  = (size_t)b * 256 * qs  + (size_t)h * 64;
  const size_t kvbase = (size_t)b * 256 * kvs + (size_t)h * 64;
  const size_t obase  = (size_t)b * 256 * 512 + (size_t)h * 64;
  {
    int t0 = tid >> 3, d0 = (tid & 7) * 8;
#pragma unroll
    for (int it = 0; it < 8; ++it) {
      int t = it * 32 + t0;
      s8v kv = *(const s8v*)(Kp + kvbase + (size_t)t * kvs + d0);
      *(s8v*)&Ks[t][d0] = kv;
      s8v vv = *(const s8v*)(Vp + kvbase + (size_t)t * kvs + d0);
#pragma unroll
      for (int j = 0; j < 8; ++j) Vt[d0 + j][t] = (u16)vv[j];
    }
  }
  __syncthreads();
  const int lhi = lane >> 4, llo = lane & 15;
  for (int qc = 0; qc < 4; ++qc) {
    const int qr0 = w * 64 + qc * 16;
    s8v aq0 = *(const s8v*)(Qp + qbase + (size_t)(qr0 + llo) * qs + lhi * 8);
    s8v aq1 = *(const s8v*)(Qp + qbase + (size_t)(qr0 + llo) * qs + 32 + lhi * 8);
    f4v S[16];
#pragma unroll
    for (int c = 0; c < 16; ++c) {
      s8v bk0 = *(const s8v*)&Ks[c * 16 + llo][lhi * 8];
      s8v bk1 = *(const s8v*)&Ks[c * 16 + llo][32 + lhi * 8];
      f4v z = {0.f, 0.f, 0.f, 0.f};
      z = __builtin_amdgcn_mfma_f32_16x16x32_bf16(aq0, bk0, z, 0, 0, 0);
      S[c] = __builtin_amdgcn_mfma_f32_16x16x32_bf16(aq1, bk1, z, 0, 0, 0);
    }
#pragma unroll
    for (int r = 0; r < 4; ++r) {
      const int tq = qr0 + lhi * 4 + r;
      float mx = -1e30f;
#pragma unroll
      for (int c = 0; c < 16; ++c) {
        float s = S[c][r] * 0.125f;
        if (causal && (c * 16 + llo) > tq) s = -1e30f;
        S[c][r] = s;
        mx = fmaxf(mx, s);
      }
      mx = fmaxf(mx, __shfl_xor(mx, 1));
      mx = fmaxf(mx, __shfl_xor(mx, 2));
      mx = fmaxf(mx, __shfl_xor(mx, 4));
      mx = fmaxf(mx, __shfl_xor(mx, 8));
      float sum = 0.f;
#pragma unroll
      for (int c = 0; c < 16; ++c) { float p = __expf(S[c][r] - mx); S[c][r] = p; sum += p; }
      sum += __shfl_xor(sum, 1); sum += __shfl_xor(sum, 2);
      sum += __shfl_xor(sum, 4); sum += __shfl_xor(sum, 8);
      float inv = 1.f / sum;
#pragma unroll
      for (int c = 0; c < 16; ++c)
        Ps[w][lhi * 4 + r][c * 16 + llo] = f2bf(S[c][r] * inv);
    }
    asm volatile("s_waitcnt lgkmcnt(0)" ::: "memory");
    f4v o[4] = {};
#pragma unroll
    for (int kb = 0; kb < 8; ++kb) {
      s8v pa = *(const s8v*)&Ps[w][llo][kb * 32 + lhi * 8];
#pragma unroll
      for (int nb = 0; nb < 4; ++nb) {
        s8v bv = *(const s8v*)&Vt[nb * 16 + llo][kb * 32 + lhi * 8];
        o[nb] = __builtin_amdgcn_mfma_f32_16x16x32_bf16(pa, bv, o[nb], 0, 0, 0);
      }
    }
#pragma unroll
    for (int nb = 0; nb < 4; ++nb)
#pragma unroll
      for (int r = 0; r < 4; ++r)
        Ob[obase + (size_t)(qr0 + lhi * 4 + r) * 512 + nb * 16 + llo] = f2bf(o[nb][r]);
  }
}

// ---------------- loss: merge per-tile partials -> per-row nll ----------------
__global__ __launch_bounds__(256) void loss_lse_kernel(const float* __restrict__ pmax,
    const float* __restrict__ psum, const float* __restrict__ logits,
    const int* __restrict__ tgt, float* __restrict__ nll, float* __restrict__ valid) {
  const int w = threadIdx.x >> 6, lane = threadIdx.x & 63;
  const int row = blockIdx.x * 4 + w;
  float m = -1e30f, s = 0.f;
  for (int e = lane; e < 250; e += 64) {
    float pm = pmax[(size_t)row * 250 + e], ps = psum[(size_t)row * 250 + e];
    if (pm > m) { s = s * __expf(m - pm) + ps; m = pm; }
    else          s += ps * __expf(pm - m);
  }
#pragma unroll
  for (int o = 1; o < 64; o <<= 1) {
    float om = __shfl_xor(m, o), os = __shfl_xor(s, o);
    float mm = fmaxf(m, om);
    s = s * __expf(m - mm) + os * __expf(om - mm);
    m = mm;
  }
  if (lane == 0) {
    int t = tgt[row];
    float lse = m + logf(s);
    float v = (t != 1) ? 1.f : 0.f;
    nll[row] = v * (lse - logits[(size_t)row * 32000 + t]);
    valid[row] = v;
  }
}

__global__ __launch_bounds__(256) void loss_final_kernel(const float* __restrict__ nll,
    const float* __restrict__ valid, float* __restrict__ out) {
  __shared__ float sa[256], sb[256];
  int tid = threadIdx.x;
  float s = 0.f, c = 0.f;
  for (int i = tid; i < 16384; i += 256) { s += nll[i]; c += valid[i]; }
  sa[tid] = s; sb[tid] = c;
  __syncthreads();
  for (int st = 128; st > 0; st >>= 1) {
    if (tid < st) { sa[tid] += sa[tid + st]; sb[tid] += sb[tid + st]; }
    __syncthreads();
  }
  if (tid == 0) out[0] = sa[0] / fmaxf(sb[0], 1.f);
}

// =============================== host ===============================
extern "C" void kernel_launch(void* const* d_in, const int* in_sizes, int n_in,
                              void* d_out, int out_size, void* d_ws, size_t ws_size,
                              hipStream_t stream) {
  (void)in_sizes; (void)n_in; (void)out_size; (void)ws_size;
  const int* idx       = (const int*)d_in[0];
  const int* idx_enc   = (const int*)d_in[1];
  const int* targets   = (const int*)d_in[2];
  const float* emb_dec = (const float*)d_in[3];
  const float* emb_enc = (const float*)d_in[4];
  const float* enc_Wq  = (const float*)d_in[5];
  const float* enc_Wk  = (const float*)d_in[6];
  const float* enc_Wv  = (const float*)d_in[7];
  const float* enc_Wo  = (const float*)d_in[8];
  const float* enc_bo  = (const float*)d_in[9];
  const float* enc_ln_g = (const float*)d_in[10];
  const float* enc_ln_b = (const float*)d_in[11];
  const float* enc_W1  = (const float*)d_in[12];
  const float* enc_b1  = (const float*)d_in[13];
  const float* enc_W2  = (const float*)d_in[14];
  const float* enc_b2  = (const float*)d_in[15];
  const float* dWq_sa  = (const float*)d_in[16];
  const float* dWk_sa  = (const float*)d_in[17];
  const float* dWv_sa  = (const float*)d_in[18];
  const float* dWo_sa  = (const float*)d_in[19];
  const float* dbo_sa  = (const float*)d_in[20];
  const float* dWq_xa  = (const float*)d_in[21];
  const float* dWk_xa  = (const float*)d_in[22];
  const float* dWv_xa  = (const float*)d_in[23];
  const float* dWo_xa  = (const float*)d_in[24];
  const float* dbo_xa  = (const float*)d_in[25];
  const float* dec_ln_g = (const float*)d_in[26];
  const float* dec_ln_b = (const float*)d_in[27];
  const float* dec_W1  = (const float*)d_in[28];
  const float* dec_b1  = (const float*)d_in[29];
  const float* dec_W2  = (const float*)d_in[30];
  const float* dec_b2  = (const float*)d_in[31];
  const float* lnf_g   = (const float*)d_in[32];
  const float* lnf_b   = (const float*)d_in[33];
  const float* Wlm     = (const float*)d_in[34];
  const float* blm     = (const float*)d_in[35];
  float* out_logits = (float*)d_out;
  float* out_loss   = out_logits + (size_t)16384 * 32000;

  size_t off = 0;
  auto alloc = [&](size_t bytes) -> char* {
    char* p = (char*)d_ws + off;
    off += (bytes + 255) & ~(size_t)255;
    return p;
  };
  const size_t SQ = 512 * 512, SF = 512 * 2048;
  u16* tWqkvE = (u16*)alloc(6 * 3 * SQ * 2);
  u16* tWoE   = (u16*)alloc(6 * SQ * 2);
  u16* tW1E   = (u16*)alloc(6 * SF * 2);
  u16* tW2E   = (u16*)alloc(6 * SF * 2);
  u16* tWqkvS = (u16*)alloc(6 * 3 * SQ * 2);
  u16* tWoS   = (u16*)alloc(6 * SQ * 2);
  u16* tWqX   = (u16*)alloc(6 * SQ * 2);
  u16* tWkvX  = (u16*)alloc(6 * 2 * SQ * 2);
  u16* tWoX   = (u16*)alloc(6 * SQ * 2);
  u16* tW1D   = (u16*)alloc(6 * SF * 2);
  u16* tW2D   = (u16*)alloc(6 * SF * 2);
  u16* tWlm   = (u16*)alloc((size_t)32000 * 512 * 2);
  float* pe   = (float*)alloc(256 * 512 * 4);
  float* yE   = (float*)alloc((size_t)16384 * 512 * 4);
  float* xD   = (float*)alloc((size_t)16384 * 512 * 4);
  u16* hA     = (u16*)alloc((size_t)16384 * 512 * 2);
  u16* hB     = (u16*)alloc((size_t)16384 * 512 * 2);
  u16* qkvB   = (u16*)alloc((size_t)16384 * 1536 * 2);
  u16* qB     = (u16*)alloc((size_t)16384 * 512 * 2);
  u16* kvB    = (u16*)alloc((size_t)16384 * 1024 * 2);
  u16* atB    = (u16*)alloc((size_t)16384 * 512 * 2);
  u16* midB   = (u16*)alloc((size_t)16384 * 2048 * 2);
  float* pmax = (float*)alloc((size_t)16384 * 250 * 4);
  float* psum = (float*)alloc((size_t)16384 * 250 * 4);
  float* rnll = (float*)alloc(16384 * 4);
  float* rval = (float*)alloc(16384 * 4);

  // ---- weight conversion (every call; deterministic) ----
  dim3 tb(256);
  const size_t S3 = 3 * SQ, S2 = 2 * SQ;
  wconv_kernel<<<dim3(8, 8, 6), tb, 0, stream>>>(enc_Wq, tWqkvE + 0 * SQ, 512, 512, S3);
  wconv_kernel<<<dim3(8, 8, 6), tb, 0, stream>>>(enc_Wk, tWqkvE + 1 * SQ, 512, 512, S3);
  wconv_kernel<<<dim3(8, 8, 6), tb, 0, stream>>>(enc_Wv, tWqkvE + 2 * SQ, 512, 512, S3);
  wconv_kernel<<<dim3(8, 8, 6), tb, 0, stream>>>(enc_Wo, tWoE, 512, 512, SQ);
  wconv_kernel<<<dim3(8, 32, 6), tb, 0, stream>>>(enc_W1, tW1E, 512, 2048, SF);
  wconv_kernel<<<dim3(32, 8, 6), tb, 0, stream>>>(enc_W2, tW2E, 2048, 512, SF);
  wconv_kernel<<<dim3(8, 8, 6), tb, 0, stream>>>(dWq_sa, tWqkvS + 0 * SQ, 512, 512, S3);
  wconv_kernel<<<dim3(8, 8, 6), tb, 0, stream>>>(dWk_sa, tWqkvS + 1 * SQ, 512, 512, S3);
  wconv_kernel<<<dim3(8, 8, 6), tb, 0, stream>>>(dWv_sa, tWqkvS + 2 * SQ, 512, 512, S3);
  wconv_kernel<<<dim3(8, 8, 6), tb, 0, stream>>>(dWo_sa, tWoS, 512, 512, SQ);
  wconv_kernel<<<dim3(8, 8, 6), tb, 0, stream>>>(dWq_xa, tWqX, 512, 512, SQ);
  wconv_kernel<<<dim3(8, 8, 6), tb, 0, stream>>>(dWk_xa, tWkvX + 0 * SQ, 512, 512, S2);
  wconv_kernel<<<dim3(8, 8, 6), tb, 0, stream>>>(dWv_xa, tWkvX + 1 * SQ, 512, 512, S2);
  wconv_kernel<<<dim3(8, 8, 6), tb, 0, stream>>>(dWo_xa, tWoX, 512, 512, SQ);
  wconv_kernel<<<dim3(8, 32, 6), tb, 0, stream>>>(dec_W1, tW1D, 512, 2048, SF);
  wconv_kernel<<<dim3(32, 8, 6), tb, 0, stream>>>(dec_W2, tW2D, 2048, 512, SF);
  wconv_kernel<<<dim3(8, 500, 1), tb, 0, stream>>>(Wlm, tWlm, 512, 32000, (size_t)0);
  pe_kernel<<<256, 256, 0, stream>>>(pe);

  auto ln = [&](const float* xin, const float* g, const float* bb, u16* o) {
    ln_kernel<<<4096, 256, 0, stream>>>(xin, g, bb, o);
  };
  auto g_bf16 = [&](const u16* Ap, const u16* Bp, u16* Op, int N) {
    gemm128<0, 0, 0, 1, 0, 0, 0><<<dim3(128, N / 128), 256, 0, stream>>>(
        Ap, Bp, nullptr, nullptr, Op, 16384, N, 512, nullptr, nullptr);
  };
  auto proj_res = [&](const u16* Ap, const u16* Bp, const float* bi, float* xr, int K) {
    gemm128<1, 1, 0, 0, 0, 0, 0><<<dim3(128, 4), 256, 0, stream>>>(
        Ap, Bp, bi, xr, xr, 16384, 512, K, nullptr, nullptr);
  };
  auto ffn1 = [&](const u16* Ap, const u16* Bp, const float* bi, u16* Op) {
    gemm128<1, 0, 1, 1, 0, 0, 0><<<dim3(128, 16), 256, 0, stream>>>(
        Ap, Bp, bi, nullptr, Op, 16384, 2048, 512, nullptr, nullptr);
  };

  // ---------------- encoder ----------------
  embed_kernel<<<8192, 256, 0, stream>>>(idx_enc, emb_enc, pe, yE);
  for (int l = 0; l < 6; ++l) {
    ln(yE, enc_ln_g + (l * 2 + 0) * 512, enc_ln_b + (l * 2 + 0) * 512, hA);
    g_bf16(hA, tWqkvE + l * S3, qkvB, 1536);
    attn_kernel<<<512, 256, 0, stream>>>(qkvB, 1536, qkvB + 512, qkvB + 1024, 1536, atB, 0);
    proj_res(atB, tWoE + l * SQ, enc_bo + l * 512, yE, 512);
    ln(yE, enc_ln_g + (l * 2 + 1) * 512, enc_ln_b + (l * 2 + 1) * 512, hA);
    ffn1(hA, tW1E + l * SF, enc_b1 + l * 2048, midB);
    proj_res(midB, tW2E + l * SF, enc_b2 + l * 512, yE, 2048);
  }

  // ---------------- decoder ----------------
  embed_kernel<<<8192, 256, 0, stream>>>(idx, emb_dec, pe, xD);
  for (int l = 0; l < 6; ++l) {
    ln(xD, dec_ln_g + (l * 4 + 0) * 512, dec_ln_b + (l * 4 + 0) * 512, hA);
    g_bf16(hA, tWqkvS + l * S3, qkvB, 1536);
    attn_kernel<<<512, 256, 0, stream>>>(qkvB, 1536, qkvB + 512, qkvB + 1024, 1536, atB, 1);
    proj_res(atB, tWoS + l * SQ, dbo_sa + l * 512, xD, 512);
    ln(xD, dec_ln_g + (l * 4 + 1) * 512, dec_ln_b + (l * 4 + 1) * 512, hA);
    ln(yE, dec_ln_g + (l * 4 + 2) * 512, dec_ln_b + (l * 4 + 2) * 512, hB);
    g_bf16(hA, tWqX + l * SQ, qB, 512);
    g_bf16(hB, tWkvX + l * S2, kvB, 1024);
    attn_kernel<<<512, 256, 0, stream>>>(qB, 512, kvB, kvB + 512, 1024, atB, 0);
    proj_res(atB, tWoX + l * SQ, dbo_xa + l * 512, xD, 512);
    ln(xD, dec_ln_g + (l * 4 + 3) * 512, dec_ln_b + (l * 4 + 3) * 512, hA);
    ffn1(hA, tW1D + l * SF, dec_b1 + l * 2048, midB);
    proj_res(midB, tW2D + l * SF, dec_b2 + l * 512, xD, 2048);
  }

  // -------- LM head (fused loss partials, nt logits, row-panel XCD swizzle) --------
  ln(xD, lnf_g, lnf_b, hA);
  gemm128<1, 0, 0, 0, 1, 1, 1><<<dim3(128, 250), 256, 0, stream>>>(
      hA, tWlm, blm, nullptr, out_logits, 16384, 32000, 512, pmax, psum);
  loss_lse_kernel<<<4096, 256, 0, stream>>>(pmax, psum, out_logits, targets, rnll, rval);
  loss_final_kernel<<<1, 256, 0, stream>>>(rnll, rval, out_loss);
}

// Round 9
// 4836.456 us; speedup vs baseline: 1.2453x; 1.0169x over previous
//
#include <hip/hip_runtime.h>

typedef __attribute__((ext_vector_type(8))) short s8v;
typedef __attribute__((ext_vector_type(4))) float f4v;
using u16 = unsigned short;

__device__ __forceinline__ u16 f2bf(float f) {
  union { float f; unsigned u; } v; v.f = f;
  return (u16)((v.u + 0x7FFFu + ((v.u >> 16) & 1u)) >> 16);
}

// ---------------- positional encoding: pe[256][512] ----------------
__global__ __launch_bounds__(256) void pe_kernel(float* __restrict__ pe) {
  int i = blockIdx.x * 256 + threadIdx.x;
  int t = i >> 8, p = i & 255;
  float ex = (2.f * (float)p) / 512.f;
  float ang = (float)t * expf(-ex * 9.210340371976184f);
  pe[t * 512 + 2 * p]     = sinf(ang);
  pe[t * 512 + 2 * p + 1] = cosf(ang);
}

// -------- weight convert: f32 [R][C] -> bf16 [C][R] --------
__global__ __launch_bounds__(256) void wconv_kernel(const float* __restrict__ in,
    u16* __restrict__ out, int R, int C, size_t dstride) {
  __shared__ float tile[64][65];
  const size_t mat = (size_t)R * C;
  const float* src = in + (size_t)blockIdx.z * mat;
  u16* dst = out + (size_t)blockIdx.z * dstride;
  int r0 = blockIdx.x * 64, c0 = blockIdx.y * 64;
  int tr = threadIdx.x >> 6, tc = threadIdx.x & 63;
#pragma unroll
  for (int i = 0; i < 16; ++i)
    tile[i * 4 + tr][tc] = src[(size_t)(r0 + i * 4 + tr) * C + (c0 + tc)];
  __syncthreads();
#pragma unroll
  for (int i = 0; i < 16; ++i)
    dst[(size_t)(c0 + i * 4 + tr) * R + (r0 + tc)] = f2bf(tile[tc][i * 4 + tr]);
}

// -------- batched square (512x512) weight convert: 12 stacks in one launch ----
struct WcSq { const float* src[12]; u16* dst[12]; unsigned long long dstr[12]; };
__global__ __launch_bounds__(256) void wconv_sq_kernel(WcSq S) {
  __shared__ float tile[64][65];
  int mm = blockIdx.z / 6, l = blockIdx.z % 6;
  const float* src = S.src[mm] + (size_t)l * 512 * 512;
  u16* dst = S.dst[mm] + (size_t)l * S.dstr[mm];
  int r0 = blockIdx.x * 64, c0 = blockIdx.y * 64;
  int tr = threadIdx.x >> 6, tc = threadIdx.x & 63;
#pragma unroll
  for (int i = 0; i < 16; ++i)
    tile[i * 4 + tr][tc] = src[(size_t)(r0 + i * 4 + tr) * 512 + (c0 + tc)];
  __syncthreads();
#pragma unroll
  for (int i = 0; i < 16; ++i)
    dst[(size_t)(c0 + i * 4 + tr) * 512 + (r0 + tc)] = f2bf(tile[tc][i * 4 + tr]);
}

// -------- LN body (wave per row) --------
__device__ __forceinline__ void ln_row(f4v v0, f4v v1, const float* g, const float* b,
                                       int lane, u16* outrow) {
  float s = v0[0] + v0[1] + v0[2] + v0[3] + v1[0] + v1[1] + v1[2] + v1[3];
#pragma unroll
  for (int o = 1; o < 64; o <<= 1) s += __shfl_xor(s, o);
  float mu = s * (1.f / 512.f);
  float q = 0.f;
#pragma unroll
  for (int j = 0; j < 4; ++j) {
    float d0 = v0[j] - mu; q += d0 * d0;
    float d1 = v1[j] - mu; q += d1 * d1;
  }
#pragma unroll
  for (int o = 1; o < 64; o <<= 1) q += __shfl_xor(q, o);
  float rs = rsqrtf(q * (1.f / 512.f) + 1e-5f);
  f4v g0 = *(const f4v*)(g + lane * 8), g1 = *(const f4v*)(g + lane * 8 + 4);
  f4v b0 = *(const f4v*)(b + lane * 8), b1 = *(const f4v*)(b + lane * 8 + 4);
  s8v ov;
#pragma unroll
  for (int j = 0; j < 4; ++j) {
    ov[j]     = (short)f2bf((v0[j] - mu) * rs * g0[j] + b0[j]);
    ov[4 + j] = (short)f2bf((v1[j] - mu) * rs * g1[j] + b1[j]);
  }
  *(s8v*)(outrow + lane * 8) = ov;
}

// ---------------- LayerNorm f32 -> bf16, wave per row ----------------
__global__ __launch_bounds__(256) void ln_kernel(const float* __restrict__ x,
    const float* __restrict__ g, const float* __restrict__ b, u16* __restrict__ out) {
  int row = blockIdx.x * 4 + (threadIdx.x >> 6);
  int lane = threadIdx.x & 63;
  const float* xr = x + (size_t)row * 512 + lane * 8;
  ln_row(*(const f4v*)xr, *(const f4v*)(xr + 4), g, b, lane, out + (size_t)row * 512);
}

// -------- dual LN: rows<16384 -> (x1,g1,b1,o1); else (x2,g2,b2,o2) --------
__global__ __launch_bounds__(256) void ln2_kernel(
    const float* __restrict__ x1, const float* __restrict__ g1, const float* __restrict__ b1,
    u16* __restrict__ o1, const float* __restrict__ x2, const float* __restrict__ g2,
    const float* __restrict__ b2, u16* __restrict__ o2) {
  int row = blockIdx.x * 4 + (threadIdx.x >> 6);
  int lane = threadIdx.x & 63;
  const float* x = x1; const float* g = g1; const float* b = b1; u16* o = o1;
  if (row >= 16384) { row -= 16384; x = x2; g = g2; b = b2; o = o2; }
  const float* xr = x + (size_t)row * 512 + lane * 8;
  ln_row(*(const f4v*)xr, *(const f4v*)(xr + 4), g, b, lane, o + (size_t)row * 512);
}

// -------- fused embedding + pe + layer-0 LN: writes y (f32) and h (bf16) ------
__global__ __launch_bounds__(256) void emb_ln_kernel(const int* __restrict__ idx,
    const float* __restrict__ emb, const float* __restrict__ pe,
    const float* __restrict__ g, const float* __restrict__ b,
    float* __restrict__ y, u16* __restrict__ h) {
  int row = blockIdx.x * 4 + (threadIdx.x >> 6);
  int lane = threadIdx.x & 63;
  int tok = idx[row], t = row & 255;
  const float* e = emb + (size_t)tok * 512 + lane * 8;
  const float* p = pe + (size_t)t * 512 + lane * 8;
  f4v v0 = *(const f4v*)e + *(const f4v*)p;
  f4v v1 = *(const f4v*)(e + 4) + *(const f4v*)(p + 4);
  float* yr = y + (size_t)row * 512 + lane * 8;
  *(f4v*)yr = v0; *(f4v*)(yr + 4) = v1;
  ln_row(v0, v1, g, b, lane, h + (size_t)row * 512);
}

// ======== GEMM: C[M,N] = A[M,K](bf16) @ Bt[N,K](bf16)^T ========
// m97-replica: 128x128 tile, BK=64, 4 waves, single-buffered 32KB LDS,
// T2 XOR swizzle. SWZM=0: XCD-chunked; SWZM=1: row-panel-major per XCD.
// DUAL: grid (128, 4+8): by<4 -> (A,Bt,outp,N); else (A2,Bt2,out2,1024).
template<int HAS_BIAS, int ADD_RES, int RELU, int OUT_BF16, int WLOSS, int NT,
         int SWZM, int DUAL>
__global__ __launch_bounds__(256, 4) void gemm128(
    const u16* __restrict__ A, const u16* __restrict__ Bt,
    const float* __restrict__ bias, const float* __restrict__ res,
    void* __restrict__ outp, int M, int N, int K,
    float* __restrict__ pmax, float* __restrict__ psum,
    const u16* __restrict__ A2, const u16* __restrict__ Bt2,
    void* __restrict__ out2) {
  __shared__ __align__(16) u16 smem[2 * 128 * 64];   // As | Bs (32 KB)
  u16* As = smem;
  u16* Bs = smem + 128 * 64;
  const int tid = threadIdx.x, lane = tid & 63, w = tid >> 6;
  int bx, by;
  if (SWZM == 1) {
    int flat = blockIdx.y * gridDim.x + blockIdx.x;
    int xcd = flat & 7, local = flat >> 3;
    int p = local / gridDim.y;
    by = local - p * gridDim.y;
    bx = xcd * (gridDim.x >> 3) + p;
  } else {
    int nx = gridDim.x;
    int flat = blockIdx.y * nx + blockIdx.x;
    int per = (nx * gridDim.y) >> 3;
    int sw = (flat & 7) * per + (flat >> 3);
    by = sw / nx; bx = sw - by * nx;
  }
  if (DUAL && by >= 4) { A = A2; Bt = Bt2; outp = out2; N = 1024; by -= 4; }
  const int m0 = bx * 128, n0 = by * 128;
  const int wm = (w >> 1) * 64, wn = (w & 1) * 64;
  const int lhi = lane >> 4, llo = lane & 15;
  const int srow = tid >> 3;
  const int sl = tid & 7;
  const int gcol = (sl ^ (srow & 7)) * 8;

  const u16* Ag = A + (size_t)(m0 + srow) * K + gcol;
  const u16* Bg = Bt + (size_t)(n0 + srow) * K + gcol;
  const size_t rstep = (size_t)32 * K;
  const int sx = llo & 7;

  f4v acc[4][4] = {};
  const int nk = K >> 6;
  for (int t = 0; t < nk; ++t) {
    const int kt = t * 64;
#pragma unroll
    for (int q = 0; q < 4; ++q)
      __builtin_amdgcn_global_load_lds(
          (const __attribute__((address_space(1))) void*)(Ag + q * rstep + kt),
          (__attribute__((address_space(3))) void*)(&As[(q * 32 + srow) * 64 + sl * 8]),
          16, 0, 0);
#pragma unroll
    for (int q = 0; q < 4; ++q)
      __builtin_amdgcn_global_load_lds(
          (const __attribute__((address_space(1))) void*)(Bg + q * rstep + kt),
          (__attribute__((address_space(3))) void*)(&Bs[(q * 32 + srow) * 64 + sl * 8]),
          16, 0, 0);
    __syncthreads();
#pragma unroll
    for (int kk = 0; kk < 2; ++kk) {
      s8v af[4], bfv[4];
#pragma unroll
      for (int i = 0; i < 4; ++i)
        af[i] = *(const s8v*)&As[(wm + i * 16 + llo) * 64 + (((kk * 4 + lhi) ^ sx) * 8)];
#pragma unroll
      for (int j = 0; j < 4; ++j)
        bfv[j] = *(const s8v*)&Bs[(wn + j * 16 + llo) * 64 + (((kk * 4 + lhi) ^ sx) * 8)];
#pragma unroll
      for (int i = 0; i < 4; ++i)
#pragma unroll
        for (int j = 0; j < 4; ++j)
          acc[i][j] = __builtin_amdgcn_mfma_f32_16x16x32_bf16(af[i], bfv[j], acc[i][j], 0, 0, 0);
    }
    __syncthreads();
  }

  // ---- epilogue (D row = (l>>4)*4 + r, col = l&15 — verified layout) ----
  if (OUT_BF16) {
    float bvj[4];
#pragma unroll
    for (int j = 0; j < 4; ++j)
      bvj[j] = HAS_BIAS ? bias[n0 + wn + j * 16 + llo] : 0.f;
#pragma unroll
    for (int i = 0; i < 4; ++i) {
#pragma unroll
      for (int j = 0; j < 4; ++j) {
        int col = n0 + wn + j * 16 + llo;
#pragma unroll
        for (int r = 0; r < 4; ++r) {
          int row = m0 + wm + i * 16 + lhi * 4 + r;
          float v = acc[i][j][r] + bvj[j];
          if (RELU) v = fmaxf(v, 0.f);
          ((u16*)outp)[(size_t)row * N + col] = f2bf(v);
        }
      }
    }
  } else {
    float* lb = (float*)smem;
    float* wbuf = lb + w * 1088;
    float* lbm = lb + 4608;
    float* lbs = lb + 4864;
    f4v bias4 = {0.f, 0.f, 0.f, 0.f};
    if (HAS_BIAS) bias4 = *(const f4v*)(bias + n0 + wn + llo * 4);
#pragma unroll
    for (int i = 0; i < 4; ++i) {
#pragma unroll
      for (int j = 0; j < 4; ++j)
#pragma unroll
        for (int r = 0; r < 4; ++r)
          wbuf[(lhi * 4 + r) * 68 + j * 16 + llo] = acc[i][j][r];
      asm volatile("s_waitcnt lgkmcnt(0)" ::: "memory");
      __builtin_amdgcn_sched_barrier(0);
#pragma unroll
      for (int p = 0; p < 4; ++p) {
        int r16 = p * 4 + lhi;
        f4v v4 = *(const f4v*)&wbuf[r16 * 68 + llo * 4];
        v4 += bias4;
        int grow = m0 + wm + i * 16 + r16;
        int gcol4 = n0 + wn + llo * 4;
        if (ADD_RES) v4 += *(const f4v*)(res + (size_t)grow * N + gcol4);
        if (RELU) {
          v4[0] = fmaxf(v4[0], 0.f); v4[1] = fmaxf(v4[1], 0.f);
          v4[2] = fmaxf(v4[2], 0.f); v4[3] = fmaxf(v4[3], 0.f);
        }
        float* dst = (float*)outp + (size_t)grow * N + gcol4;
        if (NT) __builtin_nontemporal_store(v4, (f4v*)dst);
        else    *(f4v*)dst = v4;
        if (WLOSS) {
          float mx = fmaxf(fmaxf(v4[0], v4[1]), fmaxf(v4[2], v4[3]));
          mx = fmaxf(mx, __shfl_xor(mx, 1));
          mx = fmaxf(mx, __shfl_xor(mx, 2));
          mx = fmaxf(mx, __shfl_xor(mx, 4));
          mx = fmaxf(mx, __shfl_xor(mx, 8));
          float sum = __expf(v4[0] - mx) + __expf(v4[1] - mx)
                    + __expf(v4[2] - mx) + __expf(v4[3] - mx);
          sum += __shfl_xor(sum, 1); sum += __shfl_xor(sum, 2);
          sum += __shfl_xor(sum, 4); sum += __shfl_xor(sum, 8);
          if (llo == 0) {
            int lr = wm + i * 16 + r16;
            lbm[lr * 2 + (wn >> 6)] = mx;
            lbs[lr * 2 + (wn >> 6)] = sum;
          }
        }
      }
      asm volatile("s_waitcnt lgkmcnt(0)" ::: "memory");
      __builtin_amdgcn_sched_barrier(0);
    }
    if (WLOSS) {
      __syncthreads();
      if (tid < 128) {
        float ma = lbm[tid * 2], mb = lbm[tid * 2 + 1];
        float sa = lbs[tid * 2], sb = lbs[tid * 2 + 1];
        float m = fmaxf(ma, mb);
        float ss = sa * __expf(ma - m) + sb * __expf(mb - m);
        int ntile = N >> 7;
        pmax[(size_t)(m0 + tid) * ntile + by] = m;
        psum[(size_t)(m0 + tid) * ntile + by] = ss;
      }
    }
  }
}

// ======== flash-tile attention: one (b,h)/block, T=256, hd=64 ========
// K/V tiled in 4 x 64 rows, online softmax (running m,l; deferred divide).
// LDS ~27 KB -> 2+ blocks/CU (was 102 KB -> 1).
__global__ __launch_bounds__(256, 2) void attn_kernel(
    const u16* __restrict__ Qp, int qs, const u16* __restrict__ Kp,
    const u16* __restrict__ Vp, int kvs, u16* __restrict__ Ob, int causal) {
  __shared__ __align__(16) u16 Ks[64][72];
  __shared__ __align__(16) u16 Vt[64][66];
  __shared__ __align__(16) u16 Ps[4][16][66];
  const int tid = threadIdx.x, lane = tid & 63, w = tid >> 6;
  const int b = blockIdx.x >> 3, h = blockIdx.x & 7;
  const size_t qbase  = (size_t)b * 256 * qs  + (size_t)h * 64;
  const size_t kvbase = (size_t)b * 256 * kvs + (size_t)h * 64;
  const size_t obase  = (size_t)b * 256 * 512 + (size_t)h * 64;
  const int lhi = lane >> 4, llo = lane & 15;
  // preload Q fragments: wave w owns q-rows [w*64, w*64+64)
  s8v aq0[4], aq1[4];
#pragma unroll
  for (int qc = 0; qc < 4; ++qc) {
    const u16* qp = Qp + qbase + (size_t)(w * 64 + qc * 16 + llo) * qs;
    aq0[qc] = *(const s8v*)(qp + lhi * 8);
    aq1[qc] = *(const s8v*)(qp + 32 + lhi * 8);
  }
  f4v o[4][4] = {};        // [qc][nb]
  float mrow[16], lrow[16];
#pragma unroll
  for (int i = 0; i < 16; ++i) { mrow[i] = -1e30f; lrow[i] = 0.f; }

  for (int kt = 0; kt < 4; ++kt) {
    if (kt) __syncthreads();
    {
      int tr = tid >> 3, d0 = (tid & 7) * 8;
#pragma unroll
      for (int it = 0; it < 2; ++it) {
        int t = it * 32 + tr;
        const u16* kp = Kp + kvbase + (size_t)(kt * 64 + t) * kvs + d0;
        *(s8v*)&Ks[t][d0] = *(const s8v*)kp;
        s8v vv = *(const s8v*)(Vp + kvbase + (size_t)(kt * 64 + t) * kvs + d0);
#pragma unroll
        for (int j = 0; j < 8; ++j) Vt[d0 + j][t] = (u16)vv[j];
      }
    }
    __syncthreads();
#pragma unroll
    for (int qc = 0; qc < 4; ++qc) {
      // wave-uniform skip: tile entirely above the causal diagonal for this chunk
      if (causal && kt * 64 > w * 64 + qc * 16 + 15) continue;
      f4v S[4];
#pragma unroll
      for (int c = 0; c < 4; ++c) {
        s8v bk0 = *(const s8v*)&Ks[c * 16 + llo][lhi * 8];
        s8v bk1 = *(const s8v*)&Ks[c * 16 + llo][32 + lhi * 8];
        f4v z = {0.f, 0.f, 0.f, 0.f};
        z = __builtin_amdgcn_mfma_f32_16x16x32_bf16(aq0[qc], bk0, z, 0, 0, 0);
        S[c] = __builtin_amdgcn_mfma_f32_16x16x32_bf16(aq1[qc], bk1, z, 0, 0, 0);
      }
      float scv[4];
#pragma unroll
      for (int r = 0; r < 4; ++r) {
        const int tq = w * 64 + qc * 16 + lhi * 4 + r;
        float tmax = -1e30f;
#pragma unroll
        for (int c = 0; c < 4; ++c) {
          float s = S[c][r] * 0.125f;
          if (causal && (kt * 64 + c * 16 + llo) > tq) s = -1e30f;
          S[c][r] = s;
          tmax = fmaxf(tmax, s);
        }
        tmax = fmaxf(tmax, __shfl_xor(tmax, 1));
        tmax = fmaxf(tmax, __shfl_xor(tmax, 2));
        tmax = fmaxf(tmax, __shfl_xor(tmax, 4));
        tmax = fmaxf(tmax, __shfl_xor(tmax, 8));
        float mo = mrow[qc * 4 + r];
        float mn = fmaxf(mo, tmax);
        float sc = __expf(mo - mn);
        float sum = 0.f;
#pragma unroll
        for (int c = 0; c < 4; ++c) {
          float p = __expf(S[c][r] - mn);
          sum += p;
          Ps[w][lhi * 4 + r][c * 16 + llo] = f2bf(p);
        }
        sum += __shfl_xor(sum, 1); sum += __shfl_xor(sum, 2);
        sum += __shfl_xor(sum, 4); sum += __shfl_xor(sum, 8);
        lrow[qc * 4 + r] = lrow[qc * 4 + r] * sc + sum;
        mrow[qc * 4 + r] = mn;
        scv[r] = sc;
      }
#pragma unroll
      for (int nb = 0; nb < 4; ++nb)
#pragma unroll
        for (int r = 0; r < 4; ++r)
          o[qc][nb][r] *= scv[r];
      asm volatile("s_waitcnt lgkmcnt(0)" ::: "memory");
      __builtin_amdgcn_sched_barrier(0);
#pragma unroll
      for (int kb = 0; kb < 2; ++kb) {
        s8v pa = *(const s8v*)&Ps[w][llo][kb * 32 + lhi * 8];
#pragma unroll
        for (int nb = 0; nb < 4; ++nb) {
          s8v bv = *(const s8v*)&Vt[nb * 16 + llo][kb * 32 + lhi * 8];
          o[qc][nb] = __builtin_amdgcn_mfma_f32_16x16x32_bf16(pa, bv, o[qc][nb], 0, 0, 0);
        }
      }
    }
  }
#pragma unroll
  for (int qc = 0; qc < 4; ++qc)
#pragma unroll
    for (int nb = 0; nb < 4; ++nb)
#pragma unroll
      for (int r = 0; r < 4; ++r) {
        float inv = 1.f / lrow[qc * 4 + r];
        Ob[obase + (size_t)(w * 64 + qc * 16 + lhi * 4 + r) * 512 + nb * 16 + llo] =
            f2bf(o[qc][nb][r] * inv);
      }
}

// ---------------- loss: merge per-tile partials -> per-row nll ----------------
__global__ __launch_bounds__(256) void loss_lse_kernel(const float* __restrict__ pmax,
    const float* __restrict__ psum, const float* __restrict__ logits,
    const int* __restrict__ tgt, float* __restrict__ nll, float* __restrict__ valid) {
  const int w = threadIdx.x >> 6, lane = threadIdx.x & 63;
  const int row = blockIdx.x * 4 + w;
  float m = -1e30f, s = 0.f;
  for (int e = lane; e < 250; e += 64) {
    float pm = pmax[(size_t)row * 250 + e], ps = psum[(size_t)row * 250 + e];
    if (pm > m) { s = s * __expf(m - pm) + ps; m = pm; }
    else          s += ps * __expf(pm - m);
  }
#pragma unroll
  for (int o = 1; o < 64; o <<= 1) {
    float om = __shfl_xor(m, o), os = __shfl_xor(s, o);
    float mm = fmaxf(m, om);
    s = s * __expf(m - mm) + os * __expf(om - mm);
    m = mm;
  }
  if (lane == 0) {
    int t = tgt[row];
    float lse = m + logf(s);
    float v = (t != 1) ? 1.f : 0.f;
    nll[row] = v * (lse - logits[(size_t)row * 32000 + t]);
    valid[row] = v;
  }
}

__global__ __launch_bounds__(256) void loss_final_kernel(const float* __restrict__ nll,
    const float* __restrict__ valid, float* __restrict__ out) {
  __shared__ float sa[256], sb[256];
  int tid = threadIdx.x;
  float s = 0.f, c = 0.f;
  for (int i = tid; i < 16384; i += 256) { s += nll[i]; c += valid[i]; }
  sa[tid] = s; sb[tid] = c;
  __syncthreads();
  for (int st = 128; st > 0; st >>= 1) {
    if (tid < st) { sa[tid] += sa[tid + st]; sb[tid] += sb[tid + st]; }
    __syncthreads();
  }
  if (tid == 0) out[0] = sa[0] / fmaxf(sb[0], 1.f);
}

// =============================== host ===============================
extern "C" void kernel_launch(void* const* d_in, const int* in_sizes, int n_in,
                              void* d_out, int out_size, void* d_ws, size_t ws_size,
                              hipStream_t stream) {
  (void)in_sizes; (void)n_in; (void)out_size; (void)ws_size;
  const int* idx       = (const int*)d_in[0];
  const int* idx_enc   = (const int*)d_in[1];
  const int* targets   = (const int*)d_in[2];
  const float* emb_dec = (const float*)d_in[3];
  const float* emb_enc = (const float*)d_in[4];
  const float* enc_Wq  = (const float*)d_in[5];
  const float* enc_Wk  = (const float*)d_in[6];
  const float* enc_Wv  = (const float*)d_in[7];
  const float* enc_Wo  = (const float*)d_in[8];
  const float* enc_bo  = (const float*)d_in[9];
  const float* enc_ln_g = (const float*)d_in[10];
  const float* enc_ln_b = (const float*)d_in[11];
  const float* enc_W1  = (const float*)d_in[12];
  const float* enc_b1  = (const float*)d_in[13];
  const float* enc_W2  = (const float*)d_in[14];
  const float* enc_b2  = (const float*)d_in[15];
  const float* dWq_sa  = (const float*)d_in[16];
  const float* dWk_sa  = (const float*)d_in[17];
  const float* dWv_sa  = (const float*)d_in[18];
  const float* dWo_sa  = (const float*)d_in[19];
  const float* dbo_sa  = (const float*)d_in[20];
  const float* dWq_xa  = (const float*)d_in[21];
  const float* dWk_xa  = (const float*)d_in[22];
  const float* dWv_xa  = (const float*)d_in[23];
  const float* dWo_xa  = (const float*)d_in[24];
  const float* dbo_xa  = (const float*)d_in[25];
  const float* dec_ln_g = (const float*)d_in[26];
  const float* dec_ln_b = (const float*)d_in[27];
  const float* dec_W1  = (const float*)d_in[28];
  const float* dec_b1  = (const float*)d_in[29];
  const float* dec_W2  = (const float*)d_in[30];
  const float* dec_b2  = (const float*)d_in[31];
  const float* lnf_g   = (const float*)d_in[32];
  const float* lnf_b   = (const float*)d_in[33];
  const float* Wlm     = (const float*)d_in[34];
  const float* blm     = (const float*)d_in[35];
  float* out_logits = (float*)d_out;
  float* out_loss   = out_logits + (size_t)16384 * 32000;

  size_t off = 0;
  auto alloc = [&](size_t bytes) -> char* {
    char* p = (char*)d_ws + off;
    off += (bytes + 255) & ~(size_t)255;
    return p;
  };
  const size_t SQ = 512 * 512, SF = 512 * 2048;
  u16* tWqkvE = (u16*)alloc(6 * 3 * SQ * 2);
  u16* tWoE   = (u16*)alloc(6 * SQ * 2);
  u16* tW1E   = (u16*)alloc(6 * SF * 2);
  u16* tW2E   = (u16*)alloc(6 * SF * 2);
  u16* tWqkvS = (u16*)alloc(6 * 3 * SQ * 2);
  u16* tWoS   = (u16*)alloc(6 * SQ * 2);
  u16* tWqX   = (u16*)alloc(6 * SQ * 2);
  u16* tWkvX  = (u16*)alloc(6 * 2 * SQ * 2);
  u16* tWoX   = (u16*)alloc(6 * SQ * 2);
  u16* tW1D   = (u16*)alloc(6 * SF * 2);
  u16* tW2D   = (u16*)alloc(6 * SF * 2);
  u16* tWlm   = (u16*)alloc((size_t)32000 * 512 * 2);
  float* pe   = (float*)alloc(256 * 512 * 4);
  float* yE   = (float*)alloc((size_t)16384 * 512 * 4);
  float* xD   = (float*)alloc((size_t)16384 * 512 * 4);
  u16* hA     = (u16*)alloc((size_t)16384 * 512 * 2);
  u16* hB     = (u16*)alloc((size_t)16384 * 512 * 2);
  u16* qkvB   = (u16*)alloc((size_t)16384 * 1536 * 2);
  u16* qB     = (u16*)alloc((size_t)16384 * 512 * 2);
  u16* kvB    = (u16*)alloc((size_t)16384 * 1024 * 2);
  u16* atB    = (u16*)alloc((size_t)16384 * 512 * 2);
  u16* midB   = (u16*)alloc((size_t)16384 * 2048 * 2);
  float* pmax = (float*)alloc((size_t)16384 * 250 * 4);
  float* psum = (float*)alloc((size_t)16384 * 250 * 4);
  float* rnll = (float*)alloc(16384 * 4);
  float* rval = (float*)alloc(16384 * 4);

  // ---- weight conversion ----
  dim3 tb(256);
  const size_t S3 = 3 * SQ, S2 = 2 * SQ;
  {
    WcSq S;
    S.src[0] = enc_Wq;  S.dst[0] = tWqkvE + 0 * SQ; S.dstr[0] = S3;
    S.src[1] = enc_Wk;  S.dst[1] = tWqkvE + 1 * SQ; S.dstr[1] = S3;
    S.src[2] = enc_Wv;  S.dst[2] = tWqkvE + 2 * SQ; S.dstr[2] = S3;
    S.src[3] = enc_Wo;  S.dst[3] = tWoE;            S.dstr[3] = SQ;
    S.src[4] = dWq_sa;  S.dst[4] = tWqkvS + 0 * SQ; S.dstr[4] = S3;
    S.src[5] = dWk_sa;  S.dst[5] = tWqkvS + 1 * SQ; S.dstr[5] = S3;
    S.src[6] = dWv_sa;  S.dst[6] = tWqkvS + 2 * SQ; S.dstr[6] = S3;
    S.src[7] = dWo_sa;  S.dst[7] = tWoS;            S.dstr[7] = SQ;
    S.src[8] = dWq_xa;  S.dst[8] = tWqX;            S.dstr[8] = SQ;
    S.src[9] = dWk_xa;  S.dst[9] = tWkvX + 0 * SQ;  S.dstr[9] = S2;
    S.src[10] = dWv_xa; S.dst[10] = tWkvX + 1 * SQ; S.dstr[10] = S2;
    S.src[11] = dWo_xa; S.dst[11] = tWoX;           S.dstr[11] = SQ;
    wconv_sq_kernel<<<dim3(8, 8, 72), tb, 0, stream>>>(S);
  }
  wconv_kernel<<<dim3(8, 32, 6), tb, 0, stream>>>(enc_W1, tW1E, 512, 2048, SF);
  wconv_kernel<<<dim3(32, 8, 6), tb, 0, stream>>>(enc_W2, tW2E, 2048, 512, SF);
  wconv_kernel<<<dim3(8, 32, 6), tb, 0, stream>>>(dec_W1, tW1D, 512, 2048, SF);
  wconv_kernel<<<dim3(32, 8, 6), tb, 0, stream>>>(dec_W2, tW2D, 2048, 512, SF);
  wconv_kernel<<<dim3(8, 500, 1), tb, 0, stream>>>(Wlm, tWlm, 512, 32000, (size_t)0);
  pe_kernel<<<256, 256, 0, stream>>>(pe);

  auto ln = [&](const float* xin, const float* g, const float* bb, u16* o) {
    ln_kernel<<<4096, 256, 0, stream>>>(xin, g, bb, o);
  };
  auto g_bf16 = [&](const u16* Ap, const u16* Bp, u16* Op, int N) {
    gemm128<0, 0, 0, 1, 0, 0, 0, 0><<<dim3(128, N / 128), 256, 0, stream>>>(
        Ap, Bp, nullptr, nullptr, Op, 16384, N, 512, nullptr, nullptr,
        nullptr, nullptr, nullptr);
  };
  auto g_qkv_x = [&](const u16* Aq, const u16* Bq, u16* Oq,
                     const u16* Akv, const u16* Bkv, u16* Okv) {
    gemm128<0, 0, 0, 1, 0, 0, 0, 1><<<dim3(128, 12), 256, 0, stream>>>(
        Aq, Bq, nullptr, nullptr, Oq, 16384, 512, 512, nullptr, nullptr,
        Akv, Bkv, Okv);
  };
  auto proj_res = [&](const u16* Ap, const u16* Bp, const float* bi, float* xr, int K) {
    gemm128<1, 1, 0, 0, 0, 0, 0, 0><<<dim3(128, 4), 256, 0, stream>>>(
        Ap, Bp, bi, xr, xr, 16384, 512, K, nullptr, nullptr,
        nullptr, nullptr, nullptr);
  };
  auto ffn1 = [&](const u16* Ap, const u16* Bp, const float* bi, u16* Op) {
    gemm128<1, 0, 1, 1, 0, 0, 0, 0><<<dim3(128, 16), 256, 0, stream>>>(
        Ap, Bp, bi, nullptr, Op, 16384, 2048, 512, nullptr, nullptr,
        nullptr, nullptr, nullptr);
  };

  // ---------------- encoder ----------------
  emb_ln_kernel<<<4096, 256, 0, stream>>>(idx_enc, emb_enc, pe,
      enc_ln_g + 0, enc_ln_b + 0, yE, hA);
  for (int l = 0; l < 6; ++l) {
    if (l) ln(yE, enc_ln_g + (l * 2 + 0) * 512, enc_ln_b + (l * 2 + 0) * 512, hA);
    g_bf16(hA, tWqkvE + l * S3, qkvB, 1536);
    attn_kernel<<<512, 256, 0, stream>>>(qkvB, 1536, qkvB + 512, qkvB + 1024, 1536, atB, 0);
    proj_res(atB, tWoE + l * SQ, enc_bo + l * 512, yE, 512);
    ln(yE, enc_ln_g + (l * 2 + 1) * 512, enc_ln_b + (l * 2 + 1) * 512, hA);
    ffn1(hA, tW1E + l * SF, enc_b1 + l * 2048, midB);
    proj_res(midB, tW2E + l * SF, enc_b2 + l * 512, yE, 2048);
  }

  // ---------------- decoder ----------------
  emb_ln_kernel<<<4096, 256, 0, stream>>>(idx, emb_dec, pe,
      dec_ln_g + 0, dec_ln_b + 0, xD, hA);
  for (int l = 0; l < 6; ++l) {
    if (l) ln(xD, dec_ln_g + (l * 4 + 0) * 512, dec_ln_b + (l * 4 + 0) * 512, hA);
    g_bf16(hA, tWqkvS + l * S3, qkvB, 1536);
    attn_kernel<<<512, 256, 0, stream>>>(qkvB, 1536, qkvB + 512, qkvB + 1024, 1536, atB, 1);
    proj_res(atB, tWoS + l * SQ, dbo_sa + l * 512, xD, 512);
    ln2_kernel<<<8192, 256, 0, stream>>>(
        xD, dec_ln_g + (l * 4 + 1) * 512, dec_ln_b + (l * 4 + 1) * 512, hA,
        yE, dec_ln_g + (l * 4 + 2) * 512, dec_ln_b + (l * 4 + 2) * 512, hB);
    g_qkv_x(hA, tWqX + l * SQ, qB, hB, tWkvX + l * S2, kvB);
    attn_kernel<<<512, 256, 0, stream>>>(qB, 512, kvB, kvB + 512, 1024, atB, 0);
    proj_res(atB, tWoX + l * SQ, dbo_xa + l * 512, xD, 512);
    ln(xD, dec_ln_g + (l * 4 + 3) * 512, dec_ln_b + (l * 4 + 3) * 512, hA);
    ffn1(hA, tW1D + l * SF, dec_b1 + l * 2048, midB);
    proj_res(midB, tW2D + l * SF, dec_b2 + l * 512, xD, 2048);
  }

  // -------- LM head (fused loss partials, nt logits, row-panel XCD swizzle) --------
  ln(xD, lnf_g, lnf_b, hA);
  gemm128<1, 0, 0, 0, 1, 1, 1, 0><<<dim3(128, 250), 256, 0, stream>>>(
      hA, tWlm, blm, nullptr, out_logits, 16384, 32000, 512, pmax, psum,
      nullptr, nullptr, nullptr);
  loss_lse_kernel<<<4096, 256, 0, stream>>>(pmax, psum, out_logits, targets, rnll, rval);
  loss_final_kernel<<<1, 256, 0, stream>>>(rnll, rval, out_loss);
}

// Round 10
// 4700.103 us; speedup vs baseline: 1.2814x; 1.0290x over previous
//
#include <hip/hip_runtime.h>

typedef __attribute__((ext_vector_type(8))) short s8v;
typedef __attribute__((ext_vector_type(4))) float f4v;
using u16 = unsigned short;
using u8 = unsigned char;

__device__ __forceinline__ u16 f2bf(float f) {
  union { float f; unsigned u; } v; v.f = f;
  return (u16)((v.u + 0x7FFFu + ((v.u >> 16) & 1u)) >> 16);
}

// f32 -> OCP e4m3fn, RNE, saturate-to-448
__device__ __forceinline__ u8 f2f8(float f) {
  union { float f; unsigned u; } v; v.f = f;
  unsigned s = (v.u >> 24) & 0x80;
  v.u &= 0x7fffffff;
  if (!(v.f < 448.f)) return (u8)(s | 0x7e);
  if (v.f < 0.015625f) {
    int q = (int)(v.f * 512.f + 0.5f);
    return (u8)(s | (unsigned)q);
  }
  unsigned u = v.u + 0x7FFFFu + ((v.u >> 20) & 1u);
  int e = (int)(u >> 23) - 127;
  unsigned m = (u >> 20) & 7u;
  unsigned code = ((unsigned)(e + 7) << 3) | m;
  if (code > 0x7e) code = 0x7e;
  return (u8)(s | code);
}

// ---------------- positional encoding: pe[256][512] ----------------
__global__ __launch_bounds__(256) void pe_kernel(float* __restrict__ pe) {
  int i = blockIdx.x * 256 + threadIdx.x;
  int t = i >> 8, p = i & 255;
  float ex = (2.f * (float)p) / 512.f;
  float ang = (float)t * expf(-ex * 9.210340371976184f);
  pe[t * 512 + 2 * p]     = sinf(ang);
  pe[t * 512 + 2 * p + 1] = cosf(ang);
}

// -------- weight convert: f32 [R][C] -> {bf16|fp8} [C][R] --------
template<int FP8>
__global__ __launch_bounds__(256) void wconv_kernel(const float* __restrict__ in,
    void* __restrict__ out, int R, int C, size_t dstride) {
  __shared__ float tile[64][65];
  const size_t mat = (size_t)R * C;
  const float* src = in + (size_t)blockIdx.z * mat;
  int r0 = blockIdx.x * 64, c0 = blockIdx.y * 64;
  int tr = threadIdx.x >> 6, tc = threadIdx.x & 63;
#pragma unroll
  for (int i = 0; i < 16; ++i)
    tile[i * 4 + tr][tc] = src[(size_t)(r0 + i * 4 + tr) * C + (c0 + tc)];
  __syncthreads();
#pragma unroll
  for (int i = 0; i < 16; ++i) {
    size_t di = (size_t)(c0 + i * 4 + tr) * R + (r0 + tc);
    float val = tile[tc][i * 4 + tr];
    if (FP8) ((u8*)out + (size_t)blockIdx.z * dstride)[di] = f2f8(val);
    else     ((u16*)out + (size_t)blockIdx.z * dstride)[di] = f2bf(val);
  }
}

// -------- batched square (512x512) weight convert: 12 stacks, fp8 mask ----
struct WcSq { const float* src[12]; void* dst[12]; unsigned long long dstr[12]; unsigned fp8m; };
__global__ __launch_bounds__(256) void wconv_sq_kernel(WcSq S) {
  __shared__ float tile[64][65];
  int mm = blockIdx.z / 6, l = blockIdx.z % 6;
  const float* src = S.src[mm] + (size_t)l * 512 * 512;
  int fp8 = (S.fp8m >> mm) & 1;
  int r0 = blockIdx.x * 64, c0 = blockIdx.y * 64;
  int tr = threadIdx.x >> 6, tc = threadIdx.x & 63;
#pragma unroll
  for (int i = 0; i < 16; ++i)
    tile[i * 4 + tr][tc] = src[(size_t)(r0 + i * 4 + tr) * 512 + (c0 + tc)];
  __syncthreads();
#pragma unroll
  for (int i = 0; i < 16; ++i) {
    size_t di = (size_t)(c0 + i * 4 + tr) * 512 + (r0 + tc);
    float val = tile[tc][i * 4 + tr];
    if (fp8) ((u8*)S.dst[mm] + (size_t)l * S.dstr[mm])[di] = f2f8(val);
    else     ((u16*)S.dst[mm] + (size_t)l * S.dstr[mm])[di] = f2bf(val);
  }
}

// -------- LN body (wave per row), templated output dtype --------
template<int FP8>
__device__ __forceinline__ void ln_row(f4v v0, f4v v1, const float* g, const float* b,
                                       int lane, void* outrow) {
  float s = v0[0] + v0[1] + v0[2] + v0[3] + v1[0] + v1[1] + v1[2] + v1[3];
#pragma unroll
  for (int o = 1; o < 64; o <<= 1) s += __shfl_xor(s, o);
  float mu = s * (1.f / 512.f);
  float q = 0.f;
#pragma unroll
  for (int j = 0; j < 4; ++j) {
    float d0 = v0[j] - mu; q += d0 * d0;
    float d1 = v1[j] - mu; q += d1 * d1;
  }
#pragma unroll
  for (int o = 1; o < 64; o <<= 1) q += __shfl_xor(q, o);
  float rs = rsqrtf(q * (1.f / 512.f) + 1e-5f);
  f4v g0 = *(const f4v*)(g + lane * 8), g1 = *(const f4v*)(g + lane * 8 + 4);
  f4v b0 = *(const f4v*)(b + lane * 8), b1 = *(const f4v*)(b + lane * 8 + 4);
  if (FP8) {
    unsigned long long ov = 0;
#pragma unroll
    for (int j = 0; j < 4; ++j) {
      ov |= (unsigned long long)f2f8((v0[j] - mu) * rs * g0[j] + b0[j]) << (8 * j);
      ov |= (unsigned long long)f2f8((v1[j] - mu) * rs * g1[j] + b1[j]) << (8 * (4 + j));
    }
    *(unsigned long long*)((u8*)outrow + lane * 8) = ov;
  } else {
    s8v ov;
#pragma unroll
    for (int j = 0; j < 4; ++j) {
      ov[j]     = (short)f2bf((v0[j] - mu) * rs * g0[j] + b0[j]);
      ov[4 + j] = (short)f2bf((v1[j] - mu) * rs * g1[j] + b1[j]);
    }
    *(s8v*)((u16*)outrow + lane * 8) = ov;
  }
}

template<int FP8>
__global__ __launch_bounds__(256) void ln_kernel(const float* __restrict__ x,
    const float* __restrict__ g, const float* __restrict__ b, void* __restrict__ out) {
  int row = blockIdx.x * 4 + (threadIdx.x >> 6);
  int lane = threadIdx.x & 63;
  const float* xr = x + (size_t)row * 512 + lane * 8;
  void* orow = FP8 ? (void*)((u8*)out + (size_t)row * 512)
                   : (void*)((u16*)out + (size_t)row * 512);
  ln_row<FP8>(*(const f4v*)xr, *(const f4v*)(xr + 4), g, b, lane, orow);
}

// -------- dual LN (both bf16 out) --------
__global__ __launch_bounds__(256) void ln2_kernel(
    const float* __restrict__ x1, const float* __restrict__ g1, const float* __restrict__ b1,
    u16* __restrict__ o1, const float* __restrict__ x2, const float* __restrict__ g2,
    const float* __restrict__ b2, u16* __restrict__ o2) {
  int row = blockIdx.x * 4 + (threadIdx.x >> 6);
  int lane = threadIdx.x & 63;
  const float* x = x1; const float* g = g1; const float* b = b1; u16* o = o1;
  if (row >= 16384) { row -= 16384; x = x2; g = g2; b = b2; o = o2; }
  const float* xr = x + (size_t)row * 512 + lane * 8;
  ln_row<0>(*(const f4v*)xr, *(const f4v*)(xr + 4), g, b, lane, o + (size_t)row * 512);
}

// -------- fused embedding + pe + layer-0 LN (bf16 out) --------
__global__ __launch_bounds__(256) void emb_ln_kernel(const int* __restrict__ idx,
    const float* __restrict__ emb, const float* __restrict__ pe,
    const float* __restrict__ g, const float* __restrict__ b,
    float* __restrict__ y, u16* __restrict__ h) {
  int row = blockIdx.x * 4 + (threadIdx.x >> 6);
  int lane = threadIdx.x & 63;
  int tok = idx[row], t = row & 255;
  const float* e = emb + (size_t)tok * 512 + lane * 8;
  const float* p = pe + (size_t)t * 512 + lane * 8;
  f4v v0 = *(const f4v*)e + *(const f4v*)p;
  f4v v1 = *(const f4v*)(e + 4) + *(const f4v*)(p + 4);
  float* yr = y + (size_t)row * 512 + lane * 8;
  *(f4v*)yr = v0; *(f4v*)(yr + 4) = v1;
  ln_row<0>(v0, v1, g, b, lane, h + (size_t)row * 512);
}

// ======== GEMM: C[M,N] = A[M,K] @ Bt[N,K]^T, bf16 or fp8-e4m3 operands ======
// 128x128 tile, BK=64, 4 waves, single-buffered LDS (bf16 32KB / fp8 16KB),
// T2 XOR swizzle both paths; lane-linear LDS dest for global_load_lds.
// OMODE: 0=f32(+res/LN-loss opts), 1=bf16, 2=fp8.
template<int AB8, int OMODE, int HAS_BIAS, int ADD_RES, int RELU, int WLOSS,
         int NT, int SWZM, int DUAL>
__global__ __launch_bounds__(256, 4) void gemm128(
    const void* __restrict__ Av, const void* __restrict__ Btv,
    const float* __restrict__ bias, const float* __restrict__ res,
    void* __restrict__ outp, int M, int N, int K,
    float* __restrict__ pmax, float* __restrict__ psum,
    const void* __restrict__ A2, const void* __restrict__ Bt2,
    void* __restrict__ out2) {
  constexpr int SMEM_BYTES = AB8 ? 20480 : 32768;
  __shared__ __align__(16) u8 smem[SMEM_BYTES];
  const int tid = threadIdx.x, lane = tid & 63, w = tid >> 6;
  int bx, by;
  if (SWZM == 1) {
    int flat = blockIdx.y * gridDim.x + blockIdx.x;
    int xcd = flat & 7, local = flat >> 3;
    int p = local / gridDim.y;
    by = local - p * gridDim.y;
    bx = xcd * (gridDim.x >> 3) + p;
  } else {
    int nx = gridDim.x;
    int flat = blockIdx.y * nx + blockIdx.x;
    int per = (nx * gridDim.y) >> 3;
    int sw = (flat & 7) * per + (flat >> 3);
    by = sw / nx; bx = sw - by * nx;
  }
  const void* Ause = Av; const void* Buse = Btv; void* Ouse = outp;
  int Nn = N;
  if (DUAL && by >= 4) { Ause = A2; Buse = Bt2; Ouse = out2; Nn = 1024; by -= 4; }
  const int m0 = bx * 128, n0 = by * 128;
  const int wm = (w >> 1) * 64, wn = (w & 1) * 64;
  const int lhi = lane >> 4, llo = lane & 15;

  f4v acc[4][4] = {};
  const int nk = K >> 6;

  if (AB8) {
    const u8* A = (const u8*)Ause;
    const u8* Bt = (const u8*)Buse;
    u8* As8 = smem;
    u8* Bs8 = smem + 8192;
    const int r = tid >> 2, s16 = tid & 3;       // dest byte = q*4096 + tid*16
    const int sxb = (llo & 3) << 1;              // read-side byte-slot XOR (x8)
    for (int t = 0; t < nk; ++t) {
      const int kt = t * 64;
#pragma unroll
      for (int q = 0; q < 2; ++q) {
        int row = q * 64 + r;
        int gofs = kt + ((s16 ^ (row & 3)) * 16);
        __builtin_amdgcn_global_load_lds(
            (const __attribute__((address_space(1))) void*)(A + (size_t)(m0 + row) * K + gofs),
            (__attribute__((address_space(3))) void*)(&As8[row * 64 + s16 * 16]), 16, 0, 0);
        __builtin_amdgcn_global_load_lds(
            (const __attribute__((address_space(1))) void*)(Bt + (size_t)(n0 + row) * K + gofs),
            (__attribute__((address_space(3))) void*)(&Bs8[row * 64 + s16 * 16]), 16, 0, 0);
      }
      __syncthreads();
#pragma unroll
      for (int kk = 0; kk < 2; ++kk) {
        long af[4], bf8[4];
#pragma unroll
        for (int i = 0; i < 4; ++i)
          af[i] = *(const long*)&As8[(wm + i * 16 + llo) * 64 + (((kk * 4 + lhi) ^ sxb) * 8)];
#pragma unroll
        for (int j = 0; j < 4; ++j)
          bf8[j] = *(const long*)&Bs8[(wn + j * 16 + llo) * 64 + (((kk * 4 + lhi) ^ sxb) * 8)];
#pragma unroll
        for (int i = 0; i < 4; ++i)
#pragma unroll
          for (int j = 0; j < 4; ++j)
            acc[i][j] = __builtin_amdgcn_mfma_f32_16x16x32_fp8_fp8(af[i], bf8[j], acc[i][j], 0, 0, 0);
      }
      __syncthreads();
    }
  } else {
    const u16* A = (const u16*)Ause;
    const u16* Bt = (const u16*)Buse;
    u16* As = (u16*)smem;
    u16* Bs = (u16*)(smem + 16384);
    const int srow = tid >> 3, sl = tid & 7;
    const int gcol = (sl ^ (srow & 7)) * 8;
    const u16* Ag = A + (size_t)(m0 + srow) * K + gcol;
    const u16* Bg = Bt + (size_t)(n0 + srow) * K + gcol;
    const size_t rstep = (size_t)32 * K;
    const int sx = llo & 7;
    for (int t = 0; t < nk; ++t) {
      const int kt = t * 64;
#pragma unroll
      for (int q = 0; q < 4; ++q)
        __builtin_amdgcn_global_load_lds(
            (const __attribute__((address_space(1))) void*)(Ag + q * rstep + kt),
            (__attribute__((address_space(3))) void*)(&As[(q * 32 + srow) * 64 + sl * 8]),
            16, 0, 0);
#pragma unroll
      for (int q = 0; q < 4; ++q)
        __builtin_amdgcn_global_load_lds(
            (const __attribute__((address_space(1))) void*)(Bg + q * rstep + kt),
            (__attribute__((address_space(3))) void*)(&Bs[(q * 32 + srow) * 64 + sl * 8]),
            16, 0, 0);
      __syncthreads();
#pragma unroll
      for (int kk = 0; kk < 2; ++kk) {
        s8v af[4], bfv[4];
#pragma unroll
        for (int i = 0; i < 4; ++i)
          af[i] = *(const s8v*)&As[(wm + i * 16 + llo) * 64 + (((kk * 4 + lhi) ^ sx) * 8)];
#pragma unroll
        for (int j = 0; j < 4; ++j)
          bfv[j] = *(const s8v*)&Bs[(wn + j * 16 + llo) * 64 + (((kk * 4 + lhi) ^ sx) * 8)];
#pragma unroll
        for (int i = 0; i < 4; ++i)
#pragma unroll
          for (int j = 0; j < 4; ++j)
            acc[i][j] = __builtin_amdgcn_mfma_f32_16x16x32_bf16(af[i], bfv[j], acc[i][j], 0, 0, 0);
      }
      __syncthreads();
    }
  }

  // ---- epilogue (D row = (l>>4)*4 + r, col = l&15 — verified layout) ----
  if (OMODE == 1 || OMODE == 2) {
    float bvj[4];
#pragma unroll
    for (int j = 0; j < 4; ++j)
      bvj[j] = HAS_BIAS ? bias[n0 + wn + j * 16 + llo] : 0.f;
#pragma unroll
    for (int i = 0; i < 4; ++i) {
#pragma unroll
      for (int j = 0; j < 4; ++j) {
        int col = n0 + wn + j * 16 + llo;
#pragma unroll
        for (int r = 0; r < 4; ++r) {
          int row = m0 + wm + i * 16 + lhi * 4 + r;
          float v = acc[i][j][r] + bvj[j];
          if (RELU) v = fmaxf(v, 0.f);
          if (OMODE == 1) ((u16*)Ouse)[(size_t)row * Nn + col] = f2bf(v);
          else            ((u8*)Ouse)[(size_t)row * Nn + col] = f2f8(v);
        }
      }
    }
  } else {
    float* lb = (float*)smem;
    float* wbuf = lb + w * 1088;
    float* lbm = lb + 4608;
    float* lbs = lb + 4864;
    f4v bias4 = {0.f, 0.f, 0.f, 0.f};
    if (HAS_BIAS) bias4 = *(const f4v*)(bias + n0 + wn + llo * 4);
#pragma unroll
    for (int i = 0; i < 4; ++i) {
#pragma unroll
      for (int j = 0; j < 4; ++j)
#pragma unroll
        for (int r = 0; r < 4; ++r)
          wbuf[(lhi * 4 + r) * 68 + j * 16 + llo] = acc[i][j][r];
      asm volatile("s_waitcnt lgkmcnt(0)" ::: "memory");
      __builtin_amdgcn_sched_barrier(0);
#pragma unroll
      for (int p = 0; p < 4; ++p) {
        int r16 = p * 4 + lhi;
        f4v v4 = *(const f4v*)&wbuf[r16 * 68 + llo * 4];
        v4 += bias4;
        int grow = m0 + wm + i * 16 + r16;
        int gcol4 = n0 + wn + llo * 4;
        if (ADD_RES) v4 += *(const f4v*)(res + (size_t)grow * Nn + gcol4);
        if (RELU) {
          v4[0] = fmaxf(v4[0], 0.f); v4[1] = fmaxf(v4[1], 0.f);
          v4[2] = fmaxf(v4[2], 0.f); v4[3] = fmaxf(v4[3], 0.f);
        }
        float* dst = (float*)Ouse + (size_t)grow * Nn + gcol4;
        if (NT) __builtin_nontemporal_store(v4, (f4v*)dst);
        else    *(f4v*)dst = v4;
        if (WLOSS) {
          float mx = fmaxf(fmaxf(v4[0], v4[1]), fmaxf(v4[2], v4[3]));
          mx = fmaxf(mx, __shfl_xor(mx, 1));
          mx = fmaxf(mx, __shfl_xor(mx, 2));
          mx = fmaxf(mx, __shfl_xor(mx, 4));
          mx = fmaxf(mx, __shfl_xor(mx, 8));
          float sum = __expf(v4[0] - mx) + __expf(v4[1] - mx)
                    + __expf(v4[2] - mx) + __expf(v4[3] - mx);
          sum += __shfl_xor(sum, 1); sum += __shfl_xor(sum, 2);
          sum += __shfl_xor(sum, 4); sum += __shfl_xor(sum, 8);
          if (llo == 0) {
            int lr = wm + i * 16 + r16;
            lbm[lr * 2 + (wn >> 6)] = mx;
            lbs[lr * 2 + (wn >> 6)] = sum;
          }
        }
      }
      asm volatile("s_waitcnt lgkmcnt(0)" ::: "memory");
      __builtin_amdgcn_sched_barrier(0);
    }
    if (WLOSS) {
      __syncthreads();
      if (tid < 128) {
        float ma = lbm[tid * 2], mb = lbm[tid * 2 + 1];
        float sa = lbs[tid * 2], sb = lbs[tid * 2 + 1];
        float m = fmaxf(ma, mb);
        float ss = sa * __expf(ma - m) + sb * __expf(mb - m);
        int ntile = Nn >> 7;
        pmax[(size_t)(m0 + tid) * ntile + by] = m;
        psum[(size_t)(m0 + tid) * ntile + by] = ss;
      }
    }
  }
}

// ======== flash-tile attention (bf16 in, fp8 out), one (b,h)/block ========
__global__ __launch_bounds__(256, 2) void attn_kernel(
    const u16* __restrict__ Qp, int qs, const u16* __restrict__ Kp,
    const u16* __restrict__ Vp, int kvs, u8* __restrict__ Ob, int causal) {
  __shared__ __align__(16) u16 Ks[64][72];
  __shared__ __align__(16) u16 Vt[64][66];
  __shared__ __align__(16) u16 Ps[4][16][66];
  const int tid = threadIdx.x, lane = tid & 63, w = tid >> 6;
  const int b = blockIdx.x >> 3, h = blockIdx.x & 7;
  const size_t qbase  = (size_t)b * 256 * qs  + (size_t)h * 64;
  const size_t kvbase = (size_t)b * 256 * kvs + (size_t)h * 64;
  const size_t obase  = (size_t)b * 256 * 512 + (size_t)h * 64;
  const int lhi = lane >> 4, llo = lane & 15;
  s8v aq0[4], aq1[4];
#pragma unroll
  for (int qc = 0; qc < 4; ++qc) {
    const u16* qp = Qp + qbase + (size_t)(w * 64 + qc * 16 + llo) * qs;
    aq0[qc] = *(const s8v*)(qp + lhi * 8);
    aq1[qc] = *(const s8v*)(qp + 32 + lhi * 8);
  }
  f4v o[4][4] = {};
  float mrow[16], lrow[16];
#pragma unroll
  for (int i = 0; i < 16; ++i) { mrow[i] = -1e30f; lrow[i] = 0.f; }

  for (int kt = 0; kt < 4; ++kt) {
    if (kt) __syncthreads();
    {
      int tr = tid >> 3, d0 = (tid & 7) * 8;
#pragma unroll
      for (int it = 0; it < 2; ++it) {
        int t = it * 32 + tr;
        const u16* kp = Kp + kvbase + (size_t)(kt * 64 + t) * kvs + d0;
        *(s8v*)&Ks[t][d0] = *(const s8v*)kp;
        s8v vv = *(const s8v*)(Vp + kvbase + (size_t)(kt * 64 + t) * kvs + d0);
#pragma unroll
        for (int j = 0; j < 8; ++j) Vt[d0 + j][t] = (u16)vv[j];
      }
    }
    __syncthreads();
#pragma unroll
    for (int qc = 0; qc < 4; ++qc) {
      if (causal && kt * 64 > w * 64 + qc * 16 + 15) continue;
      f4v S[4];
#pragma unroll
      for (int c = 0; c < 4; ++c) {
        s8v bk0 = *(const s8v*)&Ks[c * 16 + llo][lhi * 8];
        s8v bk1 = *(const s8v*)&Ks[c * 16 + llo][32 + lhi * 8];
        f4v z = {0.f, 0.f, 0.f, 0.f};
        z = __builtin_amdgcn_mfma_f32_16x16x32_bf16(aq0[qc], bk0, z, 0, 0, 0);
        S[c] = __builtin_amdgcn_mfma_f32_16x16x32_bf16(aq1[qc], bk1, z, 0, 0, 0);
      }
      float scv[4];
#pragma unroll
      for (int r = 0; r < 4; ++r) {
        const int tq = w * 64 + qc * 16 + lhi * 4 + r;
        float tmax = -1e30f;
#pragma unroll
        for (int c = 0; c < 4; ++c) {
          float s = S[c][r] * 0.125f;
          if (causal && (kt * 64 + c * 16 + llo) > tq) s = -1e30f;
          S[c][r] = s;
          tmax = fmaxf(tmax, s);
        }
        tmax = fmaxf(tmax, __shfl_xor(tmax, 1));
        tmax = fmaxf(tmax, __shfl_xor(tmax, 2));
        tmax = fmaxf(tmax, __shfl_xor(tmax, 4));
        tmax = fmaxf(tmax, __shfl_xor(tmax, 8));
        float mo = mrow[qc * 4 + r];
        float mn = fmaxf(mo, tmax);
        float sc = __expf(mo - mn);
        float sum = 0.f;
#pragma unroll
        for (int c = 0; c < 4; ++c) {
          float p = __expf(S[c][r] - mn);
          sum += p;
          Ps[w][lhi * 4 + r][c * 16 + llo] = f2bf(p);
        }
        sum += __shfl_xor(sum, 1); sum += __shfl_xor(sum, 2);
        sum += __shfl_xor(sum, 4); sum += __shfl_xor(sum, 8);
        lrow[qc * 4 + r] = lrow[qc * 4 + r] * sc + sum;
        mrow[qc * 4 + r] = mn;
        scv[r] = sc;
      }
#pragma unroll
      for (int nb = 0; nb < 4; ++nb)
#pragma unroll
        for (int r = 0; r < 4; ++r)
          o[qc][nb][r] *= scv[r];
      asm volatile("s_waitcnt lgkmcnt(0)" ::: "memory");
      __builtin_amdgcn_sched_barrier(0);
#pragma unroll
      for (int kb = 0; kb < 2; ++kb) {
        s8v pa = *(const s8v*)&Ps[w][llo][kb * 32 + lhi * 8];
#pragma unroll
        for (int nb = 0; nb < 4; ++nb) {
          s8v bv = *(const s8v*)&Vt[nb * 16 + llo][kb * 32 + lhi * 8];
          o[qc][nb] = __builtin_amdgcn_mfma_f32_16x16x32_bf16(pa, bv, o[qc][nb], 0, 0, 0);
        }
      }
    }
  }
#pragma unroll
  for (int qc = 0; qc < 4; ++qc)
#pragma unroll
    for (int nb = 0; nb < 4; ++nb)
#pragma unroll
      for (int r = 0; r < 4; ++r) {
        float inv = 1.f / lrow[qc * 4 + r];
        Ob[obase + (size_t)(w * 64 + qc * 16 + lhi * 4 + r) * 512 + nb * 16 + llo] =
            f2f8(o[qc][nb][r] * inv);
      }
}

// ---------------- loss: merge per-tile partials -> per-row nll ----------------
__global__ __launch_bounds__(256) void loss_lse_kernel(const float* __restrict__ pmax,
    const float* __restrict__ psum, const float* __restrict__ logits,
    const int* __restrict__ tgt, float* __restrict__ nll, float* __restrict__ valid) {
  const int w = threadIdx.x >> 6, lane = threadIdx.x & 63;
  const int row = blockIdx.x * 4 + w;
  float m = -1e30f, s = 0.f;
  for (int e = lane; e < 250; e += 64) {
    float pm = pmax[(size_t)row * 250 + e], ps = psum[(size_t)row * 250 + e];
    if (pm > m) { s = s * __expf(m - pm) + ps; m = pm; }
    else          s += ps * __expf(pm - m);
  }
#pragma unroll
  for (int o = 1; o < 64; o <<= 1) {
    float om = __shfl_xor(m, o), os = __shfl_xor(s, o);
    float mm = fmaxf(m, om);
    s = s * __expf(m - mm) + os * __expf(om - mm);
    m = mm;
  }
  if (lane == 0) {
    int t = tgt[row];
    float lse = m + logf(s);
    float v = (t != 1) ? 1.f : 0.f;
    nll[row] = v * (lse - logits[(size_t)row * 32000 + t]);
    valid[row] = v;
  }
}

__global__ __launch_bounds__(256) void loss_final_kernel(const float* __restrict__ nll,
    const float* __restrict__ valid, float* __restrict__ out) {
  __shared__ float sa[256], sb[256];
  int tid = threadIdx.x;
  float s = 0.f, c = 0.f;
  for (int i = tid; i < 16384; i += 256) { s += nll[i]; c += valid[i]; }
  sa[tid] = s; sb[tid] = c;
  __syncthreads();
  for (int st = 128; st > 0; st >>= 1) {
    if (tid < st) { sa[tid] += sa[tid + st]; sb[tid] += sb[tid + st]; }
    __syncthreads();
  }
  if (tid == 0) out[0] = sa[0] / fmaxf(sb[0], 1.f);
}

// =============================== host ===============================
extern "C" void kernel_launch(void* const* d_in, const int* in_sizes, int n_in,
                              void* d_out, int out_size, void* d_ws, size_t ws_size,
                              hipStream_t stream) {
  (void)in_sizes; (void)n_in; (void)out_size; (void)ws_size;
  const int* idx       = (const int*)d_in[0];
  const int* idx_enc   = (const int*)d_in[1];
  const int* targets   = (const int*)d_in[2];
  const float* emb_dec = (const float*)d_in[3];
  const float* emb_enc = (const float*)d_in[4];
  const float* enc_Wq  = (const float*)d_in[5];
  const float* enc_Wk  = (const float*)d_in[6];
  const float* enc_Wv  = (const float*)d_in[7];
  const float* enc_Wo  = (const float*)d_in[8];
  const float* enc_bo  = (const float*)d_in[9];
  const float* enc_ln_g = (const float*)d_in[10];
  const float* enc_ln_b = (const float*)d_in[11];
  const float* enc_W1  = (const float*)d_in[12];
  const float* enc_b1  = (const float*)d_in[13];
  const float* enc_W2  = (const float*)d_in[14];
  const float* enc_b2  = (const float*)d_in[15];
  const float* dWq_sa  = (const float*)d_in[16];
  const float* dWk_sa  = (const float*)d_in[17];
  const float* dWv_sa  = (const float*)d_in[18];
  const float* dWo_sa  = (const float*)d_in[19];
  const float* dbo_sa  = (const float*)d_in[20];
  const float* dWq_xa  = (const float*)d_in[21];
  const float* dWk_xa  = (const float*)d_in[22];
  const float* dWv_xa  = (const float*)d_in[23];
  const float* dWo_xa  = (const float*)d_in[24];
  const float* dbo_xa  = (const float*)d_in[25];
  const float* dec_ln_g = (const float*)d_in[26];
  const float* dec_ln_b = (const float*)d_in[27];
  const float* dec_W1  = (const float*)d_in[28];
  const float* dec_b1  = (const float*)d_in[29];
  const float* dec_W2  = (const float*)d_in[30];
  const float* dec_b2  = (const float*)d_in[31];
  const float* lnf_g   = (const float*)d_in[32];
  const float* lnf_b   = (const float*)d_in[33];
  const float* Wlm     = (const float*)d_in[34];
  const float* blm     = (const float*)d_in[35];
  float* out_logits = (float*)d_out;
  float* out_loss   = out_logits + (size_t)16384 * 32000;

  size_t off = 0;
  auto alloc = [&](size_t bytes) -> char* {
    char* p = (char*)d_ws + off;
    off += (bytes + 255) & ~(size_t)255;
    return p;
  };
  const size_t SQ = 512 * 512, SF = 512 * 2048;
  u16* tWqkvE = (u16*)alloc(6 * 3 * SQ * 2);
  u8*  tWoE   = (u8*)alloc(6 * SQ);
  u8*  tW1E   = (u8*)alloc(6 * SF);
  u8*  tW2E   = (u8*)alloc(6 * SF);
  u16* tWqkvS = (u16*)alloc(6 * 3 * SQ * 2);
  u8*  tWoS   = (u8*)alloc(6 * SQ);
  u16* tWqX   = (u16*)alloc(6 * SQ * 2);
  u16* tWkvX  = (u16*)alloc(6 * 2 * SQ * 2);
  u8*  tWoX   = (u8*)alloc(6 * SQ);
  u8*  tW1D   = (u8*)alloc(6 * SF);
  u8*  tW2D   = (u8*)alloc(6 * SF);
  u16* tWlm   = (u16*)alloc((size_t)32000 * 512 * 2);
  float* pe   = (float*)alloc(256 * 512 * 4);
  float* yE   = (float*)alloc((size_t)16384 * 512 * 4);
  float* xD   = (float*)alloc((size_t)16384 * 512 * 4);
  u16* hA     = (u16*)alloc((size_t)16384 * 512 * 2);   // bf16 or fp8 (reused)
  u16* hB     = (u16*)alloc((size_t)16384 * 512 * 2);
  u16* qkvB   = (u16*)alloc((size_t)16384 * 1536 * 2);
  u16* qB     = (u16*)alloc((size_t)16384 * 512 * 2);
  u16* kvB    = (u16*)alloc((size_t)16384 * 1024 * 2);
  u8*  atB    = (u8*)alloc((size_t)16384 * 512);
  u8*  midB   = (u8*)alloc((size_t)16384 * 2048);
  float* pmax = (float*)alloc((size_t)16384 * 250 * 4);
  float* psum = (float*)alloc((size_t)16384 * 250 * 4);
  float* rnll = (float*)alloc(16384 * 4);
  float* rval = (float*)alloc(16384 * 4);

  // ---- weight conversion ----
  dim3 tb(256);
  const size_t S3 = 3 * SQ, S2 = 2 * SQ;
  {
    WcSq S;
    S.src[0] = enc_Wq;  S.dst[0] = tWqkvE + 0 * SQ; S.dstr[0] = S3;
    S.src[1] = enc_Wk;  S.dst[1] = tWqkvE + 1 * SQ; S.dstr[1] = S3;
    S.src[2] = enc_Wv;  S.dst[2] = tWqkvE + 2 * SQ; S.dstr[2] = S3;
    S.src[3] = enc_Wo;  S.dst[3] = tWoE;            S.dstr[3] = SQ;
    S.src[4] = dWq_sa;  S.dst[4] = tWqkvS + 0 * SQ; S.dstr[4] = S3;
    S.src[5] = dWk_sa;  S.dst[5] = tWqkvS + 1 * SQ; S.dstr[5] = S3;
    S.src[6] = dWv_sa;  S.dst[6] = tWqkvS + 2 * SQ; S.dstr[6] = S3;
    S.src[7] = dWo_sa;  S.dst[7] = tWoS;            S.dstr[7] = SQ;
    S.src[8] = dWq_xa;  S.dst[8] = tWqX;            S.dstr[8] = SQ;
    S.src[9] = dWk_xa;  S.dst[9] = tWkvX + 0 * SQ;  S.dstr[9] = S2;
    S.src[10] = dWv_xa; S.dst[10] = tWkvX + 1 * SQ; S.dstr[10] = S2;
    S.src[11] = dWo_xa; S.dst[11] = tWoX;           S.dstr[11] = SQ;
    S.fp8m = (1u << 3) | (1u << 7) | (1u << 11);
    wconv_sq_kernel<<<dim3(8, 8, 72), tb, 0, stream>>>(S);
  }
  wconv_kernel<1><<<dim3(8, 32, 6), tb, 0, stream>>>(enc_W1, tW1E, 512, 2048, SF);
  wconv_kernel<1><<<dim3(32, 8, 6), tb, 0, stream>>>(enc_W2, tW2E, 2048, 512, SF);
  wconv_kernel<1><<<dim3(8, 32, 6), tb, 0, stream>>>(dec_W1, tW1D, 512, 2048, SF);
  wconv_kernel<1><<<dim3(32, 8, 6), tb, 0, stream>>>(dec_W2, tW2D, 2048, 512, SF);
  wconv_kernel<0><<<dim3(8, 500, 1), tb, 0, stream>>>(Wlm, tWlm, 512, 32000, (size_t)0);
  pe_kernel<<<256, 256, 0, stream>>>(pe);

  auto ln16 = [&](const float* xin, const float* g, const float* bb, u16* o) {
    ln_kernel<0><<<4096, 256, 0, stream>>>(xin, g, bb, o);
  };
  auto ln8 = [&](const float* xin, const float* g, const float* bb, void* o) {
    ln_kernel<1><<<4096, 256, 0, stream>>>(xin, g, bb, o);
  };
  auto g_bf16 = [&](const u16* Ap, const u16* Bp, u16* Op, int N) {
    gemm128<0, 1, 0, 0, 0, 0, 0, 0, 0><<<dim3(128, N / 128), 256, 0, stream>>>(
        Ap, Bp, nullptr, nullptr, Op, 16384, N, 512, nullptr, nullptr,
        nullptr, nullptr, nullptr);
  };
  auto g_qkv_x = [&](const u16* Aq, const u16* Bq, u16* Oq,
                     const u16* Akv, const u16* Bkv, u16* Okv) {
    gemm128<0, 1, 0, 0, 0, 0, 0, 0, 1><<<dim3(128, 12), 256, 0, stream>>>(
        Aq, Bq, nullptr, nullptr, Oq, 16384, 512, 512, nullptr, nullptr,
        Akv, Bkv, Okv);
  };
  auto proj_res8 = [&](const u8* Ap, const u8* Bp, const float* bi, float* xr, int K) {
    gemm128<1, 0, 1, 1, 0, 0, 0, 0, 0><<<dim3(128, 4), 256, 0, stream>>>(
        Ap, Bp, bi, xr, xr, 16384, 512, K, nullptr, nullptr,
        nullptr, nullptr, nullptr);
  };
  auto ffn1_8 = [&](const u8* Ap, const u8* Bp, const float* bi, u8* Op) {
    gemm128<1, 2, 1, 0, 1, 0, 0, 0, 0><<<dim3(128, 16), 256, 0, stream>>>(
        Ap, Bp, bi, nullptr, Op, 16384, 2048, 512, nullptr, nullptr,
        nullptr, nullptr, nullptr);
  };

  // ---------------- encoder ----------------
  emb_ln_kernel<<<4096, 256, 0, stream>>>(idx_enc, emb_enc, pe,
      enc_ln_g + 0, enc_ln_b + 0, yE, hA);
  for (int l = 0; l < 6; ++l) {
    if (l) ln16(yE, enc_ln_g + (l * 2 + 0) * 512, enc_ln_b + (l * 2 + 0) * 512, hA);
    g_bf16(hA, tWqkvE + l * S3, qkvB, 1536);
    attn_kernel<<<512, 256, 0, stream>>>(qkvB, 1536, qkvB + 512, qkvB + 1024, 1536, atB, 0);
    proj_res8(atB, tWoE + l * SQ, enc_bo + l * 512, yE, 512);
    ln8(yE, enc_ln_g + (l * 2 + 1) * 512, enc_ln_b + (l * 2 + 1) * 512, hA);
    ffn1_8((const u8*)hA, tW1E + l * SF, enc_b1 + l * 2048, midB);
    proj_res8(midB, tW2E + l * SF, enc_b2 + l * 512, yE, 2048);
  }

  // ---------------- decoder ----------------
  emb_ln_kernel<<<4096, 256, 0, stream>>>(idx, emb_dec, pe,
      dec_ln_g + 0, dec_ln_b + 0, xD, hA);
  for (int l = 0; l < 6; ++l) {
    if (l) ln16(xD, dec_ln_g + (l * 4 + 0) * 512, dec_ln_b + (l * 4 + 0) * 512, hA);
    g_bf16(hA, tWqkvS + l * S3, qkvB, 1536);
    attn_kernel<<<512, 256, 0, stream>>>(qkvB, 1536, qkvB + 512, qkvB + 1024, 1536, atB, 1);
    proj_res8(atB, tWoS + l * SQ, dbo_sa + l * 512, xD, 512);
    ln2_kernel<<<8192, 256, 0, stream>>>(
        xD, dec_ln_g + (l * 4 + 1) * 512, dec_ln_b + (l * 4 + 1) * 512, hA,
        yE, dec_ln_g + (l * 4 + 2) * 512, dec_ln_b + (l * 4 + 2) * 512, hB);
    g_qkv_x(hA, tWqX + l * SQ, qB, hB, tWkvX + l * S2, kvB);
    attn_kernel<<<512, 256, 0, stream>>>(qB, 512, kvB, kvB + 512, 1024, atB, 0);
    proj_res8(atB, tWoX + l * SQ, dbo_xa + l * 512, xD, 512);
    ln8(xD, dec_ln_g + (l * 4 + 3) * 512, dec_ln_b + (l * 4 + 3) * 512, hA);
    ffn1_8((const u8*)hA, tW1D + l * SF, dec_b1 + l * 2048, midB);
    proj_res8(midB, tW2D + l * SF, dec_b2 + l * 512, xD, 2048);
  }

  // -------- LM head (bf16, fused loss partials, nt logits, row-panel swizzle) ----
  ln16(xD, lnf_g, lnf_b, hA);
  gemm128<0, 0, 1, 0, 0, 1, 1, 1, 0><<<dim3(128, 250), 256, 0, stream>>>(
      hA, tWlm, blm, nullptr, out_logits, 16384, 32000, 512, pmax, psum,
      nullptr, nullptr, nullptr);
  loss_lse_kernel<<<4096, 256, 0, stream>>>(pmax, psum, out_logits, targets, rnll, rval);
  loss_final_kernel<<<1, 256, 0, stream>>>(rnll, rval, out_loss);
}

// Round 11
// 4498.429 us; speedup vs baseline: 1.3389x; 1.0448x over previous
//
#include <hip/hip_runtime.h>

typedef __attribute__((ext_vector_type(8))) short s8v;
typedef __attribute__((ext_vector_type(4))) float f4v;
using u16 = unsigned short;
using u8 = unsigned char;

__device__ __forceinline__ u16 f2bf(float f) {
  union { float f; unsigned u; } v; v.f = f;
  return (u16)((v.u + 0x7FFFu + ((v.u >> 16) & 1u)) >> 16);
}

// f32 -> OCP e4m3fn, RNE, saturate-to-448
__device__ __forceinline__ u8 f2f8(float f) {
  union { float f; unsigned u; } v; v.f = f;
  unsigned s = (v.u >> 24) & 0x80;
  v.u &= 0x7fffffff;
  if (!(v.f < 448.f)) return (u8)(s | 0x7e);
  if (v.f < 0.015625f) {
    int q = (int)(v.f * 512.f + 0.5f);
    return (u8)(s | (unsigned)q);
  }
  unsigned u = v.u + 0x7FFFFu + ((v.u >> 20) & 1u);
  int e = (int)(u >> 23) - 127;
  unsigned m = (u >> 20) & 7u;
  unsigned code = ((unsigned)(e + 7) << 3) | m;
  if (code > 0x7e) code = 0x7e;
  return (u8)(s | code);
}

// ---------------- positional encoding: pe[256][512] ----------------
__global__ __launch_bounds__(256) void pe_kernel(float* __restrict__ pe) {
  int i = blockIdx.x * 256 + threadIdx.x;
  int t = i >> 8, p = i & 255;
  float ex = (2.f * (float)p) / 512.f;
  float ang = (float)t * expf(-ex * 9.210340371976184f);
  pe[t * 512 + 2 * p]     = sinf(ang);
  pe[t * 512 + 2 * p + 1] = cosf(ang);
}

// -------- weight convert: f32 [R][C] -> {bf16|fp8} [C][R] --------
template<int FP8>
__global__ __launch_bounds__(256) void wconv_kernel(const float* __restrict__ in,
    void* __restrict__ out, int R, int C, size_t dstride) {
  __shared__ float tile[64][65];
  const size_t mat = (size_t)R * C;
  const float* src = in + (size_t)blockIdx.z * mat;
  int r0 = blockIdx.x * 64, c0 = blockIdx.y * 64;
  int tr = threadIdx.x >> 6, tc = threadIdx.x & 63;
#pragma unroll
  for (int i = 0; i < 16; ++i)
    tile[i * 4 + tr][tc] = src[(size_t)(r0 + i * 4 + tr) * C + (c0 + tc)];
  __syncthreads();
#pragma unroll
  for (int i = 0; i < 16; ++i) {
    size_t di = (size_t)(c0 + i * 4 + tr) * R + (r0 + tc);
    float val = tile[tc][i * 4 + tr];
    if (FP8) ((u8*)out + (size_t)blockIdx.z * dstride)[di] = f2f8(val);
    else     ((u16*)out + (size_t)blockIdx.z * dstride)[di] = f2bf(val);
  }
}

// -------- batched square (512x512) weight convert: 12 stacks, fp8 mask ----
struct WcSq { const float* src[12]; void* dst[12]; unsigned long long dstr[12]; unsigned fp8m; };
__global__ __launch_bounds__(256) void wconv_sq_kernel(WcSq S) {
  __shared__ float tile[64][65];
  int mm = blockIdx.z / 6, l = blockIdx.z % 6;
  const float* src = S.src[mm] + (size_t)l * 512 * 512;
  int fp8 = (S.fp8m >> mm) & 1;
  int r0 = blockIdx.x * 64, c0 = blockIdx.y * 64;
  int tr = threadIdx.x >> 6, tc = threadIdx.x & 63;
#pragma unroll
  for (int i = 0; i < 16; ++i)
    tile[i * 4 + tr][tc] = src[(size_t)(r0 + i * 4 + tr) * 512 + (c0 + tc)];
  __syncthreads();
#pragma unroll
  for (int i = 0; i < 16; ++i) {
    size_t di = (size_t)(c0 + i * 4 + tr) * 512 + (r0 + tc);
    float val = tile[tc][i * 4 + tr];
    if (fp8) ((u8*)S.dst[mm] + (size_t)l * S.dstr[mm])[di] = f2f8(val);
    else     ((u16*)S.dst[mm] + (size_t)l * S.dstr[mm])[di] = f2bf(val);
  }
}

// -------- LN body (wave per row), templated output dtype --------
template<int FP8>
__device__ __forceinline__ void ln_row(f4v v0, f4v v1, const float* g, const float* b,
                                       int lane, void* outrow) {
  float s = v0[0] + v0[1] + v0[2] + v0[3] + v1[0] + v1[1] + v1[2] + v1[3];
#pragma unroll
  for (int o = 1; o < 64; o <<= 1) s += __shfl_xor(s, o);
  float mu = s * (1.f / 512.f);
  float q = 0.f;
#pragma unroll
  for (int j = 0; j < 4; ++j) {
    float d0 = v0[j] - mu; q += d0 * d0;
    float d1 = v1[j] - mu; q += d1 * d1;
  }
#pragma unroll
  for (int o = 1; o < 64; o <<= 1) q += __shfl_xor(q, o);
  float rs = rsqrtf(q * (1.f / 512.f) + 1e-5f);
  f4v g0 = *(const f4v*)(g + lane * 8), g1 = *(const f4v*)(g + lane * 8 + 4);
  f4v b0 = *(const f4v*)(b + lane * 8), b1 = *(const f4v*)(b + lane * 8 + 4);
  if (FP8) {
    unsigned long long ov = 0;
#pragma unroll
    for (int j = 0; j < 4; ++j) {
      ov |= (unsigned long long)f2f8((v0[j] - mu) * rs * g0[j] + b0[j]) << (8 * j);
      ov |= (unsigned long long)f2f8((v1[j] - mu) * rs * g1[j] + b1[j]) << (8 * (4 + j));
    }
    *(unsigned long long*)((u8*)outrow + lane * 8) = ov;
  } else {
    s8v ov;
#pragma unroll
    for (int j = 0; j < 4; ++j) {
      ov[j]     = (short)f2bf((v0[j] - mu) * rs * g0[j] + b0[j]);
      ov[4 + j] = (short)f2bf((v1[j] - mu) * rs * g1[j] + b1[j]);
    }
    *(s8v*)((u16*)outrow + lane * 8) = ov;
  }
}

template<int FP8>
__global__ __launch_bounds__(256) void ln_kernel(const float* __restrict__ x,
    const float* __restrict__ g, const float* __restrict__ b, void* __restrict__ out) {
  int row = blockIdx.x * 4 + (threadIdx.x >> 6);
  int lane = threadIdx.x & 63;
  const float* xr = x + (size_t)row * 512 + lane * 8;
  void* orow = FP8 ? (void*)((u8*)out + (size_t)row * 512)
                   : (void*)((u16*)out + (size_t)row * 512);
  ln_row<FP8>(*(const f4v*)xr, *(const f4v*)(xr + 4), g, b, lane, orow);
}

// -------- dual LN (both bf16 out) --------
__global__ __launch_bounds__(256) void ln2_kernel(
    const float* __restrict__ x1, const float* __restrict__ g1, const float* __restrict__ b1,
    u16* __restrict__ o1, const float* __restrict__ x2, const float* __restrict__ g2,
    const float* __restrict__ b2, u16* __restrict__ o2) {
  int row = blockIdx.x * 4 + (threadIdx.x >> 6);
  int lane = threadIdx.x & 63;
  const float* x = x1; const float* g = g1; const float* b = b1; u16* o = o1;
  if (row >= 16384) { row -= 16384; x = x2; g = g2; b = b2; o = o2; }
  const float* xr = x + (size_t)row * 512 + lane * 8;
  ln_row<0>(*(const f4v*)xr, *(const f4v*)(xr + 4), g, b, lane, o + (size_t)row * 512);
}

// -------- fused embedding + pe + layer-0 LN (bf16 out) --------
__global__ __launch_bounds__(256) void emb_ln_kernel(const int* __restrict__ idx,
    const float* __restrict__ emb, const float* __restrict__ pe,
    const float* __restrict__ g, const float* __restrict__ b,
    float* __restrict__ y, u16* __restrict__ h) {
  int row = blockIdx.x * 4 + (threadIdx.x >> 6);
  int lane = threadIdx.x & 63;
  int tok = idx[row], t = row & 255;
  const float* e = emb + (size_t)tok * 512 + lane * 8;
  const float* p = pe + (size_t)t * 512 + lane * 8;
  f4v v0 = *(const f4v*)e + *(const f4v*)p;
  f4v v1 = *(const f4v*)(e + 4) + *(const f4v*)(p + 4);
  float* yr = y + (size_t)row * 512 + lane * 8;
  *(f4v*)yr = v0; *(f4v*)(yr + 4) = v1;
  ln_row<0>(v0, v1, g, b, lane, h + (size_t)row * 512);
}

// ======== GEMM: C[M,N] = A[M,K] @ Bt[N,K]^T, bf16 or fp8-e4m3 operands ======
// 128x128 tile, 4 waves, single-buffered 32KB LDS, T2 XOR swizzle.
// bf16: BK=64. fp8: BK=128 (same 128B row / 32KB LDS; halves barrier count).
// OMODE: 0=f32(+res/LN-loss opts), 1=bf16, 2=fp8.
template<int AB8, int OMODE, int HAS_BIAS, int ADD_RES, int RELU, int WLOSS,
         int NT, int SWZM, int DUAL>
__global__ __launch_bounds__(256, 4) void gemm128(
    const void* __restrict__ Av, const void* __restrict__ Btv,
    const float* __restrict__ bias, const float* __restrict__ res,
    void* __restrict__ outp, int M, int N, int K,
    float* __restrict__ pmax, float* __restrict__ psum,
    const void* __restrict__ A2, const void* __restrict__ Bt2,
    void* __restrict__ out2) {
  __shared__ __align__(16) u8 smem[32768];
  const int tid = threadIdx.x, lane = tid & 63, w = tid >> 6;
  int bx, by;
  if (SWZM == 1) {
    int flat = blockIdx.y * gridDim.x + blockIdx.x;
    int xcd = flat & 7, local = flat >> 3;
    int p = local / gridDim.y;
    by = local - p * gridDim.y;
    bx = xcd * (gridDim.x >> 3) + p;
  } else {
    int nx = gridDim.x;
    int flat = blockIdx.y * nx + blockIdx.x;
    int per = (nx * gridDim.y) >> 3;
    int sw = (flat & 7) * per + (flat >> 3);
    by = sw / nx; bx = sw - by * nx;
  }
  const void* Ause = Av; const void* Buse = Btv; void* Ouse = outp;
  int Nn = N;
  if (DUAL && by >= 4) { Ause = A2; Buse = Bt2; Ouse = out2; Nn = 1024; by -= 4; }
  const int m0 = bx * 128, n0 = by * 128;
  const int wm = (w >> 1) * 64, wn = (w & 1) * 64;
  const int lhi = lane >> 4, llo = lane & 15;
  const int srow = tid >> 3, sl = tid & 7;       // 32 rows/round, 8 x 16B slots

  f4v acc[4][4] = {};

  if (AB8) {
    // fp8: BK=128 -> row = 128 fp8 = 128B; LDS [128][128B] x2 = 32KB
    const u8* A = (const u8*)Ause;
    const u8* Bt = (const u8*)Buse;
    u8* As8 = smem;
    u8* Bs8 = smem + 16384;
    const int gcolb = (sl ^ (srow & 7)) * 16;    // pre-swizzled 16B slot
    const u8* Ag = A + (size_t)(m0 + srow) * K + gcolb;
    const u8* Bg = Bt + (size_t)(n0 + srow) * K + gcolb;
    const size_t rstep = (size_t)32 * K;
    const int sxb = llo & 7;
    const int nk = K >> 7;
    for (int t = 0; t < nk; ++t) {
      const int kt = t * 128;
#pragma unroll
      for (int q = 0; q < 4; ++q)
        __builtin_amdgcn_global_load_lds(
            (const __attribute__((address_space(1))) void*)(Ag + q * rstep + kt),
            (__attribute__((address_space(3))) void*)(&As8[(q * 32 + srow) * 128 + sl * 16]),
            16, 0, 0);
#pragma unroll
      for (int q = 0; q < 4; ++q)
        __builtin_amdgcn_global_load_lds(
            (const __attribute__((address_space(1))) void*)(Bg + q * rstep + kt),
            (__attribute__((address_space(3))) void*)(&Bs8[(q * 32 + srow) * 128 + sl * 16]),
            16, 0, 0);
      __syncthreads();
#pragma unroll
      for (int kk = 0; kk < 4; ++kk) {
        const int slot8 = kk * 4 + lhi;                  // 8B slot within row
        const int lbyte = (((slot8 >> 1) ^ sxb) * 16) + ((slot8 & 1) * 8);
        long af[4], bf8[4];
#pragma unroll
        for (int i = 0; i < 4; ++i)
          af[i] = *(const long*)&As8[(wm + i * 16 + llo) * 128 + lbyte];
#pragma unroll
        for (int j = 0; j < 4; ++j)
          bf8[j] = *(const long*)&Bs8[(wn + j * 16 + llo) * 128 + lbyte];
#pragma unroll
        for (int i = 0; i < 4; ++i)
#pragma unroll
          for (int j = 0; j < 4; ++j)
            acc[i][j] = __builtin_amdgcn_mfma_f32_16x16x32_fp8_fp8(af[i], bf8[j], acc[i][j], 0, 0, 0);
      }
      __syncthreads();
    }
  } else {
    // bf16: BK=64 -> row = 64 bf16 = 128B; LDS [128][128B] x2 = 32KB
    const u16* A = (const u16*)Ause;
    const u16* Bt = (const u16*)Buse;
    u16* As = (u16*)smem;
    u16* Bs = (u16*)(smem + 16384);
    const int gcol = (sl ^ (srow & 7)) * 8;
    const u16* Ag = A + (size_t)(m0 + srow) * K + gcol;
    const u16* Bg = Bt + (size_t)(n0 + srow) * K + gcol;
    const size_t rstep = (size_t)32 * K;
    const int sx = llo & 7;
    const int nk = K >> 6;
    for (int t = 0; t < nk; ++t) {
      const int kt = t * 64;
#pragma unroll
      for (int q = 0; q < 4; ++q)
        __builtin_amdgcn_global_load_lds(
            (const __attribute__((address_space(1))) void*)(Ag + q * rstep + kt),
            (__attribute__((address_space(3))) void*)(&As[(q * 32 + srow) * 64 + sl * 8]),
            16, 0, 0);
#pragma unroll
      for (int q = 0; q < 4; ++q)
        __builtin_amdgcn_global_load_lds(
            (const __attribute__((address_space(1))) void*)(Bg + q * rstep + kt),
            (__attribute__((address_space(3))) void*)(&Bs[(q * 32 + srow) * 64 + sl * 8]),
            16, 0, 0);
      __syncthreads();
#pragma unroll
      for (int kk = 0; kk < 2; ++kk) {
        s8v af[4], bfv[4];
#pragma unroll
        for (int i = 0; i < 4; ++i)
          af[i] = *(const s8v*)&As[(wm + i * 16 + llo) * 64 + (((kk * 4 + lhi) ^ sx) * 8)];
#pragma unroll
        for (int j = 0; j < 4; ++j)
          bfv[j] = *(const s8v*)&Bs[(wn + j * 16 + llo) * 64 + (((kk * 4 + lhi) ^ sx) * 8)];
#pragma unroll
        for (int i = 0; i < 4; ++i)
#pragma unroll
          for (int j = 0; j < 4; ++j)
            acc[i][j] = __builtin_amdgcn_mfma_f32_16x16x32_bf16(af[i], bfv[j], acc[i][j], 0, 0, 0);
      }
      __syncthreads();
    }
  }

  // ---- epilogue (D row = (l>>4)*4 + r, col = l&15 — verified layout) ----
  if (OMODE == 1 || OMODE == 2) {
    float bvj[4];
#pragma unroll
    for (int j = 0; j < 4; ++j)
      bvj[j] = HAS_BIAS ? bias[n0 + wn + j * 16 + llo] : 0.f;
#pragma unroll
    for (int i = 0; i < 4; ++i) {
#pragma unroll
      for (int j = 0; j < 4; ++j) {
        int col = n0 + wn + j * 16 + llo;
#pragma unroll
        for (int r = 0; r < 4; ++r) {
          int row = m0 + wm + i * 16 + lhi * 4 + r;
          float v = acc[i][j][r] + bvj[j];
          if (RELU) v = fmaxf(v, 0.f);
          if (OMODE == 1) ((u16*)Ouse)[(size_t)row * Nn + col] = f2bf(v);
          else            ((u8*)Ouse)[(size_t)row * Nn + col] = f2f8(v);
        }
      }
    }
  } else {
    float* lb = (float*)smem;
    float* wbuf = lb + w * 1088;
    float* lbm = lb + 4608;
    float* lbs = lb + 4864;
    f4v bias4 = {0.f, 0.f, 0.f, 0.f};
    if (HAS_BIAS) bias4 = *(const f4v*)(bias + n0 + wn + llo * 4);
#pragma unroll
    for (int i = 0; i < 4; ++i) {
#pragma unroll
      for (int j = 0; j < 4; ++j)
#pragma unroll
        for (int r = 0; r < 4; ++r)
          wbuf[(lhi * 4 + r) * 68 + j * 16 + llo] = acc[i][j][r];
      asm volatile("s_waitcnt lgkmcnt(0)" ::: "memory");
      __builtin_amdgcn_sched_barrier(0);
#pragma unroll
      for (int p = 0; p < 4; ++p) {
        int r16 = p * 4 + lhi;
        f4v v4 = *(const f4v*)&wbuf[r16 * 68 + llo * 4];
        v4 += bias4;
        int grow = m0 + wm + i * 16 + r16;
        int gcol4 = n0 + wn + llo * 4;
        if (ADD_RES) v4 += *(const f4v*)(res + (size_t)grow * Nn + gcol4);
        if (RELU) {
          v4[0] = fmaxf(v4[0], 0.f); v4[1] = fmaxf(v4[1], 0.f);
          v4[2] = fmaxf(v4[2], 0.f); v4[3] = fmaxf(v4[3], 0.f);
        }
        float* dst = (float*)Ouse + (size_t)grow * Nn + gcol4;
        if (NT) __builtin_nontemporal_store(v4, (f4v*)dst);
        else    *(f4v*)dst = v4;
        if (WLOSS) {
          float mx = fmaxf(fmaxf(v4[0], v4[1]), fmaxf(v4[2], v4[3]));
          mx = fmaxf(mx, __shfl_xor(mx, 1));
          mx = fmaxf(mx, __shfl_xor(mx, 2));
          mx = fmaxf(mx, __shfl_xor(mx, 4));
          mx = fmaxf(mx, __shfl_xor(mx, 8));
          float sum = __expf(v4[0] - mx) + __expf(v4[1] - mx)
                    + __expf(v4[2] - mx) + __expf(v4[3] - mx);
          sum += __shfl_xor(sum, 1); sum += __shfl_xor(sum, 2);
          sum += __shfl_xor(sum, 4); sum += __shfl_xor(sum, 8);
          if (llo == 0) {
            int lr = wm + i * 16 + r16;
            lbm[lr * 2 + (wn >> 6)] = mx;
            lbs[lr * 2 + (wn >> 6)] = sum;
          }
        }
      }
      asm volatile("s_waitcnt lgkmcnt(0)" ::: "memory");
      __builtin_amdgcn_sched_barrier(0);
    }
    if (WLOSS) {
      __syncthreads();
      if (tid < 128) {
        float ma = lbm[tid * 2], mb = lbm[tid * 2 + 1];
        float sa = lbs[tid * 2], sb = lbs[tid * 2 + 1];
        float m = fmaxf(ma, mb);
        float ss = sa * __expf(ma - m) + sb * __expf(mb - m);
        int ntile = Nn >> 7;
        pmax[(size_t)(m0 + tid) * ntile + by] = m;
        psum[(size_t)(m0 + tid) * ntile + by] = ss;
      }
    }
  }
}

// ======== flash-tile attention (bf16 in, fp8 out), one (b,h)/block ========
__global__ __launch_bounds__(256, 2) void attn_kernel(
    const u16* __restrict__ Qp, int qs, const u16* __restrict__ Kp,
    const u16* __restrict__ Vp, int kvs, u8* __restrict__ Ob, int causal) {
  __shared__ __align__(16) u16 Ks[64][72];
  __shared__ __align__(16) u16 Vt[64][66];
  __shared__ __align__(16) u16 Ps[4][16][66];
  const int tid = threadIdx.x, lane = tid & 63, w = tid >> 6;
  const int b = blockIdx.x >> 3, h = blockIdx.x & 7;
  const size_t qbase  = (size_t)b * 256 * qs  + (size_t)h * 64;
  const size_t kvbase = (size_t)b * 256 * kvs + (size_t)h * 64;
  const size_t obase  = (size_t)b * 256 * 512 + (size_t)h * 64;
  const int lhi = lane >> 4, llo = lane & 15;
  s8v aq0[4], aq1[4];
#pragma unroll
  for (int qc = 0; qc < 4; ++qc) {
    const u16* qp = Qp + qbase + (size_t)(w * 64 + qc * 16 + llo) * qs;
    aq0[qc] = *(const s8v*)(qp + lhi * 8);
    aq1[qc] = *(const s8v*)(qp + 32 + lhi * 8);
  }
  f4v o[4][4] = {};
  float mrow[16], lrow[16];
#pragma unroll
  for (int i = 0; i < 16; ++i) { mrow[i] = -1e30f; lrow[i] = 0.f; }

  for (int kt = 0; kt < 4; ++kt) {
    if (kt) __syncthreads();
    {
      int tr = tid >> 3, d0 = (tid & 7) * 8;
#pragma unroll
      for (int it = 0; it < 2; ++it) {
        int t = it * 32 + tr;
        const u16* kp = Kp + kvbase + (size_t)(kt * 64 + t) * kvs + d0;
        *(s8v*)&Ks[t][d0] = *(const s8v*)kp;
        s8v vv = *(const s8v*)(Vp + kvbase + (size_t)(kt * 64 + t) * kvs + d0);
#pragma unroll
        for (int j = 0; j < 8; ++j) Vt[d0 + j][t] = (u16)vv[j];
      }
    }
    __syncthreads();
#pragma unroll
    for (int qc = 0; qc < 4; ++qc) {
      if (causal && kt * 64 > w * 64 + qc * 16 + 15) continue;
      f4v S[4];
#pragma unroll
      for (int c = 0; c < 4; ++c) {
        s8v bk0 = *(const s8v*)&Ks[c * 16 + llo][lhi * 8];
        s8v bk1 = *(const s8v*)&Ks[c * 16 + llo][32 + lhi * 8];
        f4v z = {0.f, 0.f, 0.f, 0.f};
        z = __builtin_amdgcn_mfma_f32_16x16x32_bf16(aq0[qc], bk0, z, 0, 0, 0);
        S[c] = __builtin_amdgcn_mfma_f32_16x16x32_bf16(aq1[qc], bk1, z, 0, 0, 0);
      }
      float scv[4];
#pragma unroll
      for (int r = 0; r < 4; ++r) {
        const int tq = w * 64 + qc * 16 + lhi * 4 + r;
        float tmax = -1e30f;
#pragma unroll
        for (int c = 0; c < 4; ++c) {
          float s = S[c][r] * 0.125f;
          if (causal && (kt * 64 + c * 16 + llo) > tq) s = -1e30f;
          S[c][r] = s;
          tmax = fmaxf(tmax, s);
        }
        tmax = fmaxf(tmax, __shfl_xor(tmax, 1));
        tmax = fmaxf(tmax, __shfl_xor(tmax, 2));
        tmax = fmaxf(tmax, __shfl_xor(tmax, 4));
        tmax = fmaxf(tmax, __shfl_xor(tmax, 8));
        float mo = mrow[qc * 4 + r];
        float mn = fmaxf(mo, tmax);
        float sc = __expf(mo - mn);
        float sum = 0.f;
#pragma unroll
        for (int c = 0; c < 4; ++c) {
          float p = __expf(S[c][r] - mn);
          sum += p;
          Ps[w][lhi * 4 + r][c * 16 + llo] = f2bf(p);
        }
        sum += __shfl_xor(sum, 1); sum += __shfl_xor(sum, 2);
        sum += __shfl_xor(sum, 4); sum += __shfl_xor(sum, 8);
        lrow[qc * 4 + r] = lrow[qc * 4 + r] * sc + sum;
        mrow[qc * 4 + r] = mn;
        scv[r] = sc;
      }
#pragma unroll
      for (int nb = 0; nb < 4; ++nb)
#pragma unroll
        for (int r = 0; r < 4; ++r)
          o[qc][nb][r] *= scv[r];
      asm volatile("s_waitcnt lgkmcnt(0)" ::: "memory");
      __builtin_amdgcn_sched_barrier(0);
#pragma unroll
      for (int kb = 0; kb < 2; ++kb) {
        s8v pa = *(const s8v*)&Ps[w][llo][kb * 32 + lhi * 8];
#pragma unroll
        for (int nb = 0; nb < 4; ++nb) {
          s8v bv = *(const s8v*)&Vt[nb * 16 + llo][kb * 32 + lhi * 8];
          o[qc][nb] = __builtin_amdgcn_mfma_f32_16x16x32_bf16(pa, bv, o[qc][nb], 0, 0, 0);
        }
      }
    }
  }
#pragma unroll
  for (int qc = 0; qc < 4; ++qc)
#pragma unroll
    for (int nb = 0; nb < 4; ++nb)
#pragma unroll
      for (int r = 0; r < 4; ++r) {
        float inv = 1.f / lrow[qc * 4 + r];
        Ob[obase + (size_t)(w * 64 + qc * 16 + lhi * 4 + r) * 512 + nb * 16 + llo] =
            f2f8(o[qc][nb][r] * inv);
      }
}

// ---------------- loss: merge per-tile partials -> per-row nll ----------------
__global__ __launch_bounds__(256) void loss_lse_kernel(const float* __restrict__ pmax,
    const float* __restrict__ psum, const float* __restrict__ logits,
    const int* __restrict__ tgt, float* __restrict__ nll, float* __restrict__ valid) {
  const int w = threadIdx.x >> 6, lane = threadIdx.x & 63;
  const int row = blockIdx.x * 4 + w;
  float m = -1e30f, s = 0.f;
  for (int e = lane; e < 250; e += 64) {
    float pm = pmax[(size_t)row * 250 + e], ps = psum[(size_t)row * 250 + e];
    if (pm > m) { s = s * __expf(m - pm) + ps; m = pm; }
    else          s += ps * __expf(pm - m);
  }
#pragma unroll
  for (int o = 1; o < 64; o <<= 1) {
    float om = __shfl_xor(m, o), os = __shfl_xor(s, o);
    float mm = fmaxf(m, om);
    s = s * __expf(m - mm) + os * __expf(om - mm);
    m = mm;
  }
  if (lane == 0) {
    int t = tgt[row];
    float lse = m + logf(s);
    float v = (t != 1) ? 1.f : 0.f;
    nll[row] = v * (lse - logits[(size_t)row * 32000 + t]);
    valid[row] = v;
  }
}

__global__ __launch_bounds__(256) void loss_final_kernel(const float* __restrict__ nll,
    const float* __restrict__ valid, float* __restrict__ out) {
  __shared__ float sa[256], sb[256];
  int tid = threadIdx.x;
  float s = 0.f, c = 0.f;
  for (int i = tid; i < 16384; i += 256) { s += nll[i]; c += valid[i]; }
  sa[tid] = s; sb[tid] = c;
  __syncthreads();
  for (int st = 128; st > 0; st >>= 1) {
    if (tid < st) { sa[tid] += sa[tid + st]; sb[tid] += sb[tid + st]; }
    __syncthreads();
  }
  if (tid == 0) out[0] = sa[0] / fmaxf(sb[0], 1.f);
}

// =============================== host ===============================
extern "C" void kernel_launch(void* const* d_in, const int* in_sizes, int n_in,
                              void* d_out, int out_size, void* d_ws, size_t ws_size,
                              hipStream_t stream) {
  (void)in_sizes; (void)n_in; (void)out_size; (void)ws_size;
  const int* idx       = (const int*)d_in[0];
  const int* idx_enc   = (const int*)d_in[1];
  const int* targets   = (const int*)d_in[2];
  const float* emb_dec = (const float*)d_in[3];
  const float* emb_enc = (const float*)d_in[4];
  const float* enc_Wq  = (const float*)d_in[5];
  const float* enc_Wk  = (const float*)d_in[6];
  const float* enc_Wv  = (const float*)d_in[7];
  const float* enc_Wo  = (const float*)d_in[8];
  const float* enc_bo  = (const float*)d_in[9];
  const float* enc_ln_g = (const float*)d_in[10];
  const float* enc_ln_b = (const float*)d_in[11];
  const float* enc_W1  = (const float*)d_in[12];
  const float* enc_b1  = (const float*)d_in[13];
  const float* enc_W2  = (const float*)d_in[14];
  const float* enc_b2  = (const float*)d_in[15];
  const float* dWq_sa  = (const float*)d_in[16];
  const float* dWk_sa  = (const float*)d_in[17];
  const float* dWv_sa  = (const float*)d_in[18];
  const float* dWo_sa  = (const float*)d_in[19];
  const float* dbo_sa  = (const float*)d_in[20];
  const float* dWq_xa  = (const float*)d_in[21];
  const float* dWk_xa  = (const float*)d_in[22];
  const float* dWv_xa  = (const float*)d_in[23];
  const float* dWo_xa  = (const float*)d_in[24];
  const float* dbo_xa  = (const float*)d_in[25];
  const float* dec_ln_g = (const float*)d_in[26];
  const float* dec_ln_b = (const float*)d_in[27];
  const float* dec_W1  = (const float*)d_in[28];
  const float* dec_b1  = (const float*)d_in[29];
  const float* dec_W2  = (const float*)d_in[30];
  const float* dec_b2  = (const float*)d_in[31];
  const float* lnf_g   = (const float*)d_in[32];
  const float* lnf_b   = (const float*)d_in[33];
  const float* Wlm     = (const float*)d_in[34];
  const float* blm     = (const float*)d_in[35];
  float* out_logits = (float*)d_out;
  float* out_loss   = out_logits + (size_t)16384 * 32000;

  size_t off = 0;
  auto alloc = [&](size_t bytes) -> char* {
    char* p = (char*)d_ws + off;
    off += (bytes + 255) & ~(size_t)255;
    return p;
  };
  const size_t SQ = 512 * 512, SF = 512 * 2048;
  u16* tWqkvE = (u16*)alloc(6 * 3 * SQ * 2);
  u8*  tWoE   = (u8*)alloc(6 * SQ);
  u8*  tW1E   = (u8*)alloc(6 * SF);
  u8*  tW2E   = (u8*)alloc(6 * SF);
  u16* tWqkvS = (u16*)alloc(6 * 3 * SQ * 2);
  u8*  tWoS   = (u8*)alloc(6 * SQ);
  u16* tWqX   = (u16*)alloc(6 * SQ * 2);
  u16* tWkvX  = (u16*)alloc(6 * 2 * SQ * 2);
  u8*  tWoX   = (u8*)alloc(6 * SQ);
  u8*  tW1D   = (u8*)alloc(6 * SF);
  u8*  tW2D   = (u8*)alloc(6 * SF);
  u16* tWlm   = (u16*)alloc((size_t)32000 * 512 * 2);
  float* pe   = (float*)alloc(256 * 512 * 4);
  float* yE   = (float*)alloc((size_t)16384 * 512 * 4);
  float* xD   = (float*)alloc((size_t)16384 * 512 * 4);
  u16* hA     = (u16*)alloc((size_t)16384 * 512 * 2);   // bf16 or fp8 (reused)
  u16* hB     = (u16*)alloc((size_t)16384 * 512 * 2);
  u16* qkvB   = (u16*)alloc((size_t)16384 * 1536 * 2);
  u16* qB     = (u16*)alloc((size_t)16384 * 512 * 2);
  u16* kvB    = (u16*)alloc((size_t)16384 * 1024 * 2);
  u8*  atB    = (u8*)alloc((size_t)16384 * 512);
  u8*  midB   = (u8*)alloc((size_t)16384 * 2048);
  float* pmax = (float*)alloc((size_t)16384 * 250 * 4);
  float* psum = (float*)alloc((size_t)16384 * 250 * 4);
  float* rnll = (float*)alloc(16384 * 4);
  float* rval = (float*)alloc(16384 * 4);

  // ---- weight conversion ----
  dim3 tb(256);
  const size_t S3 = 3 * SQ, S2 = 2 * SQ;
  {
    WcSq S;
    S.src[0] = enc_Wq;  S.dst[0] = tWqkvE + 0 * SQ; S.dstr[0] = S3;
    S.src[1] = enc_Wk;  S.dst[1] = tWqkvE + 1 * SQ; S.dstr[1] = S3;
    S.src[2] = enc_Wv;  S.dst[2] = tWqkvE + 2 * SQ; S.dstr[2] = S3;
    S.src[3] = enc_Wo;  S.dst[3] = tWoE;            S.dstr[3] = SQ;
    S.src[4] = dWq_sa;  S.dst[4] = tWqkvS + 0 * SQ; S.dstr[4] = S3;
    S.src[5] = dWk_sa;  S.dst[5] = tWqkvS + 1 * SQ; S.dstr[5] = S3;
    S.src[6] = dWv_sa;  S.dst[6] = tWqkvS + 2 * SQ; S.dstr[6] = S3;
    S.src[7] = dWo_sa;  S.dst[7] = tWoS;            S.dstr[7] = SQ;
    S.src[8] = dWq_xa;  S.dst[8] = tWqX;            S.dstr[8] = SQ;
    S.src[9] = dWk_xa;  S.dst[9] = tWkvX + 0 * SQ;  S.dstr[9] = S2;
    S.src[10] = dWv_xa; S.dst[10] = tWkvX + 1 * SQ; S.dstr[10] = S2;
    S.src[11] = dWo_xa; S.dst[11] = tWoX;           S.dstr[11] = SQ;
    S.fp8m = (1u << 3) | (1u << 7) | (1u << 11);
    wconv_sq_kernel<<<dim3(8, 8, 72), tb, 0, stream>>>(S);
  }
  wconv_kernel<1><<<dim3(8, 32, 6), tb, 0, stream>>>(enc_W1, tW1E, 512, 2048, SF);
  wconv_kernel<1><<<dim3(32, 8, 6), tb, 0, stream>>>(enc_W2, tW2E, 2048, 512, SF);
  wconv_kernel<1><<<dim3(8, 32, 6), tb, 0, stream>>>(dec_W1, tW1D, 512, 2048, SF);
  wconv_kernel<1><<<dim3(32, 8, 6), tb, 0, stream>>>(dec_W2, tW2D, 2048, 512, SF);
  wconv_kernel<0><<<dim3(8, 500, 1), tb, 0, stream>>>(Wlm, tWlm, 512, 32000, (size_t)0);
  pe_kernel<<<256, 256, 0, stream>>>(pe);

  auto ln16 = [&](const float* xin, const float* g, const float* bb, u16* o) {
    ln_kernel<0><<<4096, 256, 0, stream>>>(xin, g, bb, o);
  };
  auto ln8 = [&](const float* xin, const float* g, const float* bb, void* o) {
    ln_kernel<1><<<4096, 256, 0, stream>>>(xin, g, bb, o);
  };
  auto g_bf16 = [&](const u16* Ap, const u16* Bp, u16* Op, int N) {
    gemm128<0, 1, 0, 0, 0, 0, 0, 0, 0><<<dim3(128, N / 128), 256, 0, stream>>>(
        Ap, Bp, nullptr, nullptr, Op, 16384, N, 512, nullptr, nullptr,
        nullptr, nullptr, nullptr);
  };
  auto g_qkv_x = [&](const u16* Aq, const u16* Bq, u16* Oq,
                     const u16* Akv, const u16* Bkv, u16* Okv) {
    gemm128<0, 1, 0, 0, 0, 0, 0, 0, 1><<<dim3(128, 12), 256, 0, stream>>>(
        Aq, Bq, nullptr, nullptr, Oq, 16384, 512, 512, nullptr, nullptr,
        Akv, Bkv, Okv);
  };
  auto proj_res8 = [&](const u8* Ap, const u8* Bp, const float* bi, float* xr, int K) {
    gemm128<1, 0, 1, 1, 0, 0, 0, 0, 0><<<dim3(128, 4), 256, 0, stream>>>(
        Ap, Bp, bi, xr, xr, 16384, 512, K, nullptr, nullptr,
        nullptr, nullptr, nullptr);
  };
  auto ffn1_8 = [&](const u8* Ap, const u8* Bp, const float* bi, u8* Op) {
    gemm128<1, 2, 1, 0, 1, 0, 0, 0, 0><<<dim3(128, 16), 256, 0, stream>>>(
        Ap, Bp, bi, nullptr, Op, 16384, 2048, 512, nullptr, nullptr,
        nullptr, nullptr, nullptr);
  };

  // ---------------- encoder ----------------
  emb_ln_kernel<<<4096, 256, 0, stream>>>(idx_enc, emb_enc, pe,
      enc_ln_g + 0, enc_ln_b + 0, yE, hA);
  for (int l = 0; l < 6; ++l) {
    if (l) ln16(yE, enc_ln_g + (l * 2 + 0) * 512, enc_ln_b + (l * 2 + 0) * 512, hA);
    g_bf16(hA, tWqkvE + l * S3, qkvB, 1536);
    attn_kernel<<<512, 256, 0, stream>>>(qkvB, 1536, qkvB + 512, qkvB + 1024, 1536, atB, 0);
    proj_res8(atB, tWoE + l * SQ, enc_bo + l * 512, yE, 512);
    ln8(yE, enc_ln_g + (l * 2 + 1) * 512, enc_ln_b + (l * 2 + 1) * 512, hA);
    ffn1_8((const u8*)hA, tW1E + l * SF, enc_b1 + l * 2048, midB);
    proj_res8(midB, tW2E + l * SF, enc_b2 + l * 512, yE, 2048);
  }

  // ---------------- decoder ----------------
  emb_ln_kernel<<<4096, 256, 0, stream>>>(idx, emb_dec, pe,
      dec_ln_g + 0, dec_ln_b + 0, xD, hA);
  for (int l = 0; l < 6; ++l) {
    if (l) ln16(xD, dec_ln_g + (l * 4 + 0) * 512, dec_ln_b + (l * 4 + 0) * 512, hA);
    g_bf16(hA, tWqkvS + l * S3, qkvB, 1536);
    attn_kernel<<<512, 256, 0, stream>>>(qkvB, 1536, qkvB + 512, qkvB + 1024, 1536, atB, 1);
    proj_res8(atB, tWoS + l * SQ, dbo_sa + l * 512, xD, 512);
    ln2_kernel<<<8192, 256, 0, stream>>>(
        xD, dec_ln_g + (l * 4 + 1) * 512, dec_ln_b + (l * 4 + 1) * 512, hA,
        yE, dec_ln_g + (l * 4 + 2) * 512, dec_ln_b + (l * 4 + 2) * 512, hB);
    g_qkv_x(hA, tWqX + l * SQ, qB, hB, tWkvX + l * S2, kvB);
    attn_kernel<<<512, 256, 0, stream>>>(qB, 512, kvB, kvB + 512, 1024, atB, 0);
    proj_res8(atB, tWoX + l * SQ, dbo_xa + l * 512, xD, 512);
    ln8(xD, dec_ln_g + (l * 4 + 3) * 512, dec_ln_b + (l * 4 + 3) * 512, hA);
    ffn1_8((const u8*)hA, tW1D + l * SF, dec_b1 + l * 2048, midB);
    proj_res8(midB, tW2D + l * SF, dec_b2 + l * 512, xD, 2048);
  }

  // -------- LM head (bf16, fused loss partials, nt logits, row-panel swizzle) ----
  ln16(xD, lnf_g, lnf_b, hA);
  gemm128<0, 0, 1, 0, 0, 1, 1, 1, 0><<<dim3(128, 250), 256, 0, stream>>>(
      hA, tWlm, blm, nullptr, out_logits, 16384, 32000, 512, pmax, psum,
      nullptr, nullptr, nullptr);
  loss_lse_kernel<<<4096, 256, 0, stream>>>(pmax, psum, out_logits, targets, rnll, rval);
  loss_final_kernel<<<1, 256, 0, stream>>>(rnll, rval, out_loss);
}

// Round 12
// 4322.068 us; speedup vs baseline: 1.3935x; 1.0408x over previous
//
#include <hip/hip_runtime.h>

typedef __attribute__((ext_vector_type(8))) short s8v;
typedef __attribute__((ext_vector_type(4))) float f4v;
typedef __attribute__((ext_vector_type(4))) unsigned short us4;
using u16 = unsigned short;
using u8 = unsigned char;

__device__ __forceinline__ u16 f2bf(float f) {
  union { float f; unsigned u; } v; v.f = f;
  return (u16)((v.u + 0x7FFFu + ((v.u >> 16) & 1u)) >> 16);
}
__device__ __forceinline__ float b2f(u16 x) {
  union { unsigned u; float f; } v; v.u = (unsigned)x << 16;
  return v.f;
}

// f32 -> OCP e4m3fn, RNE, saturate-to-448
__device__ __forceinline__ u8 f2f8(float f) {
  union { float f; unsigned u; } v; v.f = f;
  unsigned s = (v.u >> 24) & 0x80;
  v.u &= 0x7fffffff;
  if (!(v.f < 448.f)) return (u8)(s | 0x7e);
  if (v.f < 0.015625f) {
    int q = (int)(v.f * 512.f + 0.5f);
    return (u8)(s | (unsigned)q);
  }
  unsigned u = v.u + 0x7FFFFu + ((v.u >> 20) & 1u);
  int e = (int)(u >> 23) - 127;
  unsigned m = (u >> 20) & 7u;
  unsigned code = ((unsigned)(e + 7) << 3) | m;
  if (code > 0x7e) code = 0x7e;
  return (u8)(s | code);
}

// ---------------- positional encoding: pe[256][512] ----------------
__global__ __launch_bounds__(256) void pe_kernel(float* __restrict__ pe) {
  int i = blockIdx.x * 256 + threadIdx.x;
  int t = i >> 8, p = i & 255;
  float ex = (2.f * (float)p) / 512.f;
  float ang = (float)t * expf(-ex * 9.210340371976184f);
  pe[t * 512 + 2 * p]     = sinf(ang);
  pe[t * 512 + 2 * p + 1] = cosf(ang);
}

// -------- weight convert: f32 [R][C] -> {bf16|fp8} [C][R] --------
template<int FP8>
__global__ __launch_bounds__(256) void wconv_kernel(const float* __restrict__ in,
    void* __restrict__ out, int R, int C, size_t dstride) {
  __shared__ float tile[64][65];
  const size_t mat = (size_t)R * C;
  const float* src = in + (size_t)blockIdx.z * mat;
  int r0 = blockIdx.x * 64, c0 = blockIdx.y * 64;
  int tr = threadIdx.x >> 6, tc = threadIdx.x & 63;
#pragma unroll
  for (int i = 0; i < 16; ++i)
    tile[i * 4 + tr][tc] = src[(size_t)(r0 + i * 4 + tr) * C + (c0 + tc)];
  __syncthreads();
#pragma unroll
  for (int i = 0; i < 16; ++i) {
    size_t di = (size_t)(c0 + i * 4 + tr) * R + (r0 + tc);
    float val = tile[tc][i * 4 + tr];
    if (FP8) ((u8*)out + (size_t)blockIdx.z * dstride)[di] = f2f8(val);
    else     ((u16*)out + (size_t)blockIdx.z * dstride)[di] = f2bf(val);
  }
}

// -------- batched square (512x512) weight convert: 12 stacks, fp8 mask ----
struct WcSq { const float* src[12]; void* dst[12]; unsigned long long dstr[12]; unsigned fp8m; };
__global__ __launch_bounds__(256) void wconv_sq_kernel(WcSq S) {
  __shared__ float tile[64][65];
  int mm = blockIdx.z / 6, l = blockIdx.z % 6;
  const float* src = S.src[mm] + (size_t)l * 512 * 512;
  int fp8 = (S.fp8m >> mm) & 1;
  int r0 = blockIdx.x * 64, c0 = blockIdx.y * 64;
  int tr = threadIdx.x >> 6, tc = threadIdx.x & 63;
#pragma unroll
  for (int i = 0; i < 16; ++i)
    tile[i * 4 + tr][tc] = src[(size_t)(r0 + i * 4 + tr) * 512 + (c0 + tc)];
  __syncthreads();
#pragma unroll
  for (int i = 0; i < 16; ++i) {
    size_t di = (size_t)(c0 + i * 4 + tr) * 512 + (r0 + tc);
    float val = tile[tc][i * 4 + tr];
    if (fp8) ((u8*)S.dst[mm] + (size_t)l * S.dstr[mm])[di] = f2f8(val);
    else     ((u16*)S.dst[mm] + (size_t)l * S.dstr[mm])[di] = f2bf(val);
  }
}

// -------- LN body (wave per row), f32 inputs, templated output dtype --------
template<int FP8>
__device__ __forceinline__ void ln_row(f4v v0, f4v v1, const float* g, const float* b,
                                       int lane, void* outrow) {
  float s = v0[0] + v0[1] + v0[2] + v0[3] + v1[0] + v1[1] + v1[2] + v1[3];
#pragma unroll
  for (int o = 1; o < 64; o <<= 1) s += __shfl_xor(s, o);
  float mu = s * (1.f / 512.f);
  float q = 0.f;
#pragma unroll
  for (int j = 0; j < 4; ++j) {
    float d0 = v0[j] - mu; q += d0 * d0;
    float d1 = v1[j] - mu; q += d1 * d1;
  }
#pragma unroll
  for (int o = 1; o < 64; o <<= 1) q += __shfl_xor(q, o);
  float rs = rsqrtf(q * (1.f / 512.f) + 1e-5f);
  f4v g0 = *(const f4v*)(g + lane * 8), g1 = *(const f4v*)(g + lane * 8 + 4);
  f4v b0 = *(const f4v*)(b + lane * 8), b1 = *(const f4v*)(b + lane * 8 + 4);
  if (FP8) {
    unsigned long long ov = 0;
#pragma unroll
    for (int j = 0; j < 4; ++j) {
      ov |= (unsigned long long)f2f8((v0[j] - mu) * rs * g0[j] + b0[j]) << (8 * j);
      ov |= (unsigned long long)f2f8((v1[j] - mu) * rs * g1[j] + b1[j]) << (8 * (4 + j));
    }
    *(unsigned long long*)((u8*)outrow + lane * 8) = ov;
  } else {
    s8v ov;
#pragma unroll
    for (int j = 0; j < 4; ++j) {
      ov[j]     = (short)f2bf((v0[j] - mu) * rs * g0[j] + b0[j]);
      ov[4 + j] = (short)f2bf((v1[j] - mu) * rs * g1[j] + b1[j]);
    }
    *(s8v*)((u16*)outrow + lane * 8) = ov;
  }
}

__device__ __forceinline__ void ldbf16x8(const u16* p, f4v& v0, f4v& v1) {
  s8v raw = *(const s8v*)p;
#pragma unroll
  for (int j = 0; j < 4; ++j) {
    v0[j] = b2f((u16)raw[j]);
    v1[j] = b2f((u16)raw[4 + j]);
  }
}

// -------- LN over bf16 residual stream --------
template<int FP8>
__global__ __launch_bounds__(256) void ln_kernel(const u16* __restrict__ x,
    const float* __restrict__ g, const float* __restrict__ b, void* __restrict__ out) {
  int row = blockIdx.x * 4 + (threadIdx.x >> 6);
  int lane = threadIdx.x & 63;
  f4v v0, v1;
  ldbf16x8(x + (size_t)row * 512 + lane * 8, v0, v1);
  void* orow = FP8 ? (void*)((u8*)out + (size_t)row * 512)
                   : (void*)((u16*)out + (size_t)row * 512);
  ln_row<FP8>(v0, v1, g, b, lane, orow);
}

// -------- dual LN (both bf16 in, bf16 out) --------
__global__ __launch_bounds__(256) void ln2_kernel(
    const u16* __restrict__ x1, const float* __restrict__ g1, const float* __restrict__ b1,
    u16* __restrict__ o1, const u16* __restrict__ x2, const float* __restrict__ g2,
    const float* __restrict__ b2, u16* __restrict__ o2) {
  int row = blockIdx.x * 4 + (threadIdx.x >> 6);
  int lane = threadIdx.x & 63;
  const u16* x = x1; const float* g = g1; const float* b = b1; u16* o = o1;
  if (row >= 16384) { row -= 16384; x = x2; g = g2; b = b2; o = o2; }
  f4v v0, v1;
  ldbf16x8(x + (size_t)row * 512 + lane * 8, v0, v1);
  ln_row<0>(v0, v1, g, b, lane, o + (size_t)row * 512);
}

// -------- fused embedding + pe + layer-0 LN: writes y (bf16) and h (bf16) ----
__global__ __launch_bounds__(256) void emb_ln_kernel(const int* __restrict__ idx,
    const float* __restrict__ emb, const float* __restrict__ pe,
    const float* __restrict__ g, const float* __restrict__ b,
    u16* __restrict__ y, u16* __restrict__ h) {
  int row = blockIdx.x * 4 + (threadIdx.x >> 6);
  int lane = threadIdx.x & 63;
  int tok = idx[row], t = row & 255;
  const float* e = emb + (size_t)tok * 512 + lane * 8;
  const float* p = pe + (size_t)t * 512 + lane * 8;
  f4v v0 = *(const f4v*)e + *(const f4v*)p;
  f4v v1 = *(const f4v*)(e + 4) + *(const f4v*)(p + 4);
  s8v yv;
#pragma unroll
  for (int j = 0; j < 4; ++j) {
    yv[j] = (short)f2bf(v0[j]);
    yv[4 + j] = (short)f2bf(v1[j]);
  }
  *(s8v*)(y + (size_t)row * 512 + lane * 8) = yv;
  ln_row<0>(v0, v1, g, b, lane, h + (size_t)row * 512);
}

// ======== GEMM: C[M,N] = A[M,K] @ Bt[N,K]^T, bf16 or fp8-e4m3 operands ======
// 128x128 tile, 4 waves, single-buffered 32KB LDS, T2 XOR swizzle.
// bf16: BK=64. fp8: BK=128 (same 128B row; halves barrier count).
// OMODE: 0=f32 out (+WLOSS/NT, LM head), 1=bf16 out, 2=fp8 out,
//        3=bf16 residual out (ADD_RES reads bf16 res, LDS-transposed stores).
template<int AB8, int OMODE, int HAS_BIAS, int ADD_RES, int RELU, int WLOSS,
         int NT, int SWZM, int DUAL>
__global__ __launch_bounds__(256, 4) void gemm128(
    const void* __restrict__ Av, const void* __restrict__ Btv,
    const float* __restrict__ bias, const void* __restrict__ res,
    void* __restrict__ outp, int M, int N, int K,
    float* __restrict__ pmax, float* __restrict__ psum,
    const void* __restrict__ A2, const void* __restrict__ Bt2,
    void* __restrict__ out2) {
  __shared__ __align__(16) u8 smem[32768];
  const int tid = threadIdx.x, lane = tid & 63, w = tid >> 6;
  int bx, by;
  if (SWZM == 1) {
    int flat = blockIdx.y * gridDim.x + blockIdx.x;
    int xcd = flat & 7, local = flat >> 3;
    int p = local / gridDim.y;
    by = local - p * gridDim.y;
    bx = xcd * (gridDim.x >> 3) + p;
  } else {
    int nx = gridDim.x;
    int flat = blockIdx.y * nx + blockIdx.x;
    int per = (nx * gridDim.y) >> 3;
    int sw = (flat & 7) * per + (flat >> 3);
    by = sw / nx; bx = sw - by * nx;
  }
  const void* Ause = Av; const void* Buse = Btv; void* Ouse = outp;
  int Nn = N;
  if (DUAL && by >= 4) { Ause = A2; Buse = Bt2; Ouse = out2; Nn = 1024; by -= 4; }
  const int m0 = bx * 128, n0 = by * 128;
  const int wm = (w >> 1) * 64, wn = (w & 1) * 64;
  const int lhi = lane >> 4, llo = lane & 15;
  const int srow = tid >> 3, sl = tid & 7;

  f4v acc[4][4] = {};

  if (AB8) {
    const u8* A = (const u8*)Ause;
    const u8* Bt = (const u8*)Buse;
    u8* As8 = smem;
    u8* Bs8 = smem + 16384;
    const int gcolb = (sl ^ (srow & 7)) * 16;
    const u8* Ag = A + (size_t)(m0 + srow) * K + gcolb;
    const u8* Bg = Bt + (size_t)(n0 + srow) * K + gcolb;
    const size_t rstep = (size_t)32 * K;
    const int sxb = llo & 7;
    const int nk = K >> 7;
    for (int t = 0; t < nk; ++t) {
      const int kt = t * 128;
#pragma unroll
      for (int q = 0; q < 4; ++q)
        __builtin_amdgcn_global_load_lds(
            (const __attribute__((address_space(1))) void*)(Ag + q * rstep + kt),
            (__attribute__((address_space(3))) void*)(&As8[(q * 32 + srow) * 128 + sl * 16]),
            16, 0, 0);
#pragma unroll
      for (int q = 0; q < 4; ++q)
        __builtin_amdgcn_global_load_lds(
            (const __attribute__((address_space(1))) void*)(Bg + q * rstep + kt),
            (__attribute__((address_space(3))) void*)(&Bs8[(q * 32 + srow) * 128 + sl * 16]),
            16, 0, 0);
      __syncthreads();
#pragma unroll
      for (int kk = 0; kk < 4; ++kk) {
        const int slot8 = kk * 4 + lhi;
        const int lbyte = (((slot8 >> 1) ^ sxb) * 16) + ((slot8 & 1) * 8);
        long af[4], bf8[4];
#pragma unroll
        for (int i = 0; i < 4; ++i)
          af[i] = *(const long*)&As8[(wm + i * 16 + llo) * 128 + lbyte];
#pragma unroll
        for (int j = 0; j < 4; ++j)
          bf8[j] = *(const long*)&Bs8[(wn + j * 16 + llo) * 128 + lbyte];
#pragma unroll
        for (int i = 0; i < 4; ++i)
#pragma unroll
          for (int j = 0; j < 4; ++j)
            acc[i][j] = __builtin_amdgcn_mfma_f32_16x16x32_fp8_fp8(af[i], bf8[j], acc[i][j], 0, 0, 0);
      }
      __syncthreads();
    }
  } else {
    const u16* A = (const u16*)Ause;
    const u16* Bt = (const u16*)Buse;
    u16* As = (u16*)smem;
    u16* Bs = (u16*)(smem + 16384);
    const int gcol = (sl ^ (srow & 7)) * 8;
    const u16* Ag = A + (size_t)(m0 + srow) * K + gcol;
    const u16* Bg = Bt + (size_t)(n0 + srow) * K + gcol;
    const size_t rstep = (size_t)32 * K;
    const int sx = llo & 7;
    const int nk = K >> 6;
    for (int t = 0; t < nk; ++t) {
      const int kt = t * 64;
#pragma unroll
      for (int q = 0; q < 4; ++q)
        __builtin_amdgcn_global_load_lds(
            (const __attribute__((address_space(1))) void*)(Ag + q * rstep + kt),
            (__attribute__((address_space(3))) void*)(&As[(q * 32 + srow) * 64 + sl * 8]),
            16, 0, 0);
#pragma unroll
      for (int q = 0; q < 4; ++q)
        __builtin_amdgcn_global_load_lds(
            (const __attribute__((address_space(1))) void*)(Bg + q * rstep + kt),
            (__attribute__((address_space(3))) void*)(&Bs[(q * 32 + srow) * 64 + sl * 8]),
            16, 0, 0);
      __syncthreads();
#pragma unroll
      for (int kk = 0; kk < 2; ++kk) {
        s8v af[4], bfv[4];
#pragma unroll
        for (int i = 0; i < 4; ++i)
          af[i] = *(const s8v*)&As[(wm + i * 16 + llo) * 64 + (((kk * 4 + lhi) ^ sx) * 8)];
#pragma unroll
        for (int j = 0; j < 4; ++j)
          bfv[j] = *(const s8v*)&Bs[(wn + j * 16 + llo) * 64 + (((kk * 4 + lhi) ^ sx) * 8)];
#pragma unroll
        for (int i = 0; i < 4; ++i)
#pragma unroll
          for (int j = 0; j < 4; ++j)
            acc[i][j] = __builtin_amdgcn_mfma_f32_16x16x32_bf16(af[i], bfv[j], acc[i][j], 0, 0, 0);
      }
      __syncthreads();
    }
  }

  // ---- epilogue (D row = (l>>4)*4 + r, col = l&15 — verified layout) ----
  if (OMODE == 1 || OMODE == 2) {
    float bvj[4];
#pragma unroll
    for (int j = 0; j < 4; ++j)
      bvj[j] = HAS_BIAS ? bias[n0 + wn + j * 16 + llo] : 0.f;
#pragma unroll
    for (int i = 0; i < 4; ++i) {
#pragma unroll
      for (int j = 0; j < 4; ++j) {
        int col = n0 + wn + j * 16 + llo;
#pragma unroll
        for (int r = 0; r < 4; ++r) {
          int row = m0 + wm + i * 16 + lhi * 4 + r;
          float v = acc[i][j][r] + bvj[j];
          if (RELU) v = fmaxf(v, 0.f);
          if (OMODE == 1) ((u16*)Ouse)[(size_t)row * Nn + col] = f2bf(v);
          else            ((u8*)Ouse)[(size_t)row * Nn + col] = f2f8(v);
        }
      }
    }
  } else {
    // transposed coalesced path: wave-private LDS [16][68] f32
    float* lb = (float*)smem;
    float* wbuf = lb + w * 1088;
    float* lbm = lb + 4608;
    float* lbs = lb + 4864;
    f4v bias4 = {0.f, 0.f, 0.f, 0.f};
    if (HAS_BIAS) bias4 = *(const f4v*)(bias + n0 + wn + llo * 4);
#pragma unroll
    for (int i = 0; i < 4; ++i) {
#pragma unroll
      for (int j = 0; j < 4; ++j)
#pragma unroll
        for (int r = 0; r < 4; ++r)
          wbuf[(lhi * 4 + r) * 68 + j * 16 + llo] = acc[i][j][r];
      asm volatile("s_waitcnt lgkmcnt(0)" ::: "memory");
      __builtin_amdgcn_sched_barrier(0);
#pragma unroll
      for (int p = 0; p < 4; ++p) {
        int r16 = p * 4 + lhi;
        f4v v4 = *(const f4v*)&wbuf[r16 * 68 + llo * 4];
        v4 += bias4;
        int grow = m0 + wm + i * 16 + r16;
        int gcol4 = n0 + wn + llo * 4;
        if (OMODE == 3) {
          if (ADD_RES) {
            us4 rv = *(const us4*)((const u16*)res + (size_t)grow * Nn + gcol4);
#pragma unroll
            for (int j = 0; j < 4; ++j) v4[j] += b2f(rv[j]);
          }
          if (RELU) {
            v4[0] = fmaxf(v4[0], 0.f); v4[1] = fmaxf(v4[1], 0.f);
            v4[2] = fmaxf(v4[2], 0.f); v4[3] = fmaxf(v4[3], 0.f);
          }
          us4 ov;
#pragma unroll
          for (int j = 0; j < 4; ++j) ov[j] = f2bf(v4[j]);
          *(us4*)((u16*)Ouse + (size_t)grow * Nn + gcol4) = ov;
        } else {
          if (RELU) {
            v4[0] = fmaxf(v4[0], 0.f); v4[1] = fmaxf(v4[1], 0.f);
            v4[2] = fmaxf(v4[2], 0.f); v4[3] = fmaxf(v4[3], 0.f);
          }
          float* dst = (float*)Ouse + (size_t)grow * Nn + gcol4;
          if (NT) __builtin_nontemporal_store(v4, (f4v*)dst);
          else    *(f4v*)dst = v4;
          if (WLOSS) {
            float mx = fmaxf(fmaxf(v4[0], v4[1]), fmaxf(v4[2], v4[3]));
            mx = fmaxf(mx, __shfl_xor(mx, 1));
            mx = fmaxf(mx, __shfl_xor(mx, 2));
            mx = fmaxf(mx, __shfl_xor(mx, 4));
            mx = fmaxf(mx, __shfl_xor(mx, 8));
            float sum = __expf(v4[0] - mx) + __expf(v4[1] - mx)
                      + __expf(v4[2] - mx) + __expf(v4[3] - mx);
            sum += __shfl_xor(sum, 1); sum += __shfl_xor(sum, 2);
            sum += __shfl_xor(sum, 4); sum += __shfl_xor(sum, 8);
            if (llo == 0) {
              int lr = wm + i * 16 + r16;
              lbm[lr * 2 + (wn >> 6)] = mx;
              lbs[lr * 2 + (wn >> 6)] = sum;
            }
          }
        }
      }
      asm volatile("s_waitcnt lgkmcnt(0)" ::: "memory");
      __builtin_amdgcn_sched_barrier(0);
    }
    if (WLOSS) {
      __syncthreads();
      if (tid < 128) {
        float ma = lbm[tid * 2], mb = lbm[tid * 2 + 1];
        float sa = lbs[tid * 2], sb = lbs[tid * 2 + 1];
        float m = fmaxf(ma, mb);
        float ss = sa * __expf(ma - m) + sb * __expf(mb - m);
        int ntile = Nn >> 7;
        pmax[(size_t)(m0 + tid) * ntile + by] = m;
        psum[(size_t)(m0 + tid) * ntile + by] = ss;
      }
    }
  }
}

// ======== flash-tile attention (bf16 in, fp8 out), one (b,h)/block ========
__global__ __launch_bounds__(256, 2) void attn_kernel(
    const u16* __restrict__ Qp, int qs, const u16* __restrict__ Kp,
    const u16* __restrict__ Vp, int kvs, u8* __restrict__ Ob, int causal) {
  __shared__ __align__(16) u16 Ks[64][72];
  __shared__ __align__(16) u16 Vt[64][66];
  __shared__ __align__(16) u16 Ps[4][16][66];
  const int tid = threadIdx.x, lane = tid & 63, w = tid >> 6;
  const int b = blockIdx.x >> 3, h = blockIdx.x & 7;
  const size_t qbase  = (size_t)b * 256 * qs  + (size_t)h * 64;
  const size_t kvbase = (size_t)b * 256 * kvs + (size_t)h * 64;
  const size_t obase  = (size_t)b * 256 * 512 + (size_t)h * 64;
  const int lhi = lane >> 4, llo = lane & 15;
  s8v aq0[4], aq1[4];
#pragma unroll
  for (int qc = 0; qc < 4; ++qc) {
    const u16* qp = Qp + qbase + (size_t)(w * 64 + qc * 16 + llo) * qs;
    aq0[qc] = *(const s8v*)(qp + lhi * 8);
    aq1[qc] = *(const s8v*)(qp + 32 + lhi * 8);
  }
  f4v o[4][4] = {};
  float mrow[16], lrow[16];
#pragma unroll
  for (int i = 0; i < 16; ++i) { mrow[i] = -1e30f; lrow[i] = 0.f; }

  for (int kt = 0; kt < 4; ++kt) {
    if (kt) __syncthreads();
    {
      int tr = tid >> 3, d0 = (tid & 7) * 8;
#pragma unroll
      for (int it = 0; it < 2; ++it) {
        int t = it * 32 + tr;
        const u16* kp = Kp + kvbase + (size_t)(kt * 64 + t) * kvs + d0;
        *(s8v*)&Ks[t][d0] = *(const s8v*)kp;
        s8v vv = *(const s8v*)(Vp + kvbase + (size_t)(kt * 64 + t) * kvs + d0);
#pragma unroll
        for (int j = 0; j < 8; ++j) Vt[d0 + j][t] = (u16)vv[j];
      }
    }
    __syncthreads();
#pragma unroll
    for (int qc = 0; qc < 4; ++qc) {
      if (causal && kt * 64 > w * 64 + qc * 16 + 15) continue;
      f4v S[4];
#pragma unroll
      for (int c = 0; c < 4; ++c) {
        s8v bk0 = *(const s8v*)&Ks[c * 16 + llo][lhi * 8];
        s8v bk1 = *(const s8v*)&Ks[c * 16 + llo][32 + lhi * 8];
        f4v z = {0.f, 0.f, 0.f, 0.f};
        z = __builtin_amdgcn_mfma_f32_16x16x32_bf16(aq0[qc], bk0, z, 0, 0, 0);
        S[c] = __builtin_amdgcn_mfma_f32_16x16x32_bf16(aq1[qc], bk1, z, 0, 0, 0);
      }
      float scv[4];
#pragma unroll
      for (int r = 0; r < 4; ++r) {
        const int tq = w * 64 + qc * 16 + lhi * 4 + r;
        float tmax = -1e30f;
#pragma unroll
        for (int c = 0; c < 4; ++c) {
          float s = S[c][r] * 0.125f;
          if (causal && (kt * 64 + c * 16 + llo) > tq) s = -1e30f;
          S[c][r] = s;
          tmax = fmaxf(tmax, s);
        }
        tmax = fmaxf(tmax, __shfl_xor(tmax, 1));
        tmax = fmaxf(tmax, __shfl_xor(tmax, 2));
        tmax = fmaxf(tmax, __shfl_xor(tmax, 4));
        tmax = fmaxf(tmax, __shfl_xor(tmax, 8));
        float mo = mrow[qc * 4 + r];
        float mn = fmaxf(mo, tmax);
        float sc = __expf(mo - mn);
        float sum = 0.f;
#pragma unroll
        for (int c = 0; c < 4; ++c) {
          float p = __expf(S[c][r] - mn);
          sum += p;
          Ps[w][lhi * 4 + r][c * 16 + llo] = f2bf(p);
        }
        sum += __shfl_xor(sum, 1); sum += __shfl_xor(sum, 2);
        sum += __shfl_xor(sum, 4); sum += __shfl_xor(sum, 8);
        lrow[qc * 4 + r] = lrow[qc * 4 + r] * sc + sum;
        mrow[qc * 4 + r] = mn;
        scv[r] = sc;
      }
#pragma unroll
      for (int nb = 0; nb < 4; ++nb)
#pragma unroll
        for (int r = 0; r < 4; ++r)
          o[qc][nb][r] *= scv[r];
      asm volatile("s_waitcnt lgkmcnt(0)" ::: "memory");
      __builtin_amdgcn_sched_barrier(0);
#pragma unroll
      for (int kb = 0; kb < 2; ++kb) {
        s8v pa = *(const s8v*)&Ps[w][llo][kb * 32 + lhi * 8];
#pragma unroll
        for (int nb = 0; nb < 4; ++nb) {
          s8v bv = *(const s8v*)&Vt[nb * 16 + llo][kb * 32 + lhi * 8];
          o[qc][nb] = __builtin_amdgcn_mfma_f32_16x16x32_bf16(pa, bv, o[qc][nb], 0, 0, 0);
        }
      }
    }
  }
#pragma unroll
  for (int qc = 0; qc < 4; ++qc)
#pragma unroll
    for (int nb = 0; nb < 4; ++nb)
#pragma unroll
      for (int r = 0; r < 4; ++r) {
        float inv = 1.f / lrow[qc * 4 + r];
        Ob[obase + (size_t)(w * 64 + qc * 16 + lhi * 4 + r) * 512 + nb * 16 + llo] =
            f2f8(o[qc][nb][r] * inv);
      }
}

// ---------------- loss: merge per-tile partials -> per-row nll ----------------
__global__ __launch_bounds__(256) void loss_lse_kernel(const float* __restrict__ pmax,
    const float* __restrict__ psum, const float* __restrict__ logits,
    const int* __restrict__ tgt, float* __restrict__ nll, float* __restrict__ valid) {
  const int w = threadIdx.x >> 6, lane = threadIdx.x & 63;
  const int row = blockIdx.x * 4 + w;
  float m = -1e30f, s = 0.f;
  for (int e = lane; e < 250; e += 64) {
    float pm = pmax[(size_t)row * 250 + e], ps = psum[(size_t)row * 250 + e];
    if (pm > m) { s = s * __expf(m - pm) + ps; m = pm; }
    else          s += ps * __expf(pm - m);
  }
#pragma unroll
  for (int o = 1; o < 64; o <<= 1) {
    float om = __shfl_xor(m, o), os = __shfl_xor(s, o);
    float mm = fmaxf(m, om);
    s = s * __expf(m - mm) + os * __expf(om - mm);
    m = mm;
  }
  if (lane == 0) {
    int t = tgt[row];
    float lse = m + logf(s);
    float v = (t != 1) ? 1.f : 0.f;
    nll[row] = v * (lse - logits[(size_t)row * 32000 + t]);
    valid[row] = v;
  }
}

__global__ __launch_bounds__(256) void loss_final_kernel(const float* __restrict__ nll,
    const float* __restrict__ valid, float* __restrict__ out) {
  __shared__ float sa[256], sb[256];
  int tid = threadIdx.x;
  float s = 0.f, c = 0.f;
  for (int i = tid; i < 16384; i += 256) { s += nll[i]; c += valid[i]; }
  sa[tid] = s; sb[tid] = c;
  __syncthreads();
  for (int st = 128; st > 0; st >>= 1) {
    if (tid < st) { sa[tid] += sa[tid + st]; sb[tid] += sb[tid + st]; }
    __syncthreads();
  }
  if (tid == 0) out[0] = sa[0] / fmaxf(sb[0], 1.f);
}

// =============================== host ===============================
extern "C" void kernel_launch(void* const* d_in, const int* in_sizes, int n_in,
                              void* d_out, int out_size, void* d_ws, size_t ws_size,
                              hipStream_t stream) {
  (void)in_sizes; (void)n_in; (void)out_size; (void)ws_size;
  const int* idx       = (const int*)d_in[0];
  const int* idx_enc   = (const int*)d_in[1];
  const int* targets   = (const int*)d_in[2];
  const float* emb_dec = (const float*)d_in[3];
  const float* emb_enc = (const float*)d_in[4];
  const float* enc_Wq  = (const float*)d_in[5];
  const float* enc_Wk  = (const float*)d_in[6];
  const float* enc_Wv  = (const float*)d_in[7];
  const float* enc_Wo  = (const float*)d_in[8];
  const float* enc_bo  = (const float*)d_in[9];
  const float* enc_ln_g = (const float*)d_in[10];
  const float* enc_ln_b = (const float*)d_in[11];
  const float* enc_W1  = (const float*)d_in[12];
  const float* enc_b1  = (const float*)d_in[13];
  const float* enc_W2  = (const float*)d_in[14];
  const float* enc_b2  = (const float*)d_in[15];
  const float* dWq_sa  = (const float*)d_in[16];
  const float* dWk_sa  = (const float*)d_in[17];
  const float* dWv_sa  = (const float*)d_in[18];
  const float* dWo_sa  = (const float*)d_in[19];
  const float* dbo_sa  = (const float*)d_in[20];
  const float* dWq_xa  = (const float*)d_in[21];
  const float* dWk_xa  = (const float*)d_in[22];
  const float* dWv_xa  = (const float*)d_in[23];
  const float* dWo_xa  = (const float*)d_in[24];
  const float* dbo_xa  = (const float*)d_in[25];
  const float* dec_ln_g = (const float*)d_in[26];
  const float* dec_ln_b = (const float*)d_in[27];
  const float* dec_W1  = (const float*)d_in[28];
  const float* dec_b1  = (const float*)d_in[29];
  const float* dec_W2  = (const float*)d_in[30];
  const float* dec_b2  = (const float*)d_in[31];
  const float* lnf_g   = (const float*)d_in[32];
  const float* lnf_b   = (const float*)d_in[33];
  const float* Wlm     = (const float*)d_in[34];
  const float* blm     = (const float*)d_in[35];
  float* out_logits = (float*)d_out;
  float* out_loss   = out_logits + (size_t)16384 * 32000;

  size_t off = 0;
  auto alloc = [&](size_t bytes) -> char* {
    char* p = (char*)d_ws + off;
    off += (bytes + 255) & ~(size_t)255;
    return p;
  };
  const size_t SQ = 512 * 512, SF = 512 * 2048;
  u16* tWqkvE = (u16*)alloc(6 * 3 * SQ * 2);
  u8*  tWoE   = (u8*)alloc(6 * SQ);
  u8*  tW1E   = (u8*)alloc(6 * SF);
  u8*  tW2E   = (u8*)alloc(6 * SF);
  u16* tWqkvS = (u16*)alloc(6 * 3 * SQ * 2);
  u8*  tWoS   = (u8*)alloc(6 * SQ);
  u16* tWqX   = (u16*)alloc(6 * SQ * 2);
  u16* tWkvX  = (u16*)alloc(6 * 2 * SQ * 2);
  u8*  tWoX   = (u8*)alloc(6 * SQ);
  u8*  tW1D   = (u8*)alloc(6 * SF);
  u8*  tW2D   = (u8*)alloc(6 * SF);
  u16* tWlm   = (u16*)alloc((size_t)32000 * 512 * 2);
  float* pe   = (float*)alloc(256 * 512 * 4);
  u16* yE     = (u16*)alloc((size_t)16384 * 512 * 2);   // bf16 residual streams
  u16* xD     = (u16*)alloc((size_t)16384 * 512 * 2);
  u16* hA     = (u16*)alloc((size_t)16384 * 512 * 2);
  u16* hB     = (u16*)alloc((size_t)16384 * 512 * 2);
  u16* qkvB   = (u16*)alloc((size_t)16384 * 1536 * 2);
  u16* qB     = (u16*)alloc((size_t)16384 * 512 * 2);
  u16* kvB    = (u16*)alloc((size_t)16384 * 1024 * 2);
  u8*  atB    = (u8*)alloc((size_t)16384 * 512);
  u8*  midB   = (u8*)alloc((size_t)16384 * 2048);
  float* pmax = (float*)alloc((size_t)16384 * 250 * 4);
  float* psum = (float*)alloc((size_t)16384 * 250 * 4);
  float* rnll = (float*)alloc(16384 * 4);
  float* rval = (float*)alloc(16384 * 4);

  // ---- weight conversion ----
  dim3 tb(256);
  const size_t S3 = 3 * SQ, S2 = 2 * SQ;
  {
    WcSq S;
    S.src[0] = enc_Wq;  S.dst[0] = tWqkvE + 0 * SQ; S.dstr[0] = S3;
    S.src[1] = enc_Wk;  S.dst[1] = tWqkvE + 1 * SQ; S.dstr[1] = S3;
    S.src[2] = enc_Wv;  S.dst[2] = tWqkvE + 2 * SQ; S.dstr[2] = S3;
    S.src[3] = enc_Wo;  S.dst[3] = tWoE;            S.dstr[3] = SQ;
    S.src[4] = dWq_sa;  S.dst[4] = tWqkvS + 0 * SQ; S.dstr[4] = S3;
    S.src[5] = dWk_sa;  S.dst[5] = tWqkvS + 1 * SQ; S.dstr[5] = S3;
    S.src[6] = dWv_sa;  S.dst[6] = tWqkvS + 2 * SQ; S.dstr[6] = S3;
    S.src[7] = dWo_sa;  S.dst[7] = tWoS;            S.dstr[7] = SQ;
    S.src[8] = dWq_xa;  S.dst[8] = tWqX;            S.dstr[8] = SQ;
    S.src[9] = dWk_xa;  S.dst[9] = tWkvX + 0 * SQ;  S.dstr[9] = S2;
    S.src[10] = dWv_xa; S.dst[10] = tWkvX + 1 * SQ; S.dstr[10] = S2;
    S.src[11] = dWo_xa; S.dst[11] = tWoX;           S.dstr[11] = SQ;
    S.fp8m = (1u << 3) | (1u << 7) | (1u << 11);
    wconv_sq_kernel<<<dim3(8, 8, 72), tb, 0, stream>>>(S);
  }
  wconv_kernel<1><<<dim3(8, 32, 6), tb, 0, stream>>>(enc_W1, tW1E, 512, 2048, SF);
  wconv_kernel<1><<<dim3(32, 8, 6), tb, 0, stream>>>(enc_W2, tW2E, 2048, 512, SF);
  wconv_kernel<1><<<dim3(8, 32, 6), tb, 0, stream>>>(dec_W1, tW1D, 512, 2048, SF);
  wconv_kernel<1><<<dim3(32, 8, 6), tb, 0, stream>>>(dec_W2, tW2D, 2048, 512, SF);
  wconv_kernel<0><<<dim3(8, 500, 1), tb, 0, stream>>>(Wlm, tWlm, 512, 32000, (size_t)0);
  pe_kernel<<<256, 256, 0, stream>>>(pe);

  auto ln16 = [&](const u16* xin, const float* g, const float* bb, u16* o) {
    ln_kernel<0><<<4096, 256, 0, stream>>>(xin, g, bb, o);
  };
  auto ln8 = [&](const u16* xin, const float* g, const float* bb, void* o) {
    ln_kernel<1><<<4096, 256, 0, stream>>>(xin, g, bb, o);
  };
  auto g_bf16 = [&](const u16* Ap, const u16* Bp, u16* Op, int N) {
    gemm128<0, 1, 0, 0, 0, 0, 0, 0, 0><<<dim3(128, N / 128), 256, 0, stream>>>(
        Ap, Bp, nullptr, nullptr, Op, 16384, N, 512, nullptr, nullptr,
        nullptr, nullptr, nullptr);
  };
  auto g_qkv_x = [&](const u16* Aq, const u16* Bq, u16* Oq,
                     const u16* Akv, const u16* Bkv, u16* Okv) {
    gemm128<0, 1, 0, 0, 0, 0, 0, 0, 1><<<dim3(128, 12), 256, 0, stream>>>(
        Aq, Bq, nullptr, nullptr, Oq, 16384, 512, 512, nullptr, nullptr,
        Akv, Bkv, Okv);
  };
  // fp8 A/B, bf16 residual in/out (in-place xr)
  auto proj_res8 = [&](const u8* Ap, const u8* Bp, const float* bi, u16* xr, int K) {
    gemm128<1, 3, 1, 1, 0, 0, 0, 0, 0><<<dim3(128, 4), 256, 0, stream>>>(
        Ap, Bp, bi, xr, xr, 16384, 512, K, nullptr, nullptr,
        nullptr, nullptr, nullptr);
  };
  auto ffn1_8 = [&](const u8* Ap, const u8* Bp, const float* bi, u8* Op) {
    gemm128<1, 2, 1, 0, 1, 0, 0, 0, 0><<<dim3(128, 16), 256, 0, stream>>>(
        Ap, Bp, bi, nullptr, Op, 16384, 2048, 512, nullptr, nullptr,
        nullptr, nullptr, nullptr);
  };

  // ---------------- encoder ----------------
  emb_ln_kernel<<<4096, 256, 0, stream>>>(idx_enc, emb_enc, pe,
      enc_ln_g + 0, enc_ln_b + 0, yE, hA);
  for (int l = 0; l < 6; ++l) {
    if (l) ln16(yE, enc_ln_g + (l * 2 + 0) * 512, enc_ln_b + (l * 2 + 0) * 512, hA);
    g_bf16(hA, tWqkvE + l * S3, qkvB, 1536);
    attn_kernel<<<512, 256, 0, stream>>>(qkvB, 1536, qkvB + 512, qkvB + 1024, 1536, atB, 0);
    proj_res8(atB, tWoE + l * SQ, enc_bo + l * 512, yE, 512);
    ln8(yE, enc_ln_g + (l * 2 + 1) * 512, enc_ln_b + (l * 2 + 1) * 512, hA);
    ffn1_8((const u8*)hA, tW1E + l * SF, enc_b1 + l * 2048, midB);
    proj_res8(midB, tW2E + l * SF, enc_b2 + l * 512, yE, 2048);
  }

  // ---------------- decoder ----------------
  emb_ln_kernel<<<4096, 256, 0, stream>>>(idx, emb_dec, pe,
      dec_ln_g + 0, dec_ln_b + 0, xD, hA);
  for (int l = 0; l < 6; ++l) {
    if (l) ln16(xD, dec_ln_g + (l * 4 + 0) * 512, dec_ln_b + (l * 4 + 0) * 512, hA);
    g_bf16(hA, tWqkvS + l * S3, qkvB, 1536);
    attn_kernel<<<512, 256, 0, stream>>>(qkvB, 1536, qkvB + 512, qkvB + 1024, 1536, atB, 1);
    proj_res8(atB, tWoS + l * SQ, dbo_sa + l * 512, xD, 512);
    ln2_kernel<<<8192, 256, 0, stream>>>(
        xD, dec_ln_g + (l * 4 + 1) * 512, dec_ln_b + (l * 4 + 1) * 512, hA,
        yE, dec_ln_g + (l * 4 + 2) * 512, dec_ln_b + (l * 4 + 2) * 512, hB);
    g_qkv_x(hA, tWqX + l * SQ, qB, hB, tWkvX + l * S2, kvB);
    attn_kernel<<<512, 256, 0, stream>>>(qB, 512, kvB, kvB + 512, 1024, atB, 0);
    proj_res8(atB, tWoX + l * SQ, dbo_xa + l * 512, xD, 512);
    ln8(xD, dec_ln_g + (l * 4 + 3) * 512, dec_ln_b + (l * 4 + 3) * 512, hA);
    ffn1_8((const u8*)hA, tW1D + l * SF, dec_b1 + l * 2048, midB);
    proj_res8(midB, tW2D + l * SF, dec_b2 + l * 512, xD, 2048);
  }

  // -------- LM head (bf16, fused loss partials, nt logits, row-panel swizzle) ----
  ln16(xD, lnf_g, lnf_b, hA);
  gemm128<0, 0, 1, 0, 0, 1, 1, 1, 0><<<dim3(128, 250), 256, 0, stream>>>(
      hA, tWlm, blm, nullptr, out_logits, 16384, 32000, 512, pmax, psum,
      nullptr, nullptr, nullptr);
  loss_lse_kernel<<<4096, 256, 0, stream>>>(pmax, psum, out_logits, targets, rnll, rval);
  loss_final_kernel<<<1, 256, 0, stream>>>(rnll, rval, out_loss);
}